// Round 1
// baseline (12683.723 us; speedup 1.0000x reference)
//
#include <hip/hip_runtime.h>
#include <math.h>

#define Sdim 64
#define Vdim 16
#define NLAYER 5
#define EDdim 16
#define RDdim 16
#define TDdim 64
#define FINdim 160   // 2*S + RD + ED
#define Hdim 96      // S + 2*V
#define NVdim 48     // 3*V

__device__ __forceinline__ float silu_f(float x) {
    return x / (1.0f + __expf(-x));
}

// ---------------------------------------------------------------------------
// temb = silu(silu(t @ w1 + b1) @ w2 + b2)   (B=64 rows, one block per row)
// ---------------------------------------------------------------------------
__global__ __launch_bounds__(64) void temb_kernel(
    const float* __restrict__ t, const float* __restrict__ w1, const float* __restrict__ b1,
    const float* __restrict__ w2, const float* __restrict__ b2, float* __restrict__ temb)
{
    int b = blockIdx.x, j = threadIdx.x;
    __shared__ float row[TDdim];
    __shared__ float hid[TDdim];
    row[j] = t[b * TDdim + j];
    __syncthreads();
    float h = b1[j];
    #pragma unroll 8
    for (int i = 0; i < TDdim; ++i) h = fmaf(row[i], w1[i * TDdim + j], h);
    h = silu_f(h);
    hid[j] = h;
    __syncthreads();
    float o = b2[j];
    #pragma unroll 8
    for (int i = 0; i < TDdim; ++i) o = fmaf(hid[i], w2[i * Sdim + j], o);
    temb[b * Sdim + j] = silu_f(o);
}

// ---------------------------------------------------------------------------
// s[n][j] = sum_g atom_emb[g][x[n][g]][j] + temb[batch[n]][j]
// ---------------------------------------------------------------------------
__global__ __launch_bounds__(256) void node_init_kernel(
    const int* __restrict__ x, const int* __restrict__ batch,
    const float* __restrict__ aemb, const float* __restrict__ temb,
    float* __restrict__ sfeat, int n)
{
    int idx = blockIdx.x * 256 + threadIdx.x;
    if (idx >= n * Sdim) return;
    int node = idx >> 6, j = idx & 63;
    int x0 = x[node * 3 + 0], x1 = x[node * 3 + 1], x2 = x[node * 3 + 2];
    sfeat[idx] = aemb[(0 * 16 + x0) * Sdim + j] + aemb[(16 + x1) * Sdim + j]
               + aemb[(32 + x2) * Sdim + j] + temb[batch[node] * Sdim + j];
}

// ---------------------------------------------------------------------------
// Edge MLP + message scatter.  One thread per edge; W staged in LDS and read
// wave-uniform (LDS broadcast, conflict-free).  acc[96] lives in VGPRs.
// ---------------------------------------------------------------------------
__device__ __forceinline__ void dot4(float* acc, float4 f, const float* __restrict__ w) {
    #pragma unroll
    for (int j = 0; j < Hdim; j += 4) {
        float4 w0 = *reinterpret_cast<const float4*>(w + j);
        float4 w1 = *reinterpret_cast<const float4*>(w + Hdim + j);
        float4 w2 = *reinterpret_cast<const float4*>(w + 2 * Hdim + j);
        float4 w3 = *reinterpret_cast<const float4*>(w + 3 * Hdim + j);
        acc[j+0] = fmaf(f.x, w0.x, fmaf(f.y, w1.x, fmaf(f.z, w2.x, fmaf(f.w, w3.x, acc[j+0]))));
        acc[j+1] = fmaf(f.x, w0.y, fmaf(f.y, w1.y, fmaf(f.z, w2.y, fmaf(f.w, w3.y, acc[j+1]))));
        acc[j+2] = fmaf(f.x, w0.z, fmaf(f.y, w1.z, fmaf(f.z, w2.z, fmaf(f.w, w3.z, acc[j+2]))));
        acc[j+3] = fmaf(f.x, w0.w, fmaf(f.y, w1.w, fmaf(f.z, w2.w, fmaf(f.w, w3.w, acc[j+3]))));
    }
}

__global__ __launch_bounds__(256) void edge_kernel(
    const float* __restrict__ sfeat, const float* __restrict__ vfeat,
    const float* __restrict__ pos,
    const int* __restrict__ ei, const int* __restrict__ ea,
    const float* __restrict__ bond_emb,
    const float* __restrict__ Wg, const float* __restrict__ bg,
    float* __restrict__ acc_s, float* __restrict__ acc_v, float* __restrict__ cnt,
    int E, float cutoff)
{
    __shared__ __align__(16) float Wl[FINdim * Hdim];   // 61440 B
    {
        const float4* Wg4 = reinterpret_cast<const float4*>(Wg);
        float4* Wl4 = reinterpret_cast<float4*>(Wl);
        for (int i = threadIdx.x; i < FINdim * Hdim / 4; i += 256) Wl4[i] = Wg4[i];
    }
    __syncthreads();

    int e = blockIdx.x * 256 + threadIdx.x;
    if (e >= E) return;

    int src = ei[e];
    int tgt = ei[E + e];

    float psx = pos[3*src], psy = pos[3*src+1], psz = pos[3*src+2];
    float ptx = pos[3*tgt], pty = pos[3*tgt+1], ptz = pos[3*tgt+2];
    float rx = ptx - psx, ry = pty - psy, rz = ptz - psz;
    float rr = rx*rx + ry*ry + rz*rz;
    float d = sqrtf(fmaxf(rr, 1e-6f));
    float invd = 1.0f / d;
    float rnx = rx*invd, rny = ry*invd, rnz = rz*invd;
    float env = (d < cutoff) ? 0.5f * (__cosf(3.14159265358979f * d / cutoff) + 1.0f) : 0.0f;
    float invw = (float)RDdim / cutoff;      // 1/width, width = cutoff/RD

    float rbf[RDdim];
    #pragma unroll
    for (int k = 0; k < RDdim; ++k) {
        float c = cutoff * ((float)k / 15.0f);   // linspace(0, cutoff, 16)
        float tt = (d - c) * invw;
        rbf[k] = __expf(-0.5f * tt * tt) * env;
    }
    float bnd[EDdim];
    {
        const float4* bp = reinterpret_cast<const float4*>(bond_emb + ea[e] * EDdim);
        #pragma unroll
        for (int c4 = 0; c4 < 4; ++c4) {
            float4 bv = bp[c4];
            bnd[c4*4+0] = bv.x; bnd[c4*4+1] = bv.y; bnd[c4*4+2] = bv.z; bnd[c4*4+3] = bv.w;
        }
    }

    float acc[Hdim];
    #pragma unroll
    for (int j = 0; j < Hdim; ++j) acc[j] = bg[j];

    // segment A: feat[0:64] = s[src]
    const float4* sp = reinterpret_cast<const float4*>(sfeat + (size_t)src * Sdim);
    #pragma unroll 2
    for (int c4 = 0; c4 < 16; ++c4) {
        float4 f = sp[c4];
        dot4(acc, f, &Wl[(c4 * 4) * Hdim]);
    }
    // segment B: feat[64:128] = s[tgt]
    const float4* tp = reinterpret_cast<const float4*>(sfeat + (size_t)tgt * Sdim);
    #pragma unroll 2
    for (int c4 = 0; c4 < 16; ++c4) {
        float4 f = tp[c4];
        dot4(acc, f, &Wl[(64 + c4 * 4) * Hdim]);
    }
    // segment C: feat[128:144] = rbf
    #pragma unroll
    for (int c4 = 0; c4 < 4; ++c4) {
        float4 f = make_float4(rbf[c4*4], rbf[c4*4+1], rbf[c4*4+2], rbf[c4*4+3]);
        dot4(acc, f, &Wl[(128 + c4 * 4) * Hdim]);
    }
    // segment D: feat[144:160] = bond_emb[ea]
    #pragma unroll
    for (int c4 = 0; c4 < 4; ++c4) {
        float4 f = make_float4(bnd[c4*4], bnd[c4*4+1], bnd[c4*4+2], bnd[c4*4+3]);
        dot4(acc, f, &Wl[(144 + c4 * 4) * Hdim]);
    }

    #pragma unroll
    for (int j = 0; j < Hdim; ++j) acc[j] = silu_f(acc[j]);

    // scatter ms into acc_s[tgt]
    float* as = acc_s + (size_t)tgt * Sdim;
    #pragma unroll
    for (int j = 0; j < Sdim; ++j) atomicAdd(as + j, acc[j]);

    // vm = v[src]*wv1 + rn x wv2 ; scatter into acc_v[tgt]
    const float* vp = vfeat + (size_t)src * NVdim;
    float* av = acc_v + (size_t)tgt * NVdim;
    #pragma unroll
    for (int dd = 0; dd < 3; ++dd) {
        float rn_d = (dd == 0) ? rnx : ((dd == 1) ? rny : rnz);
        #pragma unroll
        for (int m = 0; m < Vdim; ++m) {
            float vm = fmaf(vp[dd * Vdim + m], acc[Sdim + m], rn_d * acc[Sdim + Vdim + m]);
            atomicAdd(av + dd * Vdim + m, vm);
        }
    }
    atomicAdd(cnt + tgt, 1.0f);
}

// ---------------------------------------------------------------------------
// Node update: s += silu((acc_s/cnt) @ wu + bu); v += acc_v/cnt; optional LN.
// One wave per node.
// ---------------------------------------------------------------------------
__global__ __launch_bounds__(64) void node_update_kernel(
    float* __restrict__ sfeat, float* __restrict__ vfeat,
    const float* __restrict__ acc_s, const float* __restrict__ acc_v,
    const float* __restrict__ cnt,
    const float* __restrict__ wu, const float* __restrict__ bu,
    const float* __restrict__ lng, const float* __restrict__ lnb,
    int do_ln)
{
    int node = blockIdx.x;
    int j = threadIdx.x;
    __shared__ __align__(16) float ag[Sdim];
    float c = cnt[node];
    float ic = 1.0f / fmaxf(c, 1.0f);
    ag[j] = acc_s[(size_t)node * Sdim + j] * ic;
    __syncthreads();
    float o = bu[j];
    #pragma unroll 8
    for (int i = 0; i < Sdim; ++i) o = fmaf(ag[i], wu[i * Sdim + j], o);
    float sn = sfeat[(size_t)node * Sdim + j] + silu_f(o);
    if (j < NVdim) {
        vfeat[(size_t)node * NVdim + j] += acc_v[(size_t)node * NVdim + j] * ic;
    }
    if (do_ln) {
        float m = sn;
        #pragma unroll
        for (int off = 32; off >= 1; off >>= 1) m += __shfl_xor(m, off);
        m *= (1.0f / 64.0f);
        float dv = sn - m;
        float var = dv * dv;
        #pragma unroll
        for (int off = 32; off >= 1; off >>= 1) var += __shfl_xor(var, off);
        var *= (1.0f / 64.0f);
        sn = dv * rsqrtf(var + 1e-5f) * lng[j] + lnb[j];
    }
    sfeat[(size_t)node * Sdim + j] = sn;
}

// ---------------------------------------------------------------------------
// Head part 1: dsc[n] = sum_j silu(s[n][j])*wd[j]; out[n][d] = sum_m v[n][d][m]*wo[m]
// ---------------------------------------------------------------------------
__global__ __launch_bounds__(64) void head1_kernel(
    const float* __restrict__ sfeat, const float* __restrict__ vfeat,
    const float* __restrict__ wd, const float* __restrict__ wo,
    float* __restrict__ dsc, float* __restrict__ out)
{
    int node = blockIdx.x, j = threadIdx.x;
    float val = silu_f(sfeat[(size_t)node * Sdim + j]) * wd[j];
    #pragma unroll
    for (int off = 32; off >= 1; off >>= 1) val += __shfl_xor(val, off);
    if (j == 0) dsc[node] = val;
    if (j < 3) {
        float a = 0.0f;
        #pragma unroll
        for (int m = 0; m < Vdim; ++m)
            a += vfeat[(size_t)node * NVdim + j * Vdim + m] * wo[m];
        out[(size_t)node * 3 + j] = a;
    }
}

// ---------------------------------------------------------------------------
// Head part 2: out[tgt] += (dsc[src]+dsc[tgt]) * (pos[src]-pos[tgt])  (global edges)
// ---------------------------------------------------------------------------
__global__ __launch_bounds__(256) void head2_kernel(
    const float* __restrict__ dsc, const float* __restrict__ pos,
    const int* __restrict__ eig, float* __restrict__ out, int E)
{
    int e = blockIdx.x * 256 + threadIdx.x;
    if (e >= E) return;
    int src = eig[e], tgt = eig[E + e];
    float w = dsc[src] + dsc[tgt];
    atomicAdd(out + 3 * tgt + 0, w * (pos[3*src+0] - pos[3*tgt+0]));
    atomicAdd(out + 3 * tgt + 1, w * (pos[3*src+1] - pos[3*tgt+1]));
    atomicAdd(out + 3 * tgt + 2, w * (pos[3*src+2] - pos[3*tgt+2]));
}

// ---------------------------------------------------------------------------
extern "C" void kernel_launch(void* const* d_in, const int* in_sizes, int n_in,
                              void* d_out, int out_size, void* d_ws, size_t ws_size,
                              hipStream_t stream)
{
    const int*   x     = (const int*)d_in[0];
    const float* t     = (const float*)d_in[1];
    const float* pos   = (const float*)d_in[2];
    const int*   eil   = (const int*)d_in[3];
    const int*   eig   = (const int*)d_in[4];
    const int*   eal   = (const int*)d_in[5];
    const int*   eag   = (const int*)d_in[6];
    const int*   batch = (const int*)d_in[7];
    const float* aemb  = (const float*)d_in[8];
    const float* bemb  = (const float*)d_in[9];
    const float* t_w1  = (const float*)d_in[10];
    const float* t_b1  = (const float*)d_in[11];
    const float* t_w2  = (const float*)d_in[12];
    const float* t_b2  = (const float*)d_in[13];
    const float* wm    = (const float*)d_in[14];
    const float* bm    = (const float*)d_in[15];
    const float* wu    = (const float*)d_in[16];
    const float* bu    = (const float*)d_in[17];
    const float* lng   = (const float*)d_in[18];
    const float* lnb   = (const float*)d_in[19];
    const float* wd    = (const float*)d_in[20];
    const float* wo    = (const float*)d_in[21];

    const int n  = in_sizes[7];        // 16384
    const int B  = in_sizes[1] / TDdim; // 64
    const int EL = in_sizes[3] / 2;    // 131072
    const int EG = in_sizes[4] / 2;    // 262144

    float* ws    = (float*)d_ws;
    float* temb  = ws;
    float* sfeat = temb  + (size_t)B * Sdim;
    float* vfeat = sfeat + (size_t)n * Sdim;
    float* acc_s = vfeat + (size_t)n * NVdim;
    float* acc_v = acc_s + (size_t)n * Sdim;     // contiguous with acc_s
    float* cntf  = acc_v + (size_t)n * NVdim;    // contiguous with acc_v
    float* dsc   = cntf  + (size_t)n;

    float* out = (float*)d_out;

    temb_kernel<<<B, 64, 0, stream>>>(t, t_w1, t_b1, t_w2, t_b2, temb);
    node_init_kernel<<<(n * Sdim + 255) / 256, 256, 0, stream>>>(x, batch, aemb, temb, sfeat, n);
    hipMemsetAsync(vfeat, 0, (size_t)n * NVdim * sizeof(float), stream);

    const size_t accBytes = (size_t)n * (Sdim + NVdim + 1) * sizeof(float);
    for (int l = 0; l < NLAYER; ++l) {
        for (int k = 0; k < 2; ++k) {
            const int* ei = (k == 0) ? eil : eig;
            const int* ea = (k == 0) ? eal : eag;
            int   E      = (k == 0) ? EL : EG;
            float cutoff = (k == 0) ? 3.0f : 10.0f;
            const float* Wg = wm + (size_t)(l * 2 + k) * FINdim * Hdim;
            const float* bg = bm + (size_t)(l * 2 + k) * Hdim;

            hipMemsetAsync(acc_s, 0, accBytes, stream);
            edge_kernel<<<(E + 255) / 256, 256, 0, stream>>>(
                sfeat, vfeat, pos, ei, ea, bemb, Wg, bg, acc_s, acc_v, cntf, E, cutoff);
            node_update_kernel<<<n, 64, 0, stream>>>(
                sfeat, vfeat, acc_s, acc_v, cntf,
                wu + (size_t)(l * 2 + k) * Sdim * Sdim, bu + (size_t)(l * 2 + k) * Sdim,
                lng + (size_t)l * Sdim, lnb + (size_t)l * Sdim, (k == 1) ? 1 : 0);
        }
    }

    head1_kernel<<<n, 64, 0, stream>>>(sfeat, vfeat, wd, wo, dsc, out);
    head2_kernel<<<(EG + 255) / 256, 256, 0, stream>>>(dsc, pos, eig, out, EG);
}

// Round 2
// 3986.338 us; speedup vs baseline: 3.1818x; 3.1818x over previous
//
#include <hip/hip_runtime.h>
#include <math.h>

#define Sdim 64
#define Vdim 16
#define NLAYER 5
#define EDdim 16
#define RDdim 16
#define TDdim 64
#define FINdim 160   // 2*S + RD + ED
#define Hdim 96      // S + 2*V
#define NVdim 48     // 3*V
#define ACCW 113     // 64 ms + 48 vm, padded stride (odd -> bank-friendly)

__device__ __forceinline__ float silu_f(float x) {
    return x / (1.0f + __expf(-x));
}

// ---------------------------------------------------------------------------
// temb = silu(silu(t @ w1 + b1) @ w2 + b2)   (B=64 rows, one block per row)
// ---------------------------------------------------------------------------
__global__ __launch_bounds__(64) void temb_kernel(
    const float* __restrict__ t, const float* __restrict__ w1, const float* __restrict__ b1,
    const float* __restrict__ w2, const float* __restrict__ b2, float* __restrict__ temb)
{
    int b = blockIdx.x, j = threadIdx.x;
    __shared__ float row[TDdim];
    __shared__ float hid[TDdim];
    row[j] = t[b * TDdim + j];
    __syncthreads();
    float h = b1[j];
    #pragma unroll 8
    for (int i = 0; i < TDdim; ++i) h = fmaf(row[i], w1[i * TDdim + j], h);
    h = silu_f(h);
    hid[j] = h;
    __syncthreads();
    float o = b2[j];
    #pragma unroll 8
    for (int i = 0; i < TDdim; ++i) o = fmaf(hid[i], w2[i * Sdim + j], o);
    temb[b * Sdim + j] = silu_f(o);
}

// ---------------------------------------------------------------------------
// s[n][j] = sum_g atom_emb[g][x[n][g]][j] + temb[batch[n]][j]
// ---------------------------------------------------------------------------
__global__ __launch_bounds__(256) void node_init_kernel(
    const int* __restrict__ x, const int* __restrict__ batch,
    const float* __restrict__ aemb, const float* __restrict__ temb,
    float* __restrict__ sfeat, int n)
{
    int idx = blockIdx.x * 256 + threadIdx.x;
    if (idx >= n * Sdim) return;
    int node = idx >> 6, j = idx & 63;
    int x0 = x[node * 3 + 0], x1 = x[node * 3 + 1], x2 = x[node * 3 + 2];
    sfeat[idx] = aemb[(0 * 16 + x0) * Sdim + j] + aemb[(16 + x1) * Sdim + j]
               + aemb[(32 + x2) * Sdim + j] + temb[batch[node] * Sdim + j];
}

// ---------------------------------------------------------------------------
// CSR build (once per launch, reused by all 10 layer-sets)
// ---------------------------------------------------------------------------
__global__ __launch_bounds__(256) void count_kernel(
    const int* __restrict__ ei, int E, int* __restrict__ counts)
{
    int e = blockIdx.x * 256 + threadIdx.x;
    if (e >= E) return;
    atomicAdd(&counts[ei[E + e]], 1);   // tgt
}

// single block: exclusive prefix sum of counts[n] -> rowStart[n+1], cursor[n]
__global__ __launch_bounds__(256) void scan_kernel(
    const int* __restrict__ counts, int n,
    int* __restrict__ rowStart, int* __restrict__ cursor)
{
    __shared__ int partial[256];
    __shared__ int spart[257];
    int t = threadIdx.x;
    int chunk = n / 256;
    int base = t * chunk;
    int s = 0;
    for (int i = 0; i < chunk; ++i) s += counts[base + i];
    partial[t] = s;
    __syncthreads();
    if (t == 0) {
        int a = 0;
        for (int i = 0; i < 256; ++i) { spart[i] = a; a += partial[i]; }
        spart[256] = a;
    }
    __syncthreads();
    int off = spart[t];
    for (int i = 0; i < chunk; ++i) {
        rowStart[base + i] = off;
        cursor[base + i]   = off;
        off += counts[base + i];
    }
    if (t == 255) rowStart[n] = spart[256];
}

__global__ __launch_bounds__(256) void scatter_kernel(
    const int* __restrict__ ei, const int* __restrict__ ea, int E,
    int* __restrict__ cursor,
    int* __restrict__ srcS, int* __restrict__ tgtS, int* __restrict__ eaS)
{
    int e = blockIdx.x * 256 + threadIdx.x;
    if (e >= E) return;
    int tgt = ei[E + e];
    int p = atomicAdd(&cursor[tgt], 1);
    srcS[p] = ei[e];
    tgtS[p] = tgt;
    eaS[p]  = ea[e];
}

// ---------------------------------------------------------------------------
// Fused layer-set kernel.  Block owns nodes [b*G, (b+1)*G) and (via CSR) all
// their incoming edges.  Phase 1: thread-per-edge MLP, accumulate messages in
// LDS (atomicAdd into per-node slots).  Phase 2: segment-mean + update GEMM +
// v update + optional LayerNorm, written to double-buffered s_out/v_out.
// ---------------------------------------------------------------------------
__device__ __forceinline__ void dot4(float* acc, float4 f, const float* __restrict__ w) {
    #pragma unroll
    for (int j = 0; j < Hdim; j += 4) {
        float4 w0 = *reinterpret_cast<const float4*>(w + j);
        float4 w1 = *reinterpret_cast<const float4*>(w + Hdim + j);
        float4 w2 = *reinterpret_cast<const float4*>(w + 2 * Hdim + j);
        float4 w3 = *reinterpret_cast<const float4*>(w + 3 * Hdim + j);
        acc[j+0] = fmaf(f.x, w0.x, fmaf(f.y, w1.x, fmaf(f.z, w2.x, fmaf(f.w, w3.x, acc[j+0]))));
        acc[j+1] = fmaf(f.x, w0.y, fmaf(f.y, w1.y, fmaf(f.z, w2.y, fmaf(f.w, w3.y, acc[j+1]))));
        acc[j+2] = fmaf(f.x, w0.z, fmaf(f.y, w1.z, fmaf(f.z, w2.z, fmaf(f.w, w3.z, acc[j+2]))));
        acc[j+3] = fmaf(f.x, w0.w, fmaf(f.y, w1.w, fmaf(f.z, w2.w, fmaf(f.w, w3.w, acc[j+3]))));
    }
}

template<int G>
__global__ __launch_bounds__(256) void fused_layer_kernel(
    const float* __restrict__ s_in, float* __restrict__ s_out,
    const float* __restrict__ v_in, float* __restrict__ v_out,
    const float* __restrict__ pos,
    const int* __restrict__ rowStart,
    const int* __restrict__ srcS, const int* __restrict__ tgtS, const int* __restrict__ eaS,
    const float* __restrict__ bond_emb,
    const float* __restrict__ Wg, const float* __restrict__ bg,
    const float* __restrict__ wu, const float* __restrict__ bu,
    const float* __restrict__ lng, const float* __restrict__ lnb,
    int do_ln, float cutoff)
{
    extern __shared__ float smem[];
    float* Wl   = smem;                    // FINdim*Hdim = 15360 floats
    float* accL = smem + FINdim * Hdim;    // G*ACCW floats

    const int tid = threadIdx.x;
    const int n0  = blockIdx.x * G;

    {
        const float4* Wg4 = reinterpret_cast<const float4*>(Wg);
        float4* Wl4 = reinterpret_cast<float4*>(Wl);
        #pragma unroll
        for (int i = tid; i < FINdim * Hdim / 4; i += 256) Wl4[i] = Wg4[i];
    }
    for (int i = tid; i < G * ACCW; i += 256) accL[i] = 0.0f;
    __syncthreads();

    const int e0 = rowStart[n0];
    const int e1 = rowStart[n0 + G];

    for (int e = e0 + tid; e < e1; e += 256) {
        int src = srcS[e], tgt = tgtS[e], bidx = eaS[e];

        float psx = pos[3*src], psy = pos[3*src+1], psz = pos[3*src+2];
        float ptx = pos[3*tgt], pty = pos[3*tgt+1], ptz = pos[3*tgt+2];
        float rx = ptx - psx, ry = pty - psy, rz = ptz - psz;
        float rr = rx*rx + ry*ry + rz*rz;
        float d = sqrtf(fmaxf(rr, 1e-6f));
        float invd = 1.0f / d;
        float rnx = rx*invd, rny = ry*invd, rnz = rz*invd;
        float env = (d < cutoff) ? 0.5f * (__cosf(3.14159265358979f * d / cutoff) + 1.0f) : 0.0f;
        float invw = (float)RDdim / cutoff;

        float rbf[RDdim];
        #pragma unroll
        for (int k = 0; k < RDdim; ++k) {
            float c = cutoff * ((float)k / 15.0f);
            float tt = (d - c) * invw;
            rbf[k] = __expf(-0.5f * tt * tt) * env;
        }

        float acc[Hdim];
        #pragma unroll
        for (int j = 0; j < Hdim; ++j) acc[j] = bg[j];

        const float4* sp = reinterpret_cast<const float4*>(s_in + (size_t)src * Sdim);
        #pragma unroll 2
        for (int c4 = 0; c4 < 16; ++c4) dot4(acc, sp[c4], &Wl[(c4 * 4) * Hdim]);

        const float4* tp = reinterpret_cast<const float4*>(s_in + (size_t)tgt * Sdim);
        #pragma unroll 2
        for (int c4 = 0; c4 < 16; ++c4) dot4(acc, tp[c4], &Wl[(64 + c4 * 4) * Hdim]);

        #pragma unroll
        for (int c4 = 0; c4 < 4; ++c4) {
            float4 f = make_float4(rbf[c4*4], rbf[c4*4+1], rbf[c4*4+2], rbf[c4*4+3]);
            dot4(acc, f, &Wl[(128 + c4 * 4) * Hdim]);
        }
        const float4* bp = reinterpret_cast<const float4*>(bond_emb + (size_t)bidx * EDdim);
        #pragma unroll
        for (int c4 = 0; c4 < 4; ++c4) dot4(acc, bp[c4], &Wl[(144 + c4 * 4) * Hdim]);

        #pragma unroll
        for (int j = 0; j < Hdim; ++j) acc[j] = silu_f(acc[j]);

        float* al = accL + (size_t)(tgt - n0) * ACCW;
        #pragma unroll
        for (int j = 0; j < Sdim; ++j) atomicAdd(al + j, acc[j]);

        const float* vp = v_in + (size_t)src * NVdim;
        #pragma unroll
        for (int dd = 0; dd < 3; ++dd) {
            float rn_d = (dd == 0) ? rnx : ((dd == 1) ? rny : rnz);
            #pragma unroll
            for (int m = 0; m < Vdim; ++m) {
                float vm = fmaf(vp[dd * Vdim + m], acc[Sdim + m], rn_d * acc[Sdim + Vdim + m]);
                atomicAdd(al + Sdim + dd * Vdim + m, vm);
            }
        }
    }
    __syncthreads();

    // ---- phase 2: node updates (each node owned by exactly this block) ----
    const int j = tid & 63;
    const int w = tid >> 6;
    #pragma unroll
    for (int p = 0; p < G / 4; ++p) {
        int ln_  = w + p * 4;
        int node = n0 + ln_;
        float cntn = (float)(rowStart[node + 1] - rowStart[node]);
        float ic = 1.0f / fmaxf(cntn, 1.0f);
        const float* al = accL + (size_t)ln_ * ACCW;
        float dot = 0.0f;
        #pragma unroll 8
        for (int i = 0; i < Sdim; ++i) dot = fmaf(al[i], wu[i * Sdim + j], dot);
        float sn = s_in[(size_t)node * Sdim + j] + silu_f(fmaf(dot, ic, bu[j]));
        if (do_ln) {
            float m = sn;
            #pragma unroll
            for (int off = 32; off >= 1; off >>= 1) m += __shfl_xor(m, off);
            m *= (1.0f / 64.0f);
            float dv = sn - m;
            float var = dv * dv;
            #pragma unroll
            for (int off = 32; off >= 1; off >>= 1) var += __shfl_xor(var, off);
            var *= (1.0f / 64.0f);
            sn = dv * rsqrtf(var + 1e-5f) * lng[j] + lnb[j];
        }
        s_out[(size_t)node * Sdim + j] = sn;
    }
    for (int idx = tid; idx < G * NVdim; idx += 256) {
        int ln_ = idx / NVdim, m = idx - ln_ * NVdim;
        int node = n0 + ln_;
        float cntn = (float)(rowStart[node + 1] - rowStart[node]);
        float ic = 1.0f / fmaxf(cntn, 1.0f);
        v_out[(size_t)node * NVdim + m] =
            v_in[(size_t)node * NVdim + m] + accL[(size_t)ln_ * ACCW + Sdim + m] * ic;
    }
}

// ---------------------------------------------------------------------------
// Head part 1: dsc[n] = sum_j silu(s[n][j])*wd[j]; out[n][d] = sum_m v[n][d][m]*wo[m]
// ---------------------------------------------------------------------------
__global__ __launch_bounds__(64) void head1_kernel(
    const float* __restrict__ sfeat, const float* __restrict__ vfeat,
    const float* __restrict__ wd, const float* __restrict__ wo,
    float* __restrict__ dsc, float* __restrict__ out)
{
    int node = blockIdx.x, j = threadIdx.x;
    float val = silu_f(sfeat[(size_t)node * Sdim + j]) * wd[j];
    #pragma unroll
    for (int off = 32; off >= 1; off >>= 1) val += __shfl_xor(val, off);
    if (j == 0) dsc[node] = val;
    if (j < 3) {
        float a = 0.0f;
        #pragma unroll
        for (int m = 0; m < Vdim; ++m)
            a += vfeat[(size_t)node * NVdim + j * Vdim + m] * wo[m];
        out[(size_t)node * 3 + j] = a;
    }
}

// ---------------------------------------------------------------------------
// Head part 2: out[tgt] += (dsc[src]+dsc[tgt]) * (pos[src]-pos[tgt])  (global edges)
// ---------------------------------------------------------------------------
__global__ __launch_bounds__(256) void head2_kernel(
    const float* __restrict__ dsc, const float* __restrict__ pos,
    const int* __restrict__ eig, float* __restrict__ out, int E)
{
    int e = blockIdx.x * 256 + threadIdx.x;
    if (e >= E) return;
    int src = eig[e], tgt = eig[E + e];
    float w = dsc[src] + dsc[tgt];
    atomicAdd(out + 3 * tgt + 0, w * (pos[3*src+0] - pos[3*tgt+0]));
    atomicAdd(out + 3 * tgt + 1, w * (pos[3*src+1] - pos[3*tgt+1]));
    atomicAdd(out + 3 * tgt + 2, w * (pos[3*src+2] - pos[3*tgt+2]));
}

// ---------------------------------------------------------------------------
extern "C" void kernel_launch(void* const* d_in, const int* in_sizes, int n_in,
                              void* d_out, int out_size, void* d_ws, size_t ws_size,
                              hipStream_t stream)
{
    const int*   x     = (const int*)d_in[0];
    const float* t     = (const float*)d_in[1];
    const float* pos   = (const float*)d_in[2];
    const int*   eil   = (const int*)d_in[3];
    const int*   eig   = (const int*)d_in[4];
    const int*   eal   = (const int*)d_in[5];
    const int*   eag   = (const int*)d_in[6];
    const int*   batch = (const int*)d_in[7];
    const float* aemb  = (const float*)d_in[8];
    const float* bemb  = (const float*)d_in[9];
    const float* t_w1  = (const float*)d_in[10];
    const float* t_b1  = (const float*)d_in[11];
    const float* t_w2  = (const float*)d_in[12];
    const float* t_b2  = (const float*)d_in[13];
    const float* wm    = (const float*)d_in[14];
    const float* bm    = (const float*)d_in[15];
    const float* wu    = (const float*)d_in[16];
    const float* bu    = (const float*)d_in[17];
    const float* lng   = (const float*)d_in[18];
    const float* lnb   = (const float*)d_in[19];
    const float* wd    = (const float*)d_in[20];
    const float* wo    = (const float*)d_in[21];

    const int n  = in_sizes[7];          // 16384
    const int B  = in_sizes[1] / TDdim;  // 64
    const int EL = in_sizes[3] / 2;      // 131072
    const int EG = in_sizes[4] / 2;      // 262144

    // ---- workspace layout ----
    float* fws   = (float*)d_ws;
    float* temb  = fws;                                 // B*64
    float* dsc   = temb + (size_t)B * Sdim;             // n
    float* sA    = dsc  + (size_t)n;                    // n*64
    float* sB    = sA   + (size_t)n * Sdim;             // n*64
    float* vA    = sB   + (size_t)n * Sdim;             // n*48
    float* vB    = vA   + (size_t)n * NVdim;            // n*48
    int*   ibuf  = (int*)(vB + (size_t)n * NVdim);
    int* counts = ibuf;                 // n
    int* cursor = counts + n;           // n
    int* rsL    = cursor + n;           // n+1
    int* srcL   = rsL + (n + 1);
    int* tgtL   = srcL + EL;
    int* eaL    = tgtL + EL;
    int* rsG    = eaL + EL;             // n+1
    int* srcG   = rsG + (n + 1);
    int* tgtG   = srcG + EG;
    int* eaG    = tgtG + EG;

    float* out = (float*)d_out;

    // ---- node init ----
    temb_kernel<<<B, 64, 0, stream>>>(t, t_w1, t_b1, t_w2, t_b2, temb);
    node_init_kernel<<<(n * Sdim + 255) / 256, 256, 0, stream>>>(x, batch, aemb, temb, sA, n);
    hipMemsetAsync(vA, 0, (size_t)n * NVdim * sizeof(float), stream);

    // ---- CSR build (local, then global) ----
    hipMemsetAsync(counts, 0, (size_t)n * sizeof(int), stream);
    count_kernel<<<(EL + 255) / 256, 256, 0, stream>>>(eil, EL, counts);
    scan_kernel<<<1, 256, 0, stream>>>(counts, n, rsL, cursor);
    scatter_kernel<<<(EL + 255) / 256, 256, 0, stream>>>(eil, eal, EL, cursor, srcL, tgtL, eaL);

    hipMemsetAsync(counts, 0, (size_t)n * sizeof(int), stream);
    count_kernel<<<(EG + 255) / 256, 256, 0, stream>>>(eig, EG, counts);
    scan_kernel<<<1, 256, 0, stream>>>(counts, n, rsG, cursor);
    scatter_kernel<<<(EG + 255) / 256, 256, 0, stream>>>(eig, eag, EG, cursor, srcG, tgtG, eaG);

    // ---- layers (double-buffered s, v) ----
    float* s_cur = sA; float* s_nxt = sB;
    float* v_cur = vA; float* v_nxt = vB;
    constexpr int GL = 32;   // ~256 edges/block for local set (deg~8)
    constexpr int GG = 16;   // ~256 edges/block for global set (deg~16)
    const size_t smemL = (size_t)(FINdim * Hdim + GL * ACCW) * sizeof(float);
    const size_t smemG = (size_t)(FINdim * Hdim + GG * ACCW) * sizeof(float);

    for (int l = 0; l < NLAYER; ++l) {
        for (int k = 0; k < 2; ++k) {
            const float* Wg  = wm + (size_t)(l * 2 + k) * FINdim * Hdim;
            const float* bg  = bm + (size_t)(l * 2 + k) * Hdim;
            const float* wuk = wu + (size_t)(l * 2 + k) * Sdim * Sdim;
            const float* buk = bu + (size_t)(l * 2 + k) * Sdim;
            if (k == 0) {
                fused_layer_kernel<GL><<<n / GL, 256, smemL, stream>>>(
                    s_cur, s_nxt, v_cur, v_nxt, pos,
                    rsL, srcL, tgtL, eaL, bemb, Wg, bg, wuk, buk,
                    lng + (size_t)l * Sdim, lnb + (size_t)l * Sdim, 0, 3.0f);
            } else {
                fused_layer_kernel<GG><<<n / GG, 256, smemG, stream>>>(
                    s_cur, s_nxt, v_cur, v_nxt, pos,
                    rsG, srcG, tgtG, eaG, bemb, Wg, bg, wuk, buk,
                    lng + (size_t)l * Sdim, lnb + (size_t)l * Sdim, 1, 10.0f);
            }
            float* tmp = s_cur; s_cur = s_nxt; s_nxt = tmp;
            tmp = v_cur; v_cur = v_nxt; v_nxt = tmp;
        }
    }

    head1_kernel<<<n, 64, 0, stream>>>(s_cur, v_cur, wd, wo, dsc, out);
    head2_kernel<<<(EG + 255) / 256, 256, 0, stream>>>(dsc, pos, eig, out, EG);
}

// Round 3
// 3815.676 us; speedup vs baseline: 3.3241x; 1.0447x over previous
//
#include <hip/hip_runtime.h>
#include <math.h>

#define Sdim 64
#define Vdim 16
#define NLAYER 5
#define EDdim 16
#define RDdim 16
#define TDdim 64
#define FINdim 160   // 2*S + RD + ED
#define Hdim 96      // S + 2*V
#define NVdim 48     // 3*V
#define ACCW 113     // 64 ms + 48 vm, padded stride (odd -> bank-friendly)

__device__ __forceinline__ float silu_f(float x) {
    return x / (1.0f + __expf(-x));
}

// ---------------------------------------------------------------------------
// temb = silu(silu(t @ w1 + b1) @ w2 + b2)   (B=64 rows, one block per row)
// ---------------------------------------------------------------------------
__global__ __launch_bounds__(64) void temb_kernel(
    const float* __restrict__ t, const float* __restrict__ w1, const float* __restrict__ b1,
    const float* __restrict__ w2, const float* __restrict__ b2, float* __restrict__ temb)
{
    int b = blockIdx.x, j = threadIdx.x;
    __shared__ float row[TDdim];
    __shared__ float hid[TDdim];
    row[j] = t[b * TDdim + j];
    __syncthreads();
    float h = b1[j];
    #pragma unroll 8
    for (int i = 0; i < TDdim; ++i) h = fmaf(row[i], w1[i * TDdim + j], h);
    h = silu_f(h);
    hid[j] = h;
    __syncthreads();
    float o = b2[j];
    #pragma unroll 8
    for (int i = 0; i < TDdim; ++i) o = fmaf(hid[i], w2[i * Sdim + j], o);
    temb[b * Sdim + j] = silu_f(o);
}

// ---------------------------------------------------------------------------
// s[n][j] = sum_g atom_emb[g][x[n][g]][j] + temb[batch[n]][j]
// ---------------------------------------------------------------------------
__global__ __launch_bounds__(256) void node_init_kernel(
    const int* __restrict__ x, const int* __restrict__ batch,
    const float* __restrict__ aemb, const float* __restrict__ temb,
    float* __restrict__ sfeat, int n)
{
    int idx = blockIdx.x * 256 + threadIdx.x;
    if (idx >= n * Sdim) return;
    int node = idx >> 6, j = idx & 63;
    int x0 = x[node * 3 + 0], x1 = x[node * 3 + 1], x2 = x[node * 3 + 2];
    sfeat[idx] = aemb[(0 * 16 + x0) * Sdim + j] + aemb[(16 + x1) * Sdim + j]
               + aemb[(32 + x2) * Sdim + j] + temb[batch[node] * Sdim + j];
}

// ---------------------------------------------------------------------------
// CSR build (once per launch, reused by all 10 layer-sets)
// ---------------------------------------------------------------------------
__global__ __launch_bounds__(256) void count_kernel(
    const int* __restrict__ ei, int E, int* __restrict__ counts)
{
    int e = blockIdx.x * 256 + threadIdx.x;
    if (e >= E) return;
    atomicAdd(&counts[ei[E + e]], 1);   // tgt
}

// single block: exclusive prefix sum of counts[n] -> rowStart[n+1], cursor[n]
__global__ __launch_bounds__(256) void scan_kernel(
    const int* __restrict__ counts, int n,
    int* __restrict__ rowStart, int* __restrict__ cursor)
{
    __shared__ int partial[256];
    __shared__ int spart[257];
    int t = threadIdx.x;
    int chunk = n / 256;
    int base = t * chunk;
    int s = 0;
    for (int i = 0; i < chunk; ++i) s += counts[base + i];
    partial[t] = s;
    __syncthreads();
    if (t == 0) {
        int a = 0;
        for (int i = 0; i < 256; ++i) { spart[i] = a; a += partial[i]; }
        spart[256] = a;
    }
    __syncthreads();
    int off = spart[t];
    for (int i = 0; i < chunk; ++i) {
        rowStart[base + i] = off;
        cursor[base + i]   = off;
        off += counts[base + i];
    }
    if (t == 255) rowStart[n] = spart[256];
}

__global__ __launch_bounds__(256) void scatter_kernel(
    const int* __restrict__ ei, const int* __restrict__ ea, int E,
    int* __restrict__ cursor,
    int* __restrict__ srcS, int* __restrict__ tgtS, int* __restrict__ eaS)
{
    int e = blockIdx.x * 256 + threadIdx.x;
    if (e >= E) return;
    int tgt = ei[E + e];
    int p = atomicAdd(&cursor[tgt], 1);
    srcS[p] = ei[e];
    tgtS[p] = tgt;
    eaS[p]  = ea[e];
}

// ---------------------------------------------------------------------------
// Fused layer-set kernel.  Weights are read DIRECTLY FROM GLOBAL with
// thread-uniform addresses -> compiler emits s_load + v_fmac with SGPR
// operand.  This keeps the LDS pipe free (LDS holds only the per-node
// message accumulators) and the scalar pipe streams W from L1/L2.
// ---------------------------------------------------------------------------
__device__ __forceinline__ void dot4(float* acc, float4 f, const float* __restrict__ w) {
    #pragma unroll
    for (int j = 0; j < Hdim; j += 4) {
        // w rows are wave-uniform -> scalar loads
        float w00 = w[j+0],          w01 = w[j+1],          w02 = w[j+2],          w03 = w[j+3];
        float w10 = w[Hdim+j+0],     w11 = w[Hdim+j+1],     w12 = w[Hdim+j+2],     w13 = w[Hdim+j+3];
        float w20 = w[2*Hdim+j+0],   w21 = w[2*Hdim+j+1],   w22 = w[2*Hdim+j+2],   w23 = w[2*Hdim+j+3];
        float w30 = w[3*Hdim+j+0],   w31 = w[3*Hdim+j+1],   w32 = w[3*Hdim+j+2],   w33 = w[3*Hdim+j+3];
        acc[j+0] = fmaf(f.x, w00, fmaf(f.y, w10, fmaf(f.z, w20, fmaf(f.w, w30, acc[j+0]))));
        acc[j+1] = fmaf(f.x, w01, fmaf(f.y, w11, fmaf(f.z, w21, fmaf(f.w, w31, acc[j+1]))));
        acc[j+2] = fmaf(f.x, w02, fmaf(f.y, w12, fmaf(f.z, w22, fmaf(f.w, w32, acc[j+2]))));
        acc[j+3] = fmaf(f.x, w03, fmaf(f.y, w13, fmaf(f.z, w23, fmaf(f.w, w33, acc[j+3]))));
    }
}

template<int G>
__global__ __launch_bounds__(256) void fused_layer_kernel(
    const float* __restrict__ s_in, float* __restrict__ s_out,
    const float* __restrict__ v_in, float* __restrict__ v_out,
    const float* __restrict__ pos,
    const int* __restrict__ rowStart,
    const int* __restrict__ srcS, const int* __restrict__ tgtS, const int* __restrict__ eaS,
    const float* __restrict__ bond_emb,
    const float* __restrict__ Wg, const float* __restrict__ bg,
    const float* __restrict__ wu, const float* __restrict__ bu,
    const float* __restrict__ lng, const float* __restrict__ lnb,
    int do_ln, float cutoff)
{
    extern __shared__ float accL[];        // G*ACCW floats

    const int tid = threadIdx.x;
    const int n0  = blockIdx.x * G;

    for (int i = tid; i < G * ACCW; i += 256) accL[i] = 0.0f;
    __syncthreads();

    const int e0 = rowStart[n0];
    const int e1 = rowStart[n0 + G];

    for (int e = e0 + tid; e < e1; e += 256) {
        int src = srcS[e], tgt = tgtS[e], bidx = eaS[e];

        float psx = pos[3*src], psy = pos[3*src+1], psz = pos[3*src+2];
        float ptx = pos[3*tgt], pty = pos[3*tgt+1], ptz = pos[3*tgt+2];
        float rx = ptx - psx, ry = pty - psy, rz = ptz - psz;
        float rr = rx*rx + ry*ry + rz*rz;
        float d = sqrtf(fmaxf(rr, 1e-6f));
        float invd = 1.0f / d;
        float rnx = rx*invd, rny = ry*invd, rnz = rz*invd;
        float env = (d < cutoff) ? 0.5f * (__cosf(3.14159265358979f * d / cutoff) + 1.0f) : 0.0f;
        float invw = (float)RDdim / cutoff;

        float rbf[RDdim];
        #pragma unroll
        for (int k = 0; k < RDdim; ++k) {
            float c = cutoff * ((float)k / 15.0f);
            float tt = (d - c) * invw;
            rbf[k] = __expf(-0.5f * tt * tt) * env;
        }

        float acc[Hdim];
        #pragma unroll
        for (int j = 0; j < Hdim; ++j) acc[j] = bg[j];

        const float4* sp = reinterpret_cast<const float4*>(s_in + (size_t)src * Sdim);
        #pragma unroll 4
        for (int c4 = 0; c4 < 16; ++c4) dot4(acc, sp[c4], Wg + (size_t)(c4 * 4) * Hdim);

        const float4* tp = reinterpret_cast<const float4*>(s_in + (size_t)tgt * Sdim);
        #pragma unroll 4
        for (int c4 = 0; c4 < 16; ++c4) dot4(acc, tp[c4], Wg + (size_t)(64 + c4 * 4) * Hdim);

        #pragma unroll
        for (int c4 = 0; c4 < 4; ++c4) {
            float4 f = make_float4(rbf[c4*4], rbf[c4*4+1], rbf[c4*4+2], rbf[c4*4+3]);
            dot4(acc, f, Wg + (size_t)(128 + c4 * 4) * Hdim);
        }
        const float4* bp = reinterpret_cast<const float4*>(bond_emb + (size_t)bidx * EDdim);
        #pragma unroll
        for (int c4 = 0; c4 < 4; ++c4) dot4(acc, bp[c4], Wg + (size_t)(144 + c4 * 4) * Hdim);

        #pragma unroll
        for (int j = 0; j < Hdim; ++j) acc[j] = silu_f(acc[j]);

        float* al = accL + (size_t)(tgt - n0) * ACCW;
        #pragma unroll
        for (int j = 0; j < Sdim; ++j) atomicAdd(al + j, acc[j]);

        const float* vp = v_in + (size_t)src * NVdim;
        #pragma unroll
        for (int dd = 0; dd < 3; ++dd) {
            float rn_d = (dd == 0) ? rnx : ((dd == 1) ? rny : rnz);
            #pragma unroll
            for (int m = 0; m < Vdim; ++m) {
                float vm = fmaf(vp[dd * Vdim + m], acc[Sdim + m], rn_d * acc[Sdim + Vdim + m]);
                atomicAdd(al + Sdim + dd * Vdim + m, vm);
            }
        }
    }
    __syncthreads();

    // ---- phase 2: node updates (each node owned by exactly this block) ----
    const int j = tid & 63;
    const int w = tid >> 6;
    #pragma unroll 2
    for (int p = 0; p < G / 4; ++p) {
        int ln_  = w + p * 4;
        int node = n0 + ln_;
        float cntn = (float)(rowStart[node + 1] - rowStart[node]);
        float ic = 1.0f / fmaxf(cntn, 1.0f);
        const float* al = accL + (size_t)ln_ * ACCW;
        float dot = 0.0f;
        #pragma unroll 8
        for (int i = 0; i < Sdim; ++i) dot = fmaf(al[i], wu[i * Sdim + j], dot);
        float sn = s_in[(size_t)node * Sdim + j] + silu_f(fmaf(dot, ic, bu[j]));
        if (do_ln) {
            float m = sn;
            #pragma unroll
            for (int off = 32; off >= 1; off >>= 1) m += __shfl_xor(m, off);
            m *= (1.0f / 64.0f);
            float dv = sn - m;
            float var = dv * dv;
            #pragma unroll
            for (int off = 32; off >= 1; off >>= 1) var += __shfl_xor(var, off);
            var *= (1.0f / 64.0f);
            sn = dv * rsqrtf(var + 1e-5f) * lng[j] + lnb[j];
        }
        s_out[(size_t)node * Sdim + j] = sn;
    }
    for (int idx = tid; idx < G * NVdim; idx += 256) {
        int ln_ = idx / NVdim, m = idx - ln_ * NVdim;
        int node = n0 + ln_;
        float cntn = (float)(rowStart[node + 1] - rowStart[node]);
        float ic = 1.0f / fmaxf(cntn, 1.0f);
        v_out[(size_t)node * NVdim + m] =
            v_in[(size_t)node * NVdim + m] + accL[(size_t)ln_ * ACCW + Sdim + m] * ic;
    }
}

// ---------------------------------------------------------------------------
// Head part 1: dsc[n] = sum_j silu(s[n][j])*wd[j]; out[n][d] = sum_m v[n][d][m]*wo[m]
// ---------------------------------------------------------------------------
__global__ __launch_bounds__(64) void head1_kernel(
    const float* __restrict__ sfeat, const float* __restrict__ vfeat,
    const float* __restrict__ wd, const float* __restrict__ wo,
    float* __restrict__ dsc, float* __restrict__ out)
{
    int node = blockIdx.x, j = threadIdx.x;
    float val = silu_f(sfeat[(size_t)node * Sdim + j]) * wd[j];
    #pragma unroll
    for (int off = 32; off >= 1; off >>= 1) val += __shfl_xor(val, off);
    if (j == 0) dsc[node] = val;
    if (j < 3) {
        float a = 0.0f;
        #pragma unroll
        for (int m = 0; m < Vdim; ++m)
            a += vfeat[(size_t)node * NVdim + j * Vdim + m] * wo[m];
        out[(size_t)node * 3 + j] = a;
    }
}

// ---------------------------------------------------------------------------
// Head part 2: out[tgt] += (dsc[src]+dsc[tgt]) * (pos[src]-pos[tgt])  (global edges)
// ---------------------------------------------------------------------------
__global__ __launch_bounds__(256) void head2_kernel(
    const float* __restrict__ dsc, const float* __restrict__ pos,
    const int* __restrict__ eig, float* __restrict__ out, int E)
{
    int e = blockIdx.x * 256 + threadIdx.x;
    if (e >= E) return;
    int src = eig[e], tgt = eig[E + e];
    float w = dsc[src] + dsc[tgt];
    atomicAdd(out + 3 * tgt + 0, w * (pos[3*src+0] - pos[3*tgt+0]));
    atomicAdd(out + 3 * tgt + 1, w * (pos[3*src+1] - pos[3*tgt+1]));
    atomicAdd(out + 3 * tgt + 2, w * (pos[3*src+2] - pos[3*tgt+2]));
}

// ---------------------------------------------------------------------------
extern "C" void kernel_launch(void* const* d_in, const int* in_sizes, int n_in,
                              void* d_out, int out_size, void* d_ws, size_t ws_size,
                              hipStream_t stream)
{
    const int*   x     = (const int*)d_in[0];
    const float* t     = (const float*)d_in[1];
    const float* pos   = (const float*)d_in[2];
    const int*   eil   = (const int*)d_in[3];
    const int*   eig   = (const int*)d_in[4];
    const int*   eal   = (const int*)d_in[5];
    const int*   eag   = (const int*)d_in[6];
    const int*   batch = (const int*)d_in[7];
    const float* aemb  = (const float*)d_in[8];
    const float* bemb  = (const float*)d_in[9];
    const float* t_w1  = (const float*)d_in[10];
    const float* t_b1  = (const float*)d_in[11];
    const float* t_w2  = (const float*)d_in[12];
    const float* t_b2  = (const float*)d_in[13];
    const float* wm    = (const float*)d_in[14];
    const float* bm    = (const float*)d_in[15];
    const float* wu    = (const float*)d_in[16];
    const float* bu    = (const float*)d_in[17];
    const float* lng   = (const float*)d_in[18];
    const float* lnb   = (const float*)d_in[19];
    const float* wd    = (const float*)d_in[20];
    const float* wo    = (const float*)d_in[21];

    const int n  = in_sizes[7];          // 16384
    const int B  = in_sizes[1] / TDdim;  // 64
    const int EL = in_sizes[3] / 2;      // 131072
    const int EG = in_sizes[4] / 2;      // 262144

    // ---- workspace layout ----
    float* fws   = (float*)d_ws;
    float* temb  = fws;                                 // B*64
    float* dsc   = temb + (size_t)B * Sdim;             // n
    float* sA    = dsc  + (size_t)n;                    // n*64
    float* sB    = sA   + (size_t)n * Sdim;             // n*64
    float* vA    = sB   + (size_t)n * Sdim;             // n*48
    float* vB    = vA   + (size_t)n * NVdim;            // n*48
    int*   ibuf  = (int*)(vB + (size_t)n * NVdim);
    int* counts = ibuf;                 // n
    int* cursor = counts + n;           // n
    int* rsL    = cursor + n;           // n+1
    int* srcL   = rsL + (n + 1);
    int* tgtL   = srcL + EL;
    int* eaL    = tgtL + EL;
    int* rsG    = eaL + EL;             // n+1
    int* srcG   = rsG + (n + 1);
    int* tgtG   = srcG + EG;
    int* eaG    = tgtG + EG;

    float* out = (float*)d_out;

    // ---- node init ----
    temb_kernel<<<B, 64, 0, stream>>>(t, t_w1, t_b1, t_w2, t_b2, temb);
    node_init_kernel<<<(n * Sdim + 255) / 256, 256, 0, stream>>>(x, batch, aemb, temb, sA, n);
    hipMemsetAsync(vA, 0, (size_t)n * NVdim * sizeof(float), stream);

    // ---- CSR build (local, then global) ----
    hipMemsetAsync(counts, 0, (size_t)n * sizeof(int), stream);
    count_kernel<<<(EL + 255) / 256, 256, 0, stream>>>(eil, EL, counts);
    scan_kernel<<<1, 256, 0, stream>>>(counts, n, rsL, cursor);
    scatter_kernel<<<(EL + 255) / 256, 256, 0, stream>>>(eil, eal, EL, cursor, srcL, tgtL, eaL);

    hipMemsetAsync(counts, 0, (size_t)n * sizeof(int), stream);
    count_kernel<<<(EG + 255) / 256, 256, 0, stream>>>(eig, EG, counts);
    scan_kernel<<<1, 256, 0, stream>>>(counts, n, rsG, cursor);
    scatter_kernel<<<(EG + 255) / 256, 256, 0, stream>>>(eig, eag, EG, cursor, srcG, tgtG, eaG);

    // ---- layers (double-buffered s, v) ----
    float* s_cur = sA; float* s_nxt = sB;
    float* v_cur = vA; float* v_nxt = vB;
    constexpr int GL = 32;   // 512 blocks, ~256 edges/block (deg~8)
    constexpr int GG = 32;   // 512 blocks, ~512 edges/block (deg~16)
    const size_t smemL = (size_t)(GL * ACCW) * sizeof(float);
    const size_t smemG = (size_t)(GG * ACCW) * sizeof(float);

    for (int l = 0; l < NLAYER; ++l) {
        for (int k = 0; k < 2; ++k) {
            const float* Wg  = wm + (size_t)(l * 2 + k) * FINdim * Hdim;
            const float* bg  = bm + (size_t)(l * 2 + k) * Hdim;
            const float* wuk = wu + (size_t)(l * 2 + k) * Sdim * Sdim;
            const float* buk = bu + (size_t)(l * 2 + k) * Sdim;
            if (k == 0) {
                fused_layer_kernel<GL><<<n / GL, 256, smemL, stream>>>(
                    s_cur, s_nxt, v_cur, v_nxt, pos,
                    rsL, srcL, tgtL, eaL, bemb, Wg, bg, wuk, buk,
                    lng + (size_t)l * Sdim, lnb + (size_t)l * Sdim, 0, 3.0f);
            } else {
                fused_layer_kernel<GG><<<n / GG, 256, smemG, stream>>>(
                    s_cur, s_nxt, v_cur, v_nxt, pos,
                    rsG, srcG, tgtG, eaG, bemb, Wg, bg, wuk, buk,
                    lng + (size_t)l * Sdim, lnb + (size_t)l * Sdim, 1, 10.0f);
            }
            float* tmp = s_cur; s_cur = s_nxt; s_nxt = tmp;
            tmp = v_cur; v_cur = v_nxt; v_nxt = tmp;
        }
    }

    head1_kernel<<<n, 64, 0, stream>>>(s_cur, v_cur, wd, wo, dsc, out);
    head2_kernel<<<(EG + 255) / 256, 256, 0, stream>>>(dsc, pos, eig, out, EG);
}

// Round 4
// 1756.738 us; speedup vs baseline: 7.2200x; 2.1720x over previous
//
#include <hip/hip_runtime.h>
#include <math.h>

#define Sdim 64
#define Vdim 16
#define NLAYER 5
#define EDdim 16
#define RDdim 16
#define TDdim 64
#define FINdim 160   // 2*S + RD + ED
#define Hdim 96      // S + 2*V
#define NVdim 48     // 3*V
#define ACCW 113     // 64 ms + 48 vm + pad (odd stride)
#define RBW 40       // tileRB row stride in ushorts (32 data + 8 pad)
#define WVW 33       // wv staging row stride in floats

typedef __attribute__((ext_vector_type(8))) short bf16x8;
typedef __attribute__((ext_vector_type(4))) float f32x4;

__device__ __forceinline__ float silu_f(float x) {
    return x / (1.0f + __expf(-x));
}

__device__ __forceinline__ unsigned short f2bf(float x) {
    union { float f; unsigned u; } v; v.f = x;
    unsigned r = v.u + 0x7fffu + ((v.u >> 16) & 1u);
    return (unsigned short)(r >> 16);
}

// ---------------------------------------------------------------------------
// Pack W (10 layer-sets, [160][96] fp32) into MFMA-friendly bf16 layout:
// Wp[ls][(kb*96 + col)*8 + (k&7)], kb = k>>3.  Also bond_emb -> bf16.
// ---------------------------------------------------------------------------
__global__ __launch_bounds__(256) void pack_kernel(
    const float* __restrict__ wm, const float* __restrict__ bemb,
    unsigned short* __restrict__ wp, unsigned short* __restrict__ bondbf)
{
    int idx = blockIdx.x * 256 + threadIdx.x;
    if (idx < 10 * FINdim * Hdim) {
        int ls = idx / (FINdim * Hdim), rem = idx % (FINdim * Hdim);
        int k = rem / Hdim, c = rem % Hdim;
        wp[(size_t)ls * FINdim * Hdim + ((size_t)(k >> 3) * Hdim + c) * 8 + (k & 7)] =
            f2bf(wm[idx]);
    } else if (idx < 10 * FINdim * Hdim + 80) {
        int i = idx - 10 * FINdim * Hdim;
        bondbf[i] = f2bf(bemb[i]);
    }
}

// ---------------------------------------------------------------------------
// temb = silu(silu(t @ w1 + b1) @ w2 + b2)
// ---------------------------------------------------------------------------
__global__ __launch_bounds__(64) void temb_kernel(
    const float* __restrict__ t, const float* __restrict__ w1, const float* __restrict__ b1,
    const float* __restrict__ w2, const float* __restrict__ b2, float* __restrict__ temb)
{
    int b = blockIdx.x, j = threadIdx.x;
    __shared__ float row[TDdim];
    __shared__ float hid[TDdim];
    row[j] = t[b * TDdim + j];
    __syncthreads();
    float h = b1[j];
    #pragma unroll 8
    for (int i = 0; i < TDdim; ++i) h = fmaf(row[i], w1[i * TDdim + j], h);
    h = silu_f(h);
    hid[j] = h;
    __syncthreads();
    float o = b2[j];
    #pragma unroll 8
    for (int i = 0; i < TDdim; ++i) o = fmaf(hid[i], w2[i * Sdim + j], o);
    temb[b * Sdim + j] = silu_f(o);
}

// ---------------------------------------------------------------------------
// s init (fp32 + bf16 copies)
// ---------------------------------------------------------------------------
__global__ __launch_bounds__(256) void node_init_kernel(
    const int* __restrict__ x, const int* __restrict__ batch,
    const float* __restrict__ aemb, const float* __restrict__ temb,
    float* __restrict__ sfeat, unsigned short* __restrict__ sbf, int n)
{
    int idx = blockIdx.x * 256 + threadIdx.x;
    if (idx >= n * Sdim) return;
    int node = idx >> 6, j = idx & 63;
    int x0 = x[node * 3 + 0], x1 = x[node * 3 + 1], x2 = x[node * 3 + 2];
    float v = aemb[(0 * 16 + x0) * Sdim + j] + aemb[(16 + x1) * Sdim + j]
            + aemb[(32 + x2) * Sdim + j] + temb[batch[node] * Sdim + j];
    sfeat[idx] = v;
    sbf[idx]   = f2bf(v);
}

// ---------------------------------------------------------------------------
// CSR build
// ---------------------------------------------------------------------------
__global__ __launch_bounds__(256) void count_kernel(
    const int* __restrict__ ei, int E, int* __restrict__ counts)
{
    int e = blockIdx.x * 256 + threadIdx.x;
    if (e >= E) return;
    atomicAdd(&counts[ei[E + e]], 1);
}

__global__ __launch_bounds__(256) void scan_kernel(
    const int* __restrict__ counts, int n,
    int* __restrict__ rowStart, int* __restrict__ cursor)
{
    __shared__ int partial[256];
    __shared__ int spart[257];
    int t = threadIdx.x;
    int chunk = n / 256;
    int base = t * chunk;
    int s = 0;
    for (int i = 0; i < chunk; ++i) s += counts[base + i];
    partial[t] = s;
    __syncthreads();
    if (t == 0) {
        int a = 0;
        for (int i = 0; i < 256; ++i) { spart[i] = a; a += partial[i]; }
        spart[256] = a;
    }
    __syncthreads();
    int off = spart[t];
    for (int i = 0; i < chunk; ++i) {
        rowStart[base + i] = off;
        cursor[base + i]   = off;
        off += counts[base + i];
    }
    if (t == 255) rowStart[n] = spart[256];
}

__global__ __launch_bounds__(256) void scatter_kernel(
    const int* __restrict__ ei, const int* __restrict__ ea, int E,
    int* __restrict__ cursor,
    int* __restrict__ srcS, int* __restrict__ tgtS, int* __restrict__ eaS)
{
    int e = blockIdx.x * 256 + threadIdx.x;
    if (e >= E) return;
    int tgt = ei[E + e];
    int p = atomicAdd(&cursor[tgt], 1);
    srcS[p] = ei[e];
    tgtS[p] = tgt;
    eaS[p]  = ea[e];
}

// ---------------------------------------------------------------------------
// Fused layer-set kernel with MFMA edge MLP.
// Block owns G nodes + their CSR edges, processed in 64-edge tiles.
// W held entirely in VGPRs as B-fragments (loaded once per block).
// A-fragments: s parts straight from global bf16; rbf/bond via LDS tile.
// ---------------------------------------------------------------------------
template<int G>
__global__ __launch_bounds__(256, 2) void fused_layer_mfma(
    const float* __restrict__ s_in, float* __restrict__ s_out,
    const unsigned short* __restrict__ sbf_in, unsigned short* __restrict__ sbf_out,
    const float* __restrict__ v_in, float* __restrict__ v_out,
    const float* __restrict__ pos,
    const int* __restrict__ rowStart,
    const int* __restrict__ srcS, const int* __restrict__ tgtS, const int* __restrict__ eaS,
    const unsigned short* __restrict__ bondbf,
    const unsigned short* __restrict__ wp, const float* __restrict__ bg,
    const float* __restrict__ wu, const float* __restrict__ bu,
    const float* __restrict__ lng, const float* __restrict__ lnb,
    int do_ln, float cutoff)
{
    __shared__ float accL[G * ACCW];
    __shared__ unsigned short tileRB[64 * RBW];
    __shared__ float wvS[64 * WVW];
    __shared__ int srcT[64];
    __shared__ int tgtT[64];

    const int tid  = threadIdx.x;
    const int lane = tid & 63;
    const int wid  = tid >> 6;          // wave 0..3
    const int l15  = lane & 15;
    const int l4   = lane >> 4;
    const int n0   = blockIdx.x * G;

    // ---- B fragments (whole W) into VGPRs, once per block ----
    bf16x8 Bfrag[5][6];
    #pragma unroll
    for (int kk = 0; kk < 5; ++kk)
        #pragma unroll
        for (int nt = 0; nt < 6; ++nt) {
            size_t elem = ((size_t)(kk * 4 + l4) * Hdim + nt * 16 + l15) * 8;
            Bfrag[kk][nt] = *reinterpret_cast<const bf16x8*>(wp + elem);
        }
    float bias[6];
    #pragma unroll
    for (int nt = 0; nt < 6; ++nt) bias[nt] = bg[nt * 16 + l15];

    for (int i = tid; i < G * ACCW; i += 256) accL[i] = 0.0f;
    for (int i = tid; i < 64; i += 256) { srcT[i] = n0; tgtT[i] = n0; }
    __syncthreads();

    const int e0 = rowStart[n0];
    const int e1 = rowStart[n0 + G];
    const int ntile = (e1 - e0 + 63) >> 6;

    for (int tI = 0; tI < ntile; ++tI) {
        const int base = e0 + (tI << 6);

        // ---- staging: 4 threads per edge ----
        {
            int el = tid >> 2, q = tid & 3;
            int e = base + el;
            if (e < e1) {
                int s = srcS[e], t = tgtS[e];
                if (q == 3) { srcT[el] = s; tgtT[el] = t; }
                if (q < 2) {
                    float rx = pos[3*t]-pos[3*s], ry = pos[3*t+1]-pos[3*s+1], rz = pos[3*t+2]-pos[3*s+2];
                    float d = sqrtf(fmaxf(rx*rx + ry*ry + rz*rz, 1e-6f));
                    float env = (d < cutoff) ? 0.5f * (__cosf(3.14159265358979f * d / cutoff) + 1.0f) : 0.0f;
                    float invw = (float)RDdim / cutoff;
                    unsigned int pk[4];
                    #pragma unroll
                    for (int i2 = 0; i2 < 4; ++i2) {
                        float c0 = cutoff * ((float)(q*8 + i2*2)     / 15.0f);
                        float c1 = cutoff * ((float)(q*8 + i2*2 + 1) / 15.0f);
                        float t0 = (d - c0) * invw, t1 = (d - c1) * invw;
                        unsigned short b0 = f2bf(__expf(-0.5f * t0 * t0) * env);
                        unsigned short b1 = f2bf(__expf(-0.5f * t1 * t1) * env);
                        pk[i2] = (unsigned int)b0 | ((unsigned int)b1 << 16);
                    }
                    *reinterpret_cast<uint4*>(&tileRB[el * RBW + q * 8]) =
                        make_uint4(pk[0], pk[1], pk[2], pk[3]);
                } else {
                    int ea = eaS[e];
                    const uint4 bv = *reinterpret_cast<const uint4*>(bondbf + ea * EDdim + (q - 2) * 8);
                    *reinterpret_cast<uint4*>(&tileRB[el * RBW + 16 + (q - 2) * 8]) = bv;
                }
            } else if (q == 3) {
                srcT[el] = n0; tgtT[el] = n0;
            }
        }
        __syncthreads();

        // ---- MFMA: this wave's 16-edge stripe x 96 cols x K=160 ----
        f32x4 acc[6];
        #pragma unroll
        for (int nt = 0; nt < 6; ++nt) acc[nt] = (f32x4){0.f, 0.f, 0.f, 0.f};

        {
            const int arow = wid * 16 + l15;
            const int nsrc = srcT[arow];
            const int ntgt = tgtT[arow];
            #pragma unroll
            for (int kk = 0; kk < 5; ++kk) {
                bf16x8 a;
                if (kk < 2)
                    a = *reinterpret_cast<const bf16x8*>(sbf_in + (size_t)nsrc * Sdim + kk * 32 + l4 * 8);
                else if (kk < 4)
                    a = *reinterpret_cast<const bf16x8*>(sbf_in + (size_t)ntgt * Sdim + (kk - 2) * 32 + l4 * 8);
                else
                    a = *reinterpret_cast<const bf16x8*>(&tileRB[arow * RBW + l4 * 8]);
                #pragma unroll
                for (int nt = 0; nt < 6; ++nt)
                    acc[nt] = __builtin_amdgcn_mfma_f32_16x16x32_bf16(a, Bfrag[kk][nt], acc[nt], 0, 0, 0);
            }
        }

        // ---- epilogue: bias + silu; ms -> LDS atomics; wv -> staging ----
        {
            const int rowbase = wid * 16 + l4 * 4;
            int  tg[4]; bool vld[4];
            #pragma unroll
            for (int r = 0; r < 4; ++r) {
                int er = rowbase + r;
                tg[r]  = tgtT[er];
                vld[r] = (base + er) < e1;
            }
            #pragma unroll
            for (int nt = 0; nt < 6; ++nt) {
                #pragma unroll
                for (int r = 0; r < 4; ++r) {
                    float h = silu_f(acc[nt][r] + bias[nt]);
                    int er = rowbase + r;
                    if (nt < 4) {
                        if (vld[r])
                            atomicAdd(&accL[(tg[r] - n0) * ACCW + nt * 16 + l15], h);
                    } else {
                        wvS[er * WVW + (nt - 4) * 16 + l15] = h;
                    }
                }
            }
        }
        __syncthreads();

        // ---- vm phase: 4 threads per edge, 12 outputs each ----
        {
            int el = tid >> 2, q = tid & 3;
            int e = base + el;
            if (e < e1) {
                int s = srcT[el], t = tgtT[el];
                float rx = pos[3*t]-pos[3*s], ry = pos[3*t+1]-pos[3*s+1], rz = pos[3*t+2]-pos[3*s+2];
                float d = sqrtf(fmaxf(rx*rx + ry*ry + rz*rz, 1e-6f));
                float invd = 1.0f / d;
                float rnx = rx*invd, rny = ry*invd, rnz = rz*invd;
                float* al = &accL[(t - n0) * ACCW + Sdim];
                #pragma unroll
                for (int m12 = 0; m12 < 12; ++m12) {
                    int gi = q * 12 + m12;
                    int dd = gi >> 4, mm = gi & 15;
                    float rn_d = (dd == 0) ? rnx : ((dd == 1) ? rny : rnz);
                    float wv1 = wvS[el * WVW + mm];
                    float wv2 = wvS[el * WVW + 16 + mm];
                    float vv  = v_in[(size_t)s * NVdim + dd * Vdim + mm];
                    atomicAdd(al + dd * Vdim + mm, fmaf(vv, wv1, rn_d * wv2));
                }
            }
        }
        __syncthreads();
    }

    // ---- phase 2: node updates ----
    const int j = tid & 63;
    const int w = tid >> 6;
    #pragma unroll 2
    for (int p = 0; p < G / 4; ++p) {
        int ln_  = w + p * 4;
        int node = n0 + ln_;
        float cntn = (float)(rowStart[node + 1] - rowStart[node]);
        float ic = 1.0f / fmaxf(cntn, 1.0f);
        const float* al = &accL[ln_ * ACCW];
        float dot = 0.0f;
        #pragma unroll 8
        for (int i = 0; i < Sdim; ++i) dot = fmaf(al[i], wu[i * Sdim + j], dot);
        float sn = s_in[(size_t)node * Sdim + j] + silu_f(fmaf(dot, ic, bu[j]));
        if (do_ln) {
            float m = sn;
            #pragma unroll
            for (int off = 32; off >= 1; off >>= 1) m += __shfl_xor(m, off);
            m *= (1.0f / 64.0f);
            float dv = sn - m;
            float var = dv * dv;
            #pragma unroll
            for (int off = 32; off >= 1; off >>= 1) var += __shfl_xor(var, off);
            var *= (1.0f / 64.0f);
            sn = dv * rsqrtf(var + 1e-5f) * lng[j] + lnb[j];
        }
        s_out[(size_t)node * Sdim + j]  = sn;
        sbf_out[(size_t)node * Sdim + j] = f2bf(sn);
    }
    for (int idx = tid; idx < G * NVdim; idx += 256) {
        int ln_ = idx / NVdim, m = idx - ln_ * NVdim;
        int node = n0 + ln_;
        float cntn = (float)(rowStart[node + 1] - rowStart[node]);
        float ic = 1.0f / fmaxf(cntn, 1.0f);
        v_out[(size_t)node * NVdim + m] =
            v_in[(size_t)node * NVdim + m] + accL[ln_ * ACCW + Sdim + m] * ic;
    }
}

// ---------------------------------------------------------------------------
// Head
// ---------------------------------------------------------------------------
__global__ __launch_bounds__(64) void head1_kernel(
    const float* __restrict__ sfeat, const float* __restrict__ vfeat,
    const float* __restrict__ wd, const float* __restrict__ wo,
    float* __restrict__ dsc, float* __restrict__ out)
{
    int node = blockIdx.x, j = threadIdx.x;
    float val = silu_f(sfeat[(size_t)node * Sdim + j]) * wd[j];
    #pragma unroll
    for (int off = 32; off >= 1; off >>= 1) val += __shfl_xor(val, off);
    if (j == 0) dsc[node] = val;
    if (j < 3) {
        float a = 0.0f;
        #pragma unroll
        for (int m = 0; m < Vdim; ++m)
            a += vfeat[(size_t)node * NVdim + j * Vdim + m] * wo[m];
        out[(size_t)node * 3 + j] = a;
    }
}

__global__ __launch_bounds__(256) void head2_kernel(
    const float* __restrict__ dsc, const float* __restrict__ pos,
    const int* __restrict__ eig, float* __restrict__ out, int E)
{
    int e = blockIdx.x * 256 + threadIdx.x;
    if (e >= E) return;
    int src = eig[e], tgt = eig[E + e];
    float w = dsc[src] + dsc[tgt];
    atomicAdd(out + 3 * tgt + 0, w * (pos[3*src+0] - pos[3*tgt+0]));
    atomicAdd(out + 3 * tgt + 1, w * (pos[3*src+1] - pos[3*tgt+1]));
    atomicAdd(out + 3 * tgt + 2, w * (pos[3*src+2] - pos[3*tgt+2]));
}

// ---------------------------------------------------------------------------
extern "C" void kernel_launch(void* const* d_in, const int* in_sizes, int n_in,
                              void* d_out, int out_size, void* d_ws, size_t ws_size,
                              hipStream_t stream)
{
    const int*   x     = (const int*)d_in[0];
    const float* t     = (const float*)d_in[1];
    const float* pos   = (const float*)d_in[2];
    const int*   eil   = (const int*)d_in[3];
    const int*   eig   = (const int*)d_in[4];
    const int*   eal   = (const int*)d_in[5];
    const int*   eag   = (const int*)d_in[6];
    const int*   batch = (const int*)d_in[7];
    const float* aemb  = (const float*)d_in[8];
    const float* bemb  = (const float*)d_in[9];
    const float* t_w1  = (const float*)d_in[10];
    const float* t_b1  = (const float*)d_in[11];
    const float* t_w2  = (const float*)d_in[12];
    const float* t_b2  = (const float*)d_in[13];
    const float* wm    = (const float*)d_in[14];
    const float* bm    = (const float*)d_in[15];
    const float* wu    = (const float*)d_in[16];
    const float* bu    = (const float*)d_in[17];
    const float* lng   = (const float*)d_in[18];
    const float* lnb   = (const float*)d_in[19];
    const float* wd    = (const float*)d_in[20];
    const float* wo    = (const float*)d_in[21];

    const int n  = in_sizes[7];          // 16384
    const int B  = in_sizes[1] / TDdim;  // 64
    const int EL = in_sizes[3] / 2;      // 131072
    const int EG = in_sizes[4] / 2;      // 262144

    // ---- workspace layout ----
    char* p = (char*)d_ws;
    auto alignup = [](char* q) { return (char*)(((size_t)q + 15) & ~(size_t)15); };

    float* temb = (float*)p;                 p += (size_t)B * Sdim * 4;
    float* dsc  = (float*)p;                 p += (size_t)n * 4;
    float* sA   = (float*)p;                 p += (size_t)n * Sdim * 4;
    float* sB   = (float*)p;                 p += (size_t)n * Sdim * 4;
    float* vA   = (float*)p;                 p += (size_t)n * NVdim * 4;
    float* vB   = (float*)p;                 p += (size_t)n * NVdim * 4;
    int* counts = (int*)p;                   p += (size_t)n * 4;
    int* cursor = (int*)p;                   p += (size_t)n * 4;
    int* rsL    = (int*)p;                   p += (size_t)(n + 4) * 4;
    int* srcL   = (int*)p;                   p += (size_t)EL * 4;
    int* tgtL   = (int*)p;                   p += (size_t)EL * 4;
    int* eaL    = (int*)p;                   p += (size_t)EL * 4;
    int* rsG    = (int*)p;                   p += (size_t)(n + 4) * 4;
    int* srcG   = (int*)p;                   p += (size_t)EG * 4;
    int* tgtG   = (int*)p;                   p += (size_t)EG * 4;
    int* eaG    = (int*)p;                   p += (size_t)EG * 4;
    p = alignup(p);
    unsigned short* wp     = (unsigned short*)p;  p += (size_t)10 * FINdim * Hdim * 2;
    p = alignup(p);
    unsigned short* bondbf = (unsigned short*)p;  p += 96 * 2;
    p = alignup(p);
    unsigned short* sbfA   = (unsigned short*)p;  p += (size_t)n * Sdim * 2;
    unsigned short* sbfB   = (unsigned short*)p;  p += (size_t)n * Sdim * 2;

    float* out = (float*)d_out;

    // ---- precompute packed weights + init ----
    pack_kernel<<<(10 * FINdim * Hdim + 80 + 255) / 256, 256, 0, stream>>>(wm, bemb, wp, bondbf);
    temb_kernel<<<B, 64, 0, stream>>>(t, t_w1, t_b1, t_w2, t_b2, temb);
    node_init_kernel<<<(n * Sdim + 255) / 256, 256, 0, stream>>>(x, batch, aemb, temb, sA, sbfA, n);
    hipMemsetAsync(vA, 0, (size_t)n * NVdim * sizeof(float), stream);

    // ---- CSR build ----
    hipMemsetAsync(counts, 0, (size_t)n * sizeof(int), stream);
    count_kernel<<<(EL + 255) / 256, 256, 0, stream>>>(eil, EL, counts);
    scan_kernel<<<1, 256, 0, stream>>>(counts, n, rsL, cursor);
    scatter_kernel<<<(EL + 255) / 256, 256, 0, stream>>>(eil, eal, EL, cursor, srcL, tgtL, eaL);

    hipMemsetAsync(counts, 0, (size_t)n * sizeof(int), stream);
    count_kernel<<<(EG + 255) / 256, 256, 0, stream>>>(eig, EG, counts);
    scan_kernel<<<1, 256, 0, stream>>>(counts, n, rsG, cursor);
    scatter_kernel<<<(EG + 255) / 256, 256, 0, stream>>>(eig, eag, EG, cursor, srcG, tgtG, eaG);

    // ---- layers ----
    float* s_cur = sA; float* s_nxt = sB;
    float* v_cur = vA; float* v_nxt = vB;
    unsigned short* sb_cur = sbfA; unsigned short* sb_nxt = sbfB;
    constexpr int G = 32;

    for (int l = 0; l < NLAYER; ++l) {
        for (int k = 0; k < 2; ++k) {
            int ls = l * 2 + k;
            const unsigned short* wpk = wp + (size_t)ls * FINdim * Hdim;
            const float* bgk = bm + (size_t)ls * Hdim;
            const float* wuk = wu + (size_t)ls * Sdim * Sdim;
            const float* buk = bu + (size_t)ls * Sdim;
            if (k == 0) {
                fused_layer_mfma<G><<<n / G, 256, 0, stream>>>(
                    s_cur, s_nxt, sb_cur, sb_nxt, v_cur, v_nxt, pos,
                    rsL, srcL, tgtL, eaL, bondbf, wpk, bgk, wuk, buk,
                    lng + (size_t)l * Sdim, lnb + (size_t)l * Sdim, 0, 3.0f);
            } else {
                fused_layer_mfma<G><<<n / G, 256, 0, stream>>>(
                    s_cur, s_nxt, sb_cur, sb_nxt, v_cur, v_nxt, pos,
                    rsG, srcG, tgtG, eaG, bondbf, wpk, bgk, wuk, buk,
                    lng + (size_t)l * Sdim, lnb + (size_t)l * Sdim, 1, 10.0f);
            }
            float* tmp = s_cur; s_cur = s_nxt; s_nxt = tmp;
            tmp = v_cur; v_cur = v_nxt; v_nxt = tmp;
            unsigned short* tb = sb_cur; sb_cur = sb_nxt; sb_nxt = tb;
        }
    }

    head1_kernel<<<n, 64, 0, stream>>>(s_cur, v_cur, wd, wo, dsc, out);
    head2_kernel<<<(EG + 255) / 256, 256, 0, stream>>>(dsc, pos, eig, out, EG);
}

// Round 5
// 1115.729 us; speedup vs baseline: 11.3681x; 1.5745x over previous
//
#include <hip/hip_runtime.h>
#include <math.h>

#define Sdim 64
#define Vdim 16
#define NLAYER 5
#define EDdim 16
#define RDdim 16
#define TDdim 64
#define FINdim 160   // 2*S + RD + ED
#define Hdim 96      // S + 2*V
#define NVdim 48     // 3*V
#define ACCW 113     // 64 ms + 48 vm + pad (odd stride)
#define RBW 40       // tileRB row stride in ushorts (32 data + 8 pad)
#define HPAD 100     // hS row stride in floats (96 + 4)

typedef __attribute__((ext_vector_type(8))) short bf16x8;
typedef __attribute__((ext_vector_type(4))) float f32x4;

__device__ __forceinline__ float silu_f(float x) {
    return x / (1.0f + __expf(-x));
}

__device__ __forceinline__ unsigned short f2bf(float x) {
    union { float f; unsigned u; } v; v.f = x;
    unsigned r = v.u + 0x7fffu + ((v.u >> 16) & 1u);
    return (unsigned short)(r >> 16);
}

// ---------------------------------------------------------------------------
// Pack W (10 layer-sets, [160][96] fp32) into MFMA B-fragment bf16 layout.
// ---------------------------------------------------------------------------
__global__ __launch_bounds__(256) void pack_kernel(
    const float* __restrict__ wm, const float* __restrict__ bemb,
    unsigned short* __restrict__ wp, unsigned short* __restrict__ bondbf)
{
    int idx = blockIdx.x * 256 + threadIdx.x;
    if (idx < 10 * FINdim * Hdim) {
        int ls = idx / (FINdim * Hdim), rem = idx % (FINdim * Hdim);
        int k = rem / Hdim, c = rem % Hdim;
        wp[(size_t)ls * FINdim * Hdim + ((size_t)(k >> 3) * Hdim + c) * 8 + (k & 7)] =
            f2bf(wm[idx]);
    } else if (idx < 10 * FINdim * Hdim + 80) {
        int i = idx - 10 * FINdim * Hdim;
        bondbf[i] = f2bf(bemb[i]);
    }
}

// ---------------------------------------------------------------------------
__global__ __launch_bounds__(64) void temb_kernel(
    const float* __restrict__ t, const float* __restrict__ w1, const float* __restrict__ b1,
    const float* __restrict__ w2, const float* __restrict__ b2, float* __restrict__ temb)
{
    int b = blockIdx.x, j = threadIdx.x;
    __shared__ float row[TDdim];
    __shared__ float hid[TDdim];
    row[j] = t[b * TDdim + j];
    __syncthreads();
    float h = b1[j];
    #pragma unroll 8
    for (int i = 0; i < TDdim; ++i) h = fmaf(row[i], w1[i * TDdim + j], h);
    h = silu_f(h);
    hid[j] = h;
    __syncthreads();
    float o = b2[j];
    #pragma unroll 8
    for (int i = 0; i < TDdim; ++i) o = fmaf(hid[i], w2[i * Sdim + j], o);
    temb[b * Sdim + j] = silu_f(o);
}

// ---------------------------------------------------------------------------
__global__ __launch_bounds__(256) void node_init_kernel(
    const int* __restrict__ x, const int* __restrict__ batch,
    const float* __restrict__ aemb, const float* __restrict__ temb,
    float* __restrict__ sfeat, unsigned short* __restrict__ sbf, int n)
{
    int idx = blockIdx.x * 256 + threadIdx.x;
    if (idx >= n * Sdim) return;
    int node = idx >> 6, j = idx & 63;
    int x0 = x[node * 3 + 0], x1 = x[node * 3 + 1], x2 = x[node * 3 + 2];
    float v = aemb[(0 * 16 + x0) * Sdim + j] + aemb[(16 + x1) * Sdim + j]
            + aemb[(32 + x2) * Sdim + j] + temb[batch[node] * Sdim + j];
    sfeat[idx] = v;
    sbf[idx]   = f2bf(v);
}

// ---------------------------------------------------------------------------
// CSR build
// ---------------------------------------------------------------------------
__global__ __launch_bounds__(256) void count_kernel(
    const int* __restrict__ ei, int E, int* __restrict__ counts)
{
    int e = blockIdx.x * 256 + threadIdx.x;
    if (e >= E) return;
    atomicAdd(&counts[ei[E + e]], 1);
}

__global__ __launch_bounds__(256) void scan_kernel(
    const int* __restrict__ counts, int n,
    int* __restrict__ rowStart, int* __restrict__ cursor)
{
    __shared__ int partial[256];
    __shared__ int spart[257];
    int t = threadIdx.x;
    int chunk = n / 256;
    int base = t * chunk;
    int s = 0;
    for (int i = 0; i < chunk; ++i) s += counts[base + i];
    partial[t] = s;
    __syncthreads();
    if (t == 0) {
        int a = 0;
        for (int i = 0; i < 256; ++i) { spart[i] = a; a += partial[i]; }
        spart[256] = a;
    }
    __syncthreads();
    int off = spart[t];
    for (int i = 0; i < chunk; ++i) {
        rowStart[base + i] = off;
        cursor[base + i]   = off;
        off += counts[base + i];
    }
    if (t == 255) rowStart[n] = spart[256];
}

__global__ __launch_bounds__(256) void scatter_kernel(
    const int* __restrict__ ei, const int* __restrict__ ea, int E,
    int* __restrict__ cursor,
    int* __restrict__ srcS, int* __restrict__ tgtS, int* __restrict__ eaS)
{
    int e = blockIdx.x * 256 + threadIdx.x;
    if (e >= E) return;
    int tgt = ei[E + e];
    int p = atomicAdd(&cursor[tgt], 1);
    srcS[p] = ei[e];
    tgtS[p] = tgt;
    eaS[p]  = ea[e];
}

// ---------------------------------------------------------------------------
// Fused layer-set kernel: MFMA edge MLP + atomic-free ownership reduction.
// ---------------------------------------------------------------------------
template<int G>
__global__ __launch_bounds__(256, 2) void fused_layer_mfma(
    const float* __restrict__ s_in, float* __restrict__ s_out,
    const unsigned short* __restrict__ sbf_in, unsigned short* __restrict__ sbf_out,
    const float* __restrict__ v_in, float* __restrict__ v_out,
    const float* __restrict__ pos,
    const int* __restrict__ rowStart,
    const int* __restrict__ srcS, const int* __restrict__ tgtS, const int* __restrict__ eaS,
    const unsigned short* __restrict__ bondbf,
    const unsigned short* __restrict__ wp, const float* __restrict__ bg,
    const float* __restrict__ wu, const float* __restrict__ bu,
    const float* __restrict__ lng, const float* __restrict__ lnb,
    int do_ln, float cutoff)
{
    __shared__ float accL[G * ACCW];              // per-node accumulators (owner-RMW)
    __shared__ float hS[64 * HPAD];               // per-edge silu'd MLP output
    __shared__ float rnS[64 * 4];                 // per-edge rn.x/y/z
    __shared__ unsigned short tileRB[64 * RBW];   // per-edge rbf+bond bf16
    __shared__ int srcT[64];
    __shared__ int tgtT[64];

    const int tid  = threadIdx.x;
    const int lane = tid & 63;
    const int wid  = tid >> 6;          // wave 0..3
    const int l15  = lane & 15;
    const int l4   = lane >> 4;
    const int n0   = blockIdx.x * G;

    // ---- B fragments (whole W) into VGPRs, once per block ----
    bf16x8 Bfrag[5][6];
    #pragma unroll
    for (int kk = 0; kk < 5; ++kk)
        #pragma unroll
        for (int nt = 0; nt < 6; ++nt) {
            size_t elem = ((size_t)(kk * 4 + l4) * Hdim + nt * 16 + l15) * 8;
            Bfrag[kk][nt] = *reinterpret_cast<const bf16x8*>(wp + elem);
        }
    float bias[6];
    #pragma unroll
    for (int nt = 0; nt < 6; ++nt) bias[nt] = bg[nt * 16 + l15];

    for (int i = tid; i < G * ACCW; i += 256) accL[i] = 0.0f;
    for (int i = tid; i < 64; i += 256) { srcT[i] = n0; tgtT[i] = n0; }
    __syncthreads();

    const int e0 = rowStart[n0];
    const int e1 = rowStart[n0 + G];
    const int ntile = (e1 - e0 + 63) >> 6;

    for (int tI = 0; tI < ntile; ++tI) {
        const int base = e0 + (tI << 6);
        const int nvalid = min(64, e1 - base);

        // ---- staging: 4 threads per edge ----
        {
            int el = tid >> 2, q = tid & 3;
            int e = base + el;
            if (e < e1) {
                int s = srcS[e], t = tgtS[e];
                if (q == 3) {
                    srcT[el] = s; tgtT[el] = t;
                    float rx = pos[3*t]-pos[3*s], ry = pos[3*t+1]-pos[3*s+1], rz = pos[3*t+2]-pos[3*s+2];
                    float d = sqrtf(fmaxf(rx*rx + ry*ry + rz*rz, 1e-6f));
                    float invd = 1.0f / d;
                    *reinterpret_cast<float4*>(&rnS[el * 4]) =
                        make_float4(rx*invd, ry*invd, rz*invd, d);
                } else if (q < 2) {
                    float rx = pos[3*t]-pos[3*s], ry = pos[3*t+1]-pos[3*s+1], rz = pos[3*t+2]-pos[3*s+2];
                    float d = sqrtf(fmaxf(rx*rx + ry*ry + rz*rz, 1e-6f));
                    float env = (d < cutoff) ? 0.5f * (__cosf(3.14159265358979f * d / cutoff) + 1.0f) : 0.0f;
                    float invw = (float)RDdim / cutoff;
                    unsigned int pk[4];
                    #pragma unroll
                    for (int i2 = 0; i2 < 4; ++i2) {
                        float c0 = cutoff * ((float)(q*8 + i2*2)     / 15.0f);
                        float c1 = cutoff * ((float)(q*8 + i2*2 + 1) / 15.0f);
                        float t0 = (d - c0) * invw, t1 = (d - c1) * invw;
                        unsigned short b0 = f2bf(__expf(-0.5f * t0 * t0) * env);
                        unsigned short b1 = f2bf(__expf(-0.5f * t1 * t1) * env);
                        pk[i2] = (unsigned int)b0 | ((unsigned int)b1 << 16);
                    }
                    *reinterpret_cast<uint4*>(&tileRB[el * RBW + q * 8]) =
                        make_uint4(pk[0], pk[1], pk[2], pk[3]);
                } else { // q == 2: bond embedding, 16 bf16
                    int ea = eaS[e];
                    const uint4 b0 = *reinterpret_cast<const uint4*>(bondbf + ea * EDdim);
                    const uint4 b1 = *reinterpret_cast<const uint4*>(bondbf + ea * EDdim + 8);
                    *reinterpret_cast<uint4*>(&tileRB[el * RBW + 16]) = b0;
                    *reinterpret_cast<uint4*>(&tileRB[el * RBW + 24]) = b1;
                }
            } else if (q == 3) {
                srcT[el] = n0; tgtT[el] = n0;
            }
        }
        __syncthreads();

        // ---- MFMA: wave's 16-edge stripe x 96 cols x K=160 ----
        f32x4 acc[6];
        #pragma unroll
        for (int nt = 0; nt < 6; ++nt) acc[nt] = (f32x4){0.f, 0.f, 0.f, 0.f};

        {
            const int arow = wid * 16 + l15;
            const int nsrc = srcT[arow];
            const int ntgt = tgtT[arow];
            #pragma unroll
            for (int kk = 0; kk < 5; ++kk) {
                bf16x8 a;
                if (kk < 2)
                    a = *reinterpret_cast<const bf16x8*>(sbf_in + (size_t)nsrc * Sdim + kk * 32 + l4 * 8);
                else if (kk < 4)
                    a = *reinterpret_cast<const bf16x8*>(sbf_in + (size_t)ntgt * Sdim + (kk - 2) * 32 + l4 * 8);
                else
                    a = *reinterpret_cast<const bf16x8*>(&tileRB[arow * RBW + l4 * 8]);
                #pragma unroll
                for (int nt = 0; nt < 6; ++nt)
                    acc[nt] = __builtin_amdgcn_mfma_f32_16x16x32_bf16(a, Bfrag[kk][nt], acc[nt], 0, 0, 0);
            }
        }

        // ---- epilogue: bias + silu -> hS (plain ds_write, no atomics) ----
        {
            const int rowbase = wid * 16 + l4 * 4;
            #pragma unroll
            for (int nt = 0; nt < 6; ++nt) {
                #pragma unroll
                for (int r = 0; r < 4; ++r) {
                    hS[(rowbase + r) * HPAD + nt * 16 + l15] = silu_f(acc[nt][r] + bias[nt]);
                }
            }
        }
        __syncthreads();

        // ---- ownership reduce: wave owns nodes ndFirst+wid, +4, ... ----
        {
            const int ndFirst = tgtT[0];
            const int ndLast  = tgtT[nvalid - 1];
            for (int nd = ndFirst + wid; nd <= ndLast; nd += 4) {
                int lo = rowStart[nd] - base;     if (lo < 0) lo = 0;
                int hi = rowStart[nd + 1] - base; if (hi > nvalid) hi = nvalid;
                if (lo >= hi) continue;
                float msum = 0.0f;
                float vsum = 0.0f;
                const int dd = l4 & 3, m = l15;   // for lane<48: dd = lane>>4
                for (int e = lo; e < hi; ++e) {
                    msum += hS[e * HPAD + lane];
                    if (lane < 48) {
                        float wv1 = hS[e * HPAD + 64 + m];
                        float wv2 = hS[e * HPAD + 80 + m];
                        float rn_d = rnS[e * 4 + dd];
                        float vv = v_in[(size_t)srcT[e] * NVdim + lane];
                        vsum += fmaf(vv, wv1, rn_d * wv2);
                    }
                }
                accL[(nd - n0) * ACCW + lane] += msum;
                if (lane < 48)
                    accL[(nd - n0) * ACCW + Sdim + lane] += vsum;
            }
        }
        __syncthreads();
    }

    // ---- phase 2: node updates ----
    const int j = tid & 63;
    const int w = tid >> 6;
    #pragma unroll 2
    for (int p = 0; p < G / 4; ++p) {
        int ln_  = w + p * 4;
        int node = n0 + ln_;
        float cntn = (float)(rowStart[node + 1] - rowStart[node]);
        float ic = 1.0f / fmaxf(cntn, 1.0f);
        const float* al = &accL[ln_ * ACCW];
        float dot = 0.0f;
        #pragma unroll 8
        for (int i = 0; i < Sdim; ++i) dot = fmaf(al[i], wu[i * Sdim + j], dot);
        float sn = s_in[(size_t)node * Sdim + j] + silu_f(fmaf(dot, ic, bu[j]));
        if (do_ln) {
            float m = sn;
            #pragma unroll
            for (int off = 32; off >= 1; off >>= 1) m += __shfl_xor(m, off);
            m *= (1.0f / 64.0f);
            float dv = sn - m;
            float var = dv * dv;
            #pragma unroll
            for (int off = 32; off >= 1; off >>= 1) var += __shfl_xor(var, off);
            var *= (1.0f / 64.0f);
            sn = dv * rsqrtf(var + 1e-5f) * lng[j] + lnb[j];
        }
        s_out[(size_t)node * Sdim + j]  = sn;
        sbf_out[(size_t)node * Sdim + j] = f2bf(sn);
    }
    for (int idx = tid; idx < G * NVdim; idx += 256) {
        int ln_ = idx / NVdim, m = idx - ln_ * NVdim;
        int node = n0 + ln_;
        float cntn = (float)(rowStart[node + 1] - rowStart[node]);
        float ic = 1.0f / fmaxf(cntn, 1.0f);
        v_out[(size_t)node * NVdim + m] =
            v_in[(size_t)node * NVdim + m] + accL[ln_ * ACCW + Sdim + m] * ic;
    }
}

// ---------------------------------------------------------------------------
// Head
// ---------------------------------------------------------------------------
__global__ __launch_bounds__(64) void head1_kernel(
    const float* __restrict__ sfeat, const float* __restrict__ vfeat,
    const float* __restrict__ wd, const float* __restrict__ wo,
    float* __restrict__ dsc, float* __restrict__ out)
{
    int node = blockIdx.x, j = threadIdx.x;
    float val = silu_f(sfeat[(size_t)node * Sdim + j]) * wd[j];
    #pragma unroll
    for (int off = 32; off >= 1; off >>= 1) val += __shfl_xor(val, off);
    if (j == 0) dsc[node] = val;
    if (j < 3) {
        float a = 0.0f;
        #pragma unroll
        for (int m = 0; m < Vdim; ++m)
            a += vfeat[(size_t)node * NVdim + j * Vdim + m] * wo[m];
        out[(size_t)node * 3 + j] = a;
    }
}

__global__ __launch_bounds__(256) void head2_kernel(
    const float* __restrict__ dsc, const float* __restrict__ pos,
    const int* __restrict__ eig, float* __restrict__ out, int E)
{
    int e = blockIdx.x * 256 + threadIdx.x;
    if (e >= E) return;
    int src = eig[e], tgt = eig[E + e];
    float w = dsc[src] + dsc[tgt];
    atomicAdd(out + 3 * tgt + 0, w * (pos[3*src+0] - pos[3*tgt+0]));
    atomicAdd(out + 3 * tgt + 1, w * (pos[3*src+1] - pos[3*tgt+1]));
    atomicAdd(out + 3 * tgt + 2, w * (pos[3*src+2] - pos[3*tgt+2]));
}

// ---------------------------------------------------------------------------
extern "C" void kernel_launch(void* const* d_in, const int* in_sizes, int n_in,
                              void* d_out, int out_size, void* d_ws, size_t ws_size,
                              hipStream_t stream)
{
    const int*   x     = (const int*)d_in[0];
    const float* t     = (const float*)d_in[1];
    const float* pos   = (const float*)d_in[2];
    const int*   eil   = (const int*)d_in[3];
    const int*   eig   = (const int*)d_in[4];
    const int*   eal   = (const int*)d_in[5];
    const int*   eag   = (const int*)d_in[6];
    const int*   batch = (const int*)d_in[7];
    const float* aemb  = (const float*)d_in[8];
    const float* bemb  = (const float*)d_in[9];
    const float* t_w1  = (const float*)d_in[10];
    const float* t_b1  = (const float*)d_in[11];
    const float* t_w2  = (const float*)d_in[12];
    const float* t_b2  = (const float*)d_in[13];
    const float* wm    = (const float*)d_in[14];
    const float* bm    = (const float*)d_in[15];
    const float* wu    = (const float*)d_in[16];
    const float* bu    = (const float*)d_in[17];
    const float* lng   = (const float*)d_in[18];
    const float* lnb   = (const float*)d_in[19];
    const float* wd    = (const float*)d_in[20];
    const float* wo    = (const float*)d_in[21];

    const int n  = in_sizes[7];          // 16384
    const int B  = in_sizes[1] / TDdim;  // 64
    const int EL = in_sizes[3] / 2;      // 131072
    const int EG = in_sizes[4] / 2;      // 262144

    // ---- workspace layout ----
    char* p = (char*)d_ws;
    auto alignup = [](char* q) { return (char*)(((size_t)q + 15) & ~(size_t)15); };

    float* temb = (float*)p;                 p += (size_t)B * Sdim * 4;
    float* dsc  = (float*)p;                 p += (size_t)n * 4;
    float* sA   = (float*)p;                 p += (size_t)n * Sdim * 4;
    float* sB   = (float*)p;                 p += (size_t)n * Sdim * 4;
    float* vA   = (float*)p;                 p += (size_t)n * NVdim * 4;
    float* vB   = (float*)p;                 p += (size_t)n * NVdim * 4;
    int* counts = (int*)p;                   p += (size_t)n * 4;
    int* cursor = (int*)p;                   p += (size_t)n * 4;
    int* rsL    = (int*)p;                   p += (size_t)(n + 4) * 4;
    int* srcL   = (int*)p;                   p += (size_t)EL * 4;
    int* tgtL   = (int*)p;                   p += (size_t)EL * 4;
    int* eaL    = (int*)p;                   p += (size_t)EL * 4;
    int* rsG    = (int*)p;                   p += (size_t)(n + 4) * 4;
    int* srcG   = (int*)p;                   p += (size_t)EG * 4;
    int* tgtG   = (int*)p;                   p += (size_t)EG * 4;
    int* eaG    = (int*)p;                   p += (size_t)EG * 4;
    p = alignup(p);
    unsigned short* wp     = (unsigned short*)p;  p += (size_t)10 * FINdim * Hdim * 2;
    p = alignup(p);
    unsigned short* bondbf = (unsigned short*)p;  p += 96 * 2;
    p = alignup(p);
    unsigned short* sbfA   = (unsigned short*)p;  p += (size_t)n * Sdim * 2;
    unsigned short* sbfB   = (unsigned short*)p;  p += (size_t)n * Sdim * 2;

    float* out = (float*)d_out;

    // ---- precompute packed weights + init ----
    pack_kernel<<<(10 * FINdim * Hdim + 80 + 255) / 256, 256, 0, stream>>>(wm, bemb, wp, bondbf);
    temb_kernel<<<B, 64, 0, stream>>>(t, t_w1, t_b1, t_w2, t_b2, temb);
    node_init_kernel<<<(n * Sdim + 255) / 256, 256, 0, stream>>>(x, batch, aemb, temb, sA, sbfA, n);
    hipMemsetAsync(vA, 0, (size_t)n * NVdim * sizeof(float), stream);

    // ---- CSR build ----
    hipMemsetAsync(counts, 0, (size_t)n * sizeof(int), stream);
    count_kernel<<<(EL + 255) / 256, 256, 0, stream>>>(eil, EL, counts);
    scan_kernel<<<1, 256, 0, stream>>>(counts, n, rsL, cursor);
    scatter_kernel<<<(EL + 255) / 256, 256, 0, stream>>>(eil, eal, EL, cursor, srcL, tgtL, eaL);

    hipMemsetAsync(counts, 0, (size_t)n * sizeof(int), stream);
    count_kernel<<<(EG + 255) / 256, 256, 0, stream>>>(eig, EG, counts);
    scan_kernel<<<1, 256, 0, stream>>>(counts, n, rsG, cursor);
    scatter_kernel<<<(EG + 255) / 256, 256, 0, stream>>>(eig, eag, EG, cursor, srcG, tgtG, eaG);

    // ---- layers ----
    float* s_cur = sA; float* s_nxt = sB;
    float* v_cur = vA; float* v_nxt = vB;
    unsigned short* sb_cur = sbfA; unsigned short* sb_nxt = sbfB;
    constexpr int G = 32;

    for (int l = 0; l < NLAYER; ++l) {
        for (int k = 0; k < 2; ++k) {
            int ls = l * 2 + k;
            const unsigned short* wpk = wp + (size_t)ls * FINdim * Hdim;
            const float* bgk = bm + (size_t)ls * Hdim;
            const float* wuk = wu + (size_t)ls * Sdim * Sdim;
            const float* buk = bu + (size_t)ls * Sdim;
            if (k == 0) {
                fused_layer_mfma<G><<<n / G, 256, 0, stream>>>(
                    s_cur, s_nxt, sb_cur, sb_nxt, v_cur, v_nxt, pos,
                    rsL, srcL, tgtL, eaL, bondbf, wpk, bgk, wuk, buk,
                    lng + (size_t)l * Sdim, lnb + (size_t)l * Sdim, 0, 3.0f);
            } else {
                fused_layer_mfma<G><<<n / G, 256, 0, stream>>>(
                    s_cur, s_nxt, sb_cur, sb_nxt, v_cur, v_nxt, pos,
                    rsG, srcG, tgtG, eaG, bondbf, wpk, bgk, wuk, buk,
                    lng + (size_t)l * Sdim, lnb + (size_t)l * Sdim, 1, 10.0f);
            }
            float* tmp = s_cur; s_cur = s_nxt; s_nxt = tmp;
            tmp = v_cur; v_cur = v_nxt; v_nxt = tmp;
            unsigned short* tb = sb_cur; sb_cur = sb_nxt; sb_nxt = tb;
        }
    }

    head1_kernel<<<n, 64, 0, stream>>>(s_cur, v_cur, wd, wo, dsc, out);
    head2_kernel<<<(EG + 255) / 256, 256, 0, stream>>>(dsc, pos, eig, out, EG);
}

// Round 6
// 809.104 us; speedup vs baseline: 15.6763x; 1.3790x over previous
//
#include <hip/hip_runtime.h>
#include <math.h>

#define Sdim 64
#define Vdim 16
#define NLAYER 5
#define EDdim 16
#define RDdim 16
#define TDdim 64
#define FINdim 160   // 2*S + RD + ED
#define Hdim 96      // S + 2*V
#define NVdim 48     // 3*V
#define ACCW 113     // 64 ms + 48 vm + pad (odd stride)
#define RBW 40       // tileRB row stride in ushorts (32 data + 8 pad)
#define HPAD 98      // hS row stride in floats
#define VSW 52       // vS row stride in floats
#define GW 8         // nodes per wave-block

typedef __attribute__((ext_vector_type(8))) short bf16x8;
typedef __attribute__((ext_vector_type(4))) float f32x4;

__device__ __forceinline__ float silu_f(float x) {
    return x / (1.0f + __expf(-x));
}

__device__ __forceinline__ unsigned short f2bf(float x) {
    union { float f; unsigned u; } v; v.f = x;
    unsigned r = v.u + 0x7fffu + ((v.u >> 16) & 1u);
    return (unsigned short)(r >> 16);
}

// ---------------------------------------------------------------------------
// Pack W (10 layer-sets, [160][96] fp32) into MFMA B-fragment bf16 layout.
// ---------------------------------------------------------------------------
__global__ __launch_bounds__(256) void pack_kernel(
    const float* __restrict__ wm, const float* __restrict__ bemb,
    unsigned short* __restrict__ wp, unsigned short* __restrict__ bondbf)
{
    int idx = blockIdx.x * 256 + threadIdx.x;
    if (idx < 10 * FINdim * Hdim) {
        int ls = idx / (FINdim * Hdim), rem = idx % (FINdim * Hdim);
        int k = rem / Hdim, c = rem % Hdim;
        wp[(size_t)ls * FINdim * Hdim + ((size_t)(k >> 3) * Hdim + c) * 8 + (k & 7)] =
            f2bf(wm[idx]);
    } else if (idx < 10 * FINdim * Hdim + 80) {
        int i = idx - 10 * FINdim * Hdim;
        bondbf[i] = f2bf(bemb[i]);
    }
}

// ---------------------------------------------------------------------------
__global__ __launch_bounds__(64) void temb_kernel(
    const float* __restrict__ t, const float* __restrict__ w1, const float* __restrict__ b1,
    const float* __restrict__ w2, const float* __restrict__ b2, float* __restrict__ temb)
{
    int b = blockIdx.x, j = threadIdx.x;
    __shared__ float row[TDdim];
    __shared__ float hid[TDdim];
    row[j] = t[b * TDdim + j];
    __syncthreads();
    float h = b1[j];
    #pragma unroll 8
    for (int i = 0; i < TDdim; ++i) h = fmaf(row[i], w1[i * TDdim + j], h);
    h = silu_f(h);
    hid[j] = h;
    __syncthreads();
    float o = b2[j];
    #pragma unroll 8
    for (int i = 0; i < TDdim; ++i) o = fmaf(hid[i], w2[i * Sdim + j], o);
    temb[b * Sdim + j] = silu_f(o);
}

// ---------------------------------------------------------------------------
__global__ __launch_bounds__(256) void node_init_kernel(
    const int* __restrict__ x, const int* __restrict__ batch,
    const float* __restrict__ aemb, const float* __restrict__ temb,
    float* __restrict__ sfeat, unsigned short* __restrict__ sbf, int n)
{
    int idx = blockIdx.x * 256 + threadIdx.x;
    if (idx >= n * Sdim) return;
    int node = idx >> 6, j = idx & 63;
    int x0 = x[node * 3 + 0], x1 = x[node * 3 + 1], x2 = x[node * 3 + 2];
    float v = aemb[(0 * 16 + x0) * Sdim + j] + aemb[(16 + x1) * Sdim + j]
            + aemb[(32 + x2) * Sdim + j] + temb[batch[node] * Sdim + j];
    sfeat[idx] = v;
    sbf[idx]   = f2bf(v);
}

// ---------------------------------------------------------------------------
// CSR build
// ---------------------------------------------------------------------------
__global__ __launch_bounds__(256) void count_kernel(
    const int* __restrict__ ei, int E, int* __restrict__ counts)
{
    int e = blockIdx.x * 256 + threadIdx.x;
    if (e >= E) return;
    atomicAdd(&counts[ei[E + e]], 1);
}

__global__ __launch_bounds__(256) void scan_kernel(
    const int* __restrict__ counts, int n,
    int* __restrict__ rowStart, int* __restrict__ cursor)
{
    __shared__ int partial[256];
    __shared__ int spart[257];
    int t = threadIdx.x;
    int chunk = n / 256;
    int base = t * chunk;
    int s = 0;
    for (int i = 0; i < chunk; ++i) s += counts[base + i];
    partial[t] = s;
    __syncthreads();
    if (t == 0) {
        int a = 0;
        for (int i = 0; i < 256; ++i) { spart[i] = a; a += partial[i]; }
        spart[256] = a;
    }
    __syncthreads();
    int off = spart[t];
    for (int i = 0; i < chunk; ++i) {
        rowStart[base + i] = off;
        cursor[base + i]   = off;
        off += counts[base + i];
    }
    if (t == 255) rowStart[n] = spart[256];
}

__global__ __launch_bounds__(256) void scatter_kernel(
    const int* __restrict__ ei, const int* __restrict__ ea, int E,
    int* __restrict__ cursor,
    int* __restrict__ srcS, int* __restrict__ tgtS, int* __restrict__ eaS)
{
    int e = blockIdx.x * 256 + threadIdx.x;
    if (e >= E) return;
    int tgt = ei[E + e];
    int p = atomicAdd(&cursor[tgt], 1);
    srcS[p] = ei[e];
    tgtS[p] = tgt;
    eaS[p]  = ea[e];
}

// ---------------------------------------------------------------------------
// One-time per-edge geometry: rn4[e] = (rn.x, rn.y, rn.z, d);
// rbfb[e][0:16] = rbf bf16, rbfb[e][16:32] = bond_emb bf16.
// Layer-invariant -> hoisted out of the layer loop.
// ---------------------------------------------------------------------------
__global__ __launch_bounds__(256) void geom_kernel(
    const float* __restrict__ pos,
    const int* __restrict__ srcS, const int* __restrict__ tgtS, const int* __restrict__ eaS,
    const unsigned short* __restrict__ bondbf,
    float4* __restrict__ rn4, unsigned short* __restrict__ rbfb,
    int E, float cutoff)
{
    int e = blockIdx.x * 256 + threadIdx.x;
    if (e >= E) return;
    int s = srcS[e], t = tgtS[e];
    float rx = pos[3*t]-pos[3*s], ry = pos[3*t+1]-pos[3*s+1], rz = pos[3*t+2]-pos[3*s+2];
    float d = sqrtf(fmaxf(rx*rx + ry*ry + rz*rz, 1e-6f));
    float invd = 1.0f / d;
    rn4[e] = make_float4(rx*invd, ry*invd, rz*invd, d);
    float env = (d < cutoff) ? 0.5f * (__cosf(3.14159265358979f * d / cutoff) + 1.0f) : 0.0f;
    float invw = (float)RDdim / cutoff;
    unsigned int pk[8];
    #pragma unroll
    for (int i2 = 0; i2 < 8; ++i2) {
        float c0 = cutoff * ((float)(2*i2)     / 15.0f);
        float c1 = cutoff * ((float)(2*i2 + 1) / 15.0f);
        float t0 = (d - c0) * invw, t1 = (d - c1) * invw;
        unsigned short b0 = f2bf(__expf(-0.5f * t0 * t0) * env);
        unsigned short b1 = f2bf(__expf(-0.5f * t1 * t1) * env);
        pk[i2] = (unsigned)b0 | ((unsigned)b1 << 16);
    }
    uint4* o = reinterpret_cast<uint4*>(rbfb + (size_t)e * 32);
    o[0] = make_uint4(pk[0], pk[1], pk[2], pk[3]);
    o[1] = make_uint4(pk[4], pk[5], pk[6], pk[7]);
    int ea = eaS[e];
    const uint4* bp = reinterpret_cast<const uint4*>(bondbf + ea * EDdim);
    o[2] = bp[0];
    o[3] = bp[1];
}

// ---------------------------------------------------------------------------
// Fused layer-set kernel: ONE WAVE per block, ZERO barriers.
// Wave owns nodes [blockIdx*GW, +GW) and all their CSR edges, processed in
// 16-edge chunks: stage (coalesced copies) -> MFMA (W resident in VGPRs) ->
// epilogue (silu -> hS) -> ownership reduce (pure LDS) -> node update.
// Per-wave DS ops are in-order; no __syncthreads anywhere.
// ---------------------------------------------------------------------------
__global__ __launch_bounds__(64) void fused_layer_wave(
    const float* __restrict__ s_in, float* __restrict__ s_out,
    const unsigned short* __restrict__ sbf_in, unsigned short* __restrict__ sbf_out,
    const float* __restrict__ v_in, float* __restrict__ v_out,
    const int* __restrict__ rowStart,
    const int* __restrict__ srcS, const int* __restrict__ tgtS,
    const float4* __restrict__ rn4, const unsigned short* __restrict__ rbfb,
    const unsigned short* __restrict__ wp, const float* __restrict__ bg,
    const float* __restrict__ wu, const float* __restrict__ bu,
    const float* __restrict__ lng, const float* __restrict__ lnb,
    int do_ln)
{
    __shared__ float accL[GW * ACCW];                       // 3616 B
    __shared__ __align__(16) float hS[16 * HPAD];           // 6272 B
    __shared__ __align__(16) float vS[16 * VSW];            // 3328 B
    __shared__ __align__(16) float rnS[16 * 4];             // 256 B
    __shared__ __align__(16) unsigned short tileRB[16 * RBW]; // 1280 B
    __shared__ int srcT[16];
    __shared__ int tgtT[16];
    __shared__ int rsW[GW + 1];

    const int lane = threadIdx.x;
    const int l15 = lane & 15, l4 = lane >> 4;
    const int n0 = blockIdx.x * GW;

    // ---- W as B-fragments, resident for the whole kernel ----
    bf16x8 Bfrag[5][6];
    #pragma unroll
    for (int kk = 0; kk < 5; ++kk)
        #pragma unroll
        for (int nt = 0; nt < 6; ++nt)
            Bfrag[kk][nt] = *reinterpret_cast<const bf16x8*>(
                wp + ((size_t)(kk * 4 + l4) * Hdim + nt * 16 + l15) * 8);
    float bias[6];
    #pragma unroll
    for (int nt = 0; nt < 6; ++nt) bias[nt] = bg[nt * 16 + l15];

    for (int i = lane; i < GW * ACCW; i += 64) accL[i] = 0.0f;
    if (lane <= GW) rsW[lane] = rowStart[n0 + lane];
    if (lane < 16) { srcT[lane] = n0; tgtT[lane] = n0; }

    const int eW0 = rowStart[n0];
    const int eW1 = rowStart[n0 + GW];

    for (int base = eW0; base < eW1; base += 16) {
        // ---- stage: 4 lanes per edge, pure coalesced copies ----
        {
            const int el = lane >> 2, q = lane & 3;
            const int e = base + el;
            if (e < eW1) {
                const int s = srcS[e];
                if (q == 3) {
                    srcT[el] = s;
                    tgtT[el] = tgtS[e];
                    *reinterpret_cast<float4*>(&rnS[el * 4]) = rn4[e];
                }
                *reinterpret_cast<uint4*>(&tileRB[el * RBW + q * 8]) =
                    *reinterpret_cast<const uint4*>(rbfb + (size_t)e * 32 + q * 8);
                const float4* vp = reinterpret_cast<const float4*>(v_in + (size_t)s * NVdim + q * 12);
                float4 v0 = vp[0], v1 = vp[1], v2 = vp[2];
                *reinterpret_cast<float4*>(&vS[el * VSW + q * 12 + 0]) = v0;
                *reinterpret_cast<float4*>(&vS[el * VSW + q * 12 + 4]) = v1;
                *reinterpret_cast<float4*>(&vS[el * VSW + q * 12 + 8]) = v2;
            }
        }

        // ---- MFMA: 16 edges x 96 cols x K=160 ----
        f32x4 acc[6];
        #pragma unroll
        for (int nt = 0; nt < 6; ++nt) acc[nt] = (f32x4){0.f, 0.f, 0.f, 0.f};
        {
            const int nsrc = srcT[l15];
            const int ntgt = tgtT[l15];
            #pragma unroll
            for (int kk = 0; kk < 5; ++kk) {
                bf16x8 a;
                if (kk < 2)
                    a = *reinterpret_cast<const bf16x8*>(sbf_in + (size_t)nsrc * Sdim + kk * 32 + l4 * 8);
                else if (kk < 4)
                    a = *reinterpret_cast<const bf16x8*>(sbf_in + (size_t)ntgt * Sdim + (kk - 2) * 32 + l4 * 8);
                else
                    a = *reinterpret_cast<const bf16x8*>(&tileRB[l15 * RBW + l4 * 8]);
                #pragma unroll
                for (int nt = 0; nt < 6; ++nt)
                    acc[nt] = __builtin_amdgcn_mfma_f32_16x16x32_bf16(a, Bfrag[kk][nt], acc[nt], 0, 0, 0);
            }
        }

        // ---- epilogue: bias + silu -> hS ----
        #pragma unroll
        for (int nt = 0; nt < 6; ++nt) {
            #pragma unroll
            for (int r = 0; r < 4; ++r)
                hS[(l4 * 4 + r) * HPAD + nt * 16 + l15] = silu_f(acc[nt][r] + bias[nt]);
        }

        // ---- ownership reduce: pure LDS, single-owner RMW ----
        {
            const int m = l15, dd = l4;  // for lane<48
            for (int i = 0; i < GW; ++i) {
                int lo = rsW[i] - base;     if (lo < 0) lo = 0;
                int hi = rsW[i + 1] - base; if (hi > 16) hi = 16;
                if (lo >= hi) continue;
                float msum = 0.0f, vsum = 0.0f;
                for (int e2 = lo; e2 < hi; ++e2) {
                    msum += hS[e2 * HPAD + lane];
                    if (lane < NVdim)
                        vsum += vS[e2 * VSW + lane] * hS[e2 * HPAD + 64 + m]
                              + rnS[e2 * 4 + dd]    * hS[e2 * HPAD + 80 + m];
                }
                accL[i * ACCW + lane] += msum;
                if (lane < NVdim) accL[i * ACCW + Sdim + lane] += vsum;
            }
        }
    }

    // ---- node update: wave's own 8 nodes ----
    const int j = lane;
    for (int i = 0; i < GW; ++i) {
        const int node = n0 + i;
        const float cntn = (float)(rsW[i + 1] - rsW[i]);
        const float ic = 1.0f / fmaxf(cntn, 1.0f);
        const float* al = &accL[i * ACCW];
        float dot = 0.0f;
        #pragma unroll 8
        for (int ii = 0; ii < Sdim; ++ii) dot = fmaf(al[ii], wu[ii * Sdim + j], dot);
        float sn = s_in[(size_t)node * Sdim + j] + silu_f(fmaf(dot, ic, bu[j]));
        if (do_ln) {
            float mm = sn;
            #pragma unroll
            for (int off = 32; off >= 1; off >>= 1) mm += __shfl_xor(mm, off);
            mm *= (1.0f / 64.0f);
            float dv = sn - mm;
            float var = dv * dv;
            #pragma unroll
            for (int off = 32; off >= 1; off >>= 1) var += __shfl_xor(var, off);
            var *= (1.0f / 64.0f);
            sn = dv * rsqrtf(var + 1e-5f) * lng[j] + lnb[j];
        }
        s_out[(size_t)node * Sdim + j]   = sn;
        sbf_out[(size_t)node * Sdim + j] = f2bf(sn);
        if (lane < NVdim)
            v_out[(size_t)node * NVdim + lane] =
                v_in[(size_t)node * NVdim + lane] + accL[i * ACCW + Sdim + lane] * ic;
    }
}

// ---------------------------------------------------------------------------
// Head
// ---------------------------------------------------------------------------
__global__ __launch_bounds__(64) void head1_kernel(
    const float* __restrict__ sfeat, const float* __restrict__ vfeat,
    const float* __restrict__ wd, const float* __restrict__ wo,
    float* __restrict__ dsc, float* __restrict__ out)
{
    int node = blockIdx.x, j = threadIdx.x;
    float val = silu_f(sfeat[(size_t)node * Sdim + j]) * wd[j];
    #pragma unroll
    for (int off = 32; off >= 1; off >>= 1) val += __shfl_xor(val, off);
    if (j == 0) dsc[node] = val;
    if (j < 3) {
        float a = 0.0f;
        #pragma unroll
        for (int m = 0; m < Vdim; ++m)
            a += vfeat[(size_t)node * NVdim + j * Vdim + m] * wo[m];
        out[(size_t)node * 3 + j] = a;
    }
}

__global__ __launch_bounds__(256) void head2_kernel(
    const float* __restrict__ dsc, const float* __restrict__ pos,
    const int* __restrict__ eig, float* __restrict__ out, int E)
{
    int e = blockIdx.x * 256 + threadIdx.x;
    if (e >= E) return;
    int src = eig[e], tgt = eig[E + e];
    float w = dsc[src] + dsc[tgt];
    atomicAdd(out + 3 * tgt + 0, w * (pos[3*src+0] - pos[3*tgt+0]));
    atomicAdd(out + 3 * tgt + 1, w * (pos[3*src+1] - pos[3*tgt+1]));
    atomicAdd(out + 3 * tgt + 2, w * (pos[3*src+2] - pos[3*tgt+2]));
}

// ---------------------------------------------------------------------------
extern "C" void kernel_launch(void* const* d_in, const int* in_sizes, int n_in,
                              void* d_out, int out_size, void* d_ws, size_t ws_size,
                              hipStream_t stream)
{
    const int*   x     = (const int*)d_in[0];
    const float* t     = (const float*)d_in[1];
    const float* pos   = (const float*)d_in[2];
    const int*   eil   = (const int*)d_in[3];
    const int*   eig   = (const int*)d_in[4];
    const int*   eal   = (const int*)d_in[5];
    const int*   eag   = (const int*)d_in[6];
    const int*   batch = (const int*)d_in[7];
    const float* aemb  = (const float*)d_in[8];
    const float* bemb  = (const float*)d_in[9];
    const float* t_w1  = (const float*)d_in[10];
    const float* t_b1  = (const float*)d_in[11];
    const float* t_w2  = (const float*)d_in[12];
    const float* t_b2  = (const float*)d_in[13];
    const float* wm    = (const float*)d_in[14];
    const float* bm    = (const float*)d_in[15];
    const float* wu    = (const float*)d_in[16];
    const float* bu    = (const float*)d_in[17];
    const float* lng   = (const float*)d_in[18];
    const float* lnb   = (const float*)d_in[19];
    const float* wd    = (const float*)d_in[20];
    const float* wo    = (const float*)d_in[21];

    const int n  = in_sizes[7];          // 16384
    const int B  = in_sizes[1] / TDdim;  // 64
    const int EL = in_sizes[3] / 2;      // 131072
    const int EG = in_sizes[4] / 2;      // 262144

    // ---- workspace layout ----
    char* p = (char*)d_ws;
    auto alignup = [](char* q) { return (char*)(((size_t)q + 15) & ~(size_t)15); };

    float* temb = (float*)p;                 p += (size_t)B * Sdim * 4;
    float* dsc  = (float*)p;                 p += (size_t)n * 4;
    float* sA   = (float*)p;                 p += (size_t)n * Sdim * 4;
    float* sB   = (float*)p;                 p += (size_t)n * Sdim * 4;
    float* vA   = (float*)p;                 p += (size_t)n * NVdim * 4;
    float* vB   = (float*)p;                 p += (size_t)n * NVdim * 4;
    int* counts = (int*)p;                   p += (size_t)n * 4;
    int* cursor = (int*)p;                   p += (size_t)n * 4;
    int* rsL    = (int*)p;                   p += (size_t)(n + 4) * 4;
    int* srcL   = (int*)p;                   p += (size_t)EL * 4;
    int* tgtL   = (int*)p;                   p += (size_t)EL * 4;
    int* eaL    = (int*)p;                   p += (size_t)EL * 4;
    int* rsG    = (int*)p;                   p += (size_t)(n + 4) * 4;
    int* srcG   = (int*)p;                   p += (size_t)EG * 4;
    int* tgtG   = (int*)p;                   p += (size_t)EG * 4;
    int* eaG    = (int*)p;                   p += (size_t)EG * 4;
    p = alignup(p);
    unsigned short* wp     = (unsigned short*)p;  p += (size_t)10 * FINdim * Hdim * 2;
    p = alignup(p);
    unsigned short* bondbf = (unsigned short*)p;  p += 96 * 2;
    p = alignup(p);
    unsigned short* sbfA   = (unsigned short*)p;  p += (size_t)n * Sdim * 2;
    unsigned short* sbfB   = (unsigned short*)p;  p += (size_t)n * Sdim * 2;
    p = alignup(p);
    float4* rn4L = (float4*)p;               p += (size_t)EL * 16;
    float4* rn4G = (float4*)p;               p += (size_t)EG * 16;
    unsigned short* rbfbL = (unsigned short*)p;  p += (size_t)EL * 32 * 2;
    unsigned short* rbfbG = (unsigned short*)p;  p += (size_t)EG * 32 * 2;

    float* out = (float*)d_out;

    // ---- precompute packed weights + init ----
    pack_kernel<<<(10 * FINdim * Hdim + 80 + 255) / 256, 256, 0, stream>>>(wm, bemb, wp, bondbf);
    temb_kernel<<<B, 64, 0, stream>>>(t, t_w1, t_b1, t_w2, t_b2, temb);
    node_init_kernel<<<(n * Sdim + 255) / 256, 256, 0, stream>>>(x, batch, aemb, temb, sA, sbfA, n);
    hipMemsetAsync(vA, 0, (size_t)n * NVdim * sizeof(float), stream);

    // ---- CSR build ----
    hipMemsetAsync(counts, 0, (size_t)n * sizeof(int), stream);
    count_kernel<<<(EL + 255) / 256, 256, 0, stream>>>(eil, EL, counts);
    scan_kernel<<<1, 256, 0, stream>>>(counts, n, rsL, cursor);
    scatter_kernel<<<(EL + 255) / 256, 256, 0, stream>>>(eil, eal, EL, cursor, srcL, tgtL, eaL);

    hipMemsetAsync(counts, 0, (size_t)n * sizeof(int), stream);
    count_kernel<<<(EG + 255) / 256, 256, 0, stream>>>(eig, EG, counts);
    scan_kernel<<<1, 256, 0, stream>>>(counts, n, rsG, cursor);
    scatter_kernel<<<(EG + 255) / 256, 256, 0, stream>>>(eig, eag, EG, cursor, srcG, tgtG, eaG);

    // ---- one-time edge geometry (layer-invariant) ----
    geom_kernel<<<(EL + 255) / 256, 256, 0, stream>>>(pos, srcL, tgtL, eaL, bondbf, rn4L, rbfbL, EL, 3.0f);
    geom_kernel<<<(EG + 255) / 256, 256, 0, stream>>>(pos, srcG, tgtG, eaG, bondbf, rn4G, rbfbG, EG, 10.0f);

    // ---- layers ----
    float* s_cur = sA; float* s_nxt = sB;
    float* v_cur = vA; float* v_nxt = vB;
    unsigned short* sb_cur = sbfA; unsigned short* sb_nxt = sbfB;

    for (int l = 0; l < NLAYER; ++l) {
        for (int k = 0; k < 2; ++k) {
            int ls = l * 2 + k;
            const unsigned short* wpk = wp + (size_t)ls * FINdim * Hdim;
            const float* bgk = bm + (size_t)ls * Hdim;
            const float* wuk = wu + (size_t)ls * Sdim * Sdim;
            const float* buk = bu + (size_t)ls * Sdim;
            if (k == 0) {
                fused_layer_wave<<<n / GW, 64, 0, stream>>>(
                    s_cur, s_nxt, sb_cur, sb_nxt, v_cur, v_nxt,
                    rsL, srcL, tgtL, rn4L, rbfbL, wpk, bgk, wuk, buk,
                    lng + (size_t)l * Sdim, lnb + (size_t)l * Sdim, 0);
            } else {
                fused_layer_wave<<<n / GW, 64, 0, stream>>>(
                    s_cur, s_nxt, sb_cur, sb_nxt, v_cur, v_nxt,
                    rsG, srcG, tgtG, rn4G, rbfbG, wpk, bgk, wuk, buk,
                    lng + (size_t)l * Sdim, lnb + (size_t)l * Sdim, 1);
            }
            float* tmp = s_cur; s_cur = s_nxt; s_nxt = tmp;
            tmp = v_cur; v_cur = v_nxt; v_nxt = tmp;
            unsigned short* tb = sb_cur; sb_cur = sb_nxt; sb_nxt = tb;
        }
    }

    head1_kernel<<<n, 64, 0, stream>>>(s_cur, v_cur, wd, wo, dsc, out);
    head2_kernel<<<(EG + 255) / 256, 256, 0, stream>>>(dsc, pos, eig, out, EG);
}

// Round 7
// 771.504 us; speedup vs baseline: 16.4403x; 1.0487x over previous
//
#include <hip/hip_runtime.h>
#include <math.h>

#define Sdim 64
#define Vdim 16
#define NLAYER 5
#define EDdim 16
#define RDdim 16
#define TDdim 64
#define FINdim 160   // 2*S + RD + ED
#define Hdim 96      // S + 2*V
#define NVdim 48     // 3*V
#define ACCW 113     // 64 ms + 48 vm + pad
#define HPAD 98      // hS row stride in floats
#define VSW 52       // vS row stride in floats
#define GW 4         // nodes per block (2 waves)

typedef __attribute__((ext_vector_type(8))) short bf16x8;
typedef __attribute__((ext_vector_type(4))) float f32x4;

__device__ __forceinline__ float silu_f(float x) {
    return x / (1.0f + __expf(-x));
}

__device__ __forceinline__ unsigned short f2bf(float x) {
    union { float f; unsigned u; } v; v.f = x;
    unsigned r = v.u + 0x7fffu + ((v.u >> 16) & 1u);
    return (unsigned short)(r >> 16);
}

// ---------------------------------------------------------------------------
// Pack W (10 layer-sets, [160][96] fp32) into MFMA B-fragment bf16 layout.
// ---------------------------------------------------------------------------
__global__ __launch_bounds__(256) void pack_kernel(
    const float* __restrict__ wm, const float* __restrict__ bemb,
    unsigned short* __restrict__ wp, unsigned short* __restrict__ bondbf)
{
    int idx = blockIdx.x * 256 + threadIdx.x;
    if (idx < 10 * FINdim * Hdim) {
        int ls = idx / (FINdim * Hdim), rem = idx % (FINdim * Hdim);
        int k = rem / Hdim, c = rem % Hdim;
        wp[(size_t)ls * FINdim * Hdim + ((size_t)(k >> 3) * Hdim + c) * 8 + (k & 7)] =
            f2bf(wm[idx]);
    } else if (idx < 10 * FINdim * Hdim + 80) {
        int i = idx - 10 * FINdim * Hdim;
        bondbf[i] = f2bf(bemb[i]);
    }
}

// ---------------------------------------------------------------------------
__global__ __launch_bounds__(64) void temb_kernel(
    const float* __restrict__ t, const float* __restrict__ w1, const float* __restrict__ b1,
    const float* __restrict__ w2, const float* __restrict__ b2, float* __restrict__ temb)
{
    int b = blockIdx.x, j = threadIdx.x;
    __shared__ float row[TDdim];
    __shared__ float hid[TDdim];
    row[j] = t[b * TDdim + j];
    __syncthreads();
    float h = b1[j];
    #pragma unroll 8
    for (int i = 0; i < TDdim; ++i) h = fmaf(row[i], w1[i * TDdim + j], h);
    h = silu_f(h);
    hid[j] = h;
    __syncthreads();
    float o = b2[j];
    #pragma unroll 8
    for (int i = 0; i < TDdim; ++i) o = fmaf(hid[i], w2[i * Sdim + j], o);
    temb[b * Sdim + j] = silu_f(o);
}

// ---------------------------------------------------------------------------
__global__ __launch_bounds__(256) void node_init_kernel(
    const int* __restrict__ x, const int* __restrict__ batch,
    const float* __restrict__ aemb, const float* __restrict__ temb,
    float* __restrict__ sfeat, unsigned short* __restrict__ sbf, int n)
{
    int idx = blockIdx.x * 256 + threadIdx.x;
    if (idx >= n * Sdim) return;
    int node = idx >> 6, j = idx & 63;
    int x0 = x[node * 3 + 0], x1 = x[node * 3 + 1], x2 = x[node * 3 + 2];
    float v = aemb[(0 * 16 + x0) * Sdim + j] + aemb[(16 + x1) * Sdim + j]
            + aemb[(32 + x2) * Sdim + j] + temb[batch[node] * Sdim + j];
    sfeat[idx] = v;
    sbf[idx]   = f2bf(v);
}

// ---------------------------------------------------------------------------
// CSR build
// ---------------------------------------------------------------------------
__global__ __launch_bounds__(256) void count_kernel(
    const int* __restrict__ ei, int E, int* __restrict__ counts)
{
    int e = blockIdx.x * 256 + threadIdx.x;
    if (e >= E) return;
    atomicAdd(&counts[ei[E + e]], 1);
}

__global__ __launch_bounds__(256) void scan_kernel(
    const int* __restrict__ counts, int n,
    int* __restrict__ rowStart, int* __restrict__ cursor)
{
    __shared__ int partial[256];
    __shared__ int spart[257];
    int t = threadIdx.x;
    int chunk = n / 256;
    int base = t * chunk;
    int s = 0;
    for (int i = 0; i < chunk; ++i) s += counts[base + i];
    partial[t] = s;
    __syncthreads();
    if (t == 0) {
        int a = 0;
        for (int i = 0; i < 256; ++i) { spart[i] = a; a += partial[i]; }
        spart[256] = a;
    }
    __syncthreads();
    int off = spart[t];
    for (int i = 0; i < chunk; ++i) {
        rowStart[base + i] = off;
        cursor[base + i]   = off;
        off += counts[base + i];
    }
    if (t == 255) rowStart[n] = spart[256];
}

__global__ __launch_bounds__(256) void scatter_kernel(
    const int* __restrict__ ei, const int* __restrict__ ea, int E,
    int* __restrict__ cursor,
    int* __restrict__ srcS, int* __restrict__ tgtS, int* __restrict__ eaS)
{
    int e = blockIdx.x * 256 + threadIdx.x;
    if (e >= E) return;
    int tgt = ei[E + e];
    int p = atomicAdd(&cursor[tgt], 1);
    srcS[p] = ei[e];
    tgtS[p] = tgt;
    eaS[p]  = ea[e];
}

// ---------------------------------------------------------------------------
// One-time per-edge geometry (layer-invariant).
// ---------------------------------------------------------------------------
__global__ __launch_bounds__(256) void geom_kernel(
    const float* __restrict__ pos,
    const int* __restrict__ srcS, const int* __restrict__ tgtS, const int* __restrict__ eaS,
    const unsigned short* __restrict__ bondbf,
    float4* __restrict__ rn4, unsigned short* __restrict__ rbfb,
    int E, float cutoff)
{
    int e = blockIdx.x * 256 + threadIdx.x;
    if (e >= E) return;
    int s = srcS[e], t = tgtS[e];
    float rx = pos[3*t]-pos[3*s], ry = pos[3*t+1]-pos[3*s+1], rz = pos[3*t+2]-pos[3*s+2];
    float d = sqrtf(fmaxf(rx*rx + ry*ry + rz*rz, 1e-6f));
    float invd = 1.0f / d;
    rn4[e] = make_float4(rx*invd, ry*invd, rz*invd, d);
    float env = (d < cutoff) ? 0.5f * (__cosf(3.14159265358979f * d / cutoff) + 1.0f) : 0.0f;
    float invw = (float)RDdim / cutoff;
    unsigned int pk[8];
    #pragma unroll
    for (int i2 = 0; i2 < 8; ++i2) {
        float c0 = cutoff * ((float)(2*i2)     / 15.0f);
        float c1 = cutoff * ((float)(2*i2 + 1) / 15.0f);
        float t0 = (d - c0) * invw, t1 = (d - c1) * invw;
        unsigned short b0 = f2bf(__expf(-0.5f * t0 * t0) * env);
        unsigned short b1 = f2bf(__expf(-0.5f * t1 * t1) * env);
        pk[i2] = (unsigned)b0 | ((unsigned)b1 << 16);
    }
    uint4* o = reinterpret_cast<uint4*>(rbfb + (size_t)e * 32);
    o[0] = make_uint4(pk[0], pk[1], pk[2], pk[3]);
    o[1] = make_uint4(pk[4], pk[5], pk[6], pk[7]);
    int ea = eaS[e];
    const uint4* bp = reinterpret_cast<const uint4*>(bondbf + ea * EDdim);
    o[2] = bp[0];
    o[3] = bp[1];
}

// ---------------------------------------------------------------------------
// Fused layer-set kernel: 2 waves per block, N-split, zero barriers in the
// chunk loop.  Wave0: cols 0-63 (ms) — 4 B-tiles, ms reduce.  Wave1: cols
// 64-95 (wv) — 2 B-tiles, v/rn staging, vm reduce.  Data flow is disjoint
// per wave; one __syncthreads before the node update.
// A-fragments (s rows, rbf/bond) and src/tgt load DIRECTLY from global —
// rbfb/srcS/tgtS are contiguous in edge index (coalesced).
// ---------------------------------------------------------------------------
__global__ __launch_bounds__(128, 4) void fused_layer_dual(
    const float* __restrict__ s_in, float* __restrict__ s_out,
    const unsigned short* __restrict__ sbf_in, unsigned short* __restrict__ sbf_out,
    const float* __restrict__ v_in, float* __restrict__ v_out,
    const int* __restrict__ rowStart,
    const int* __restrict__ srcS, const int* __restrict__ tgtS,
    const float4* __restrict__ rn4, const unsigned short* __restrict__ rbfb,
    const unsigned short* __restrict__ wp, const float* __restrict__ bg,
    const float* __restrict__ wu, const float* __restrict__ bu,
    const float* __restrict__ lng, const float* __restrict__ lnb,
    int do_ln)
{
    __shared__ float accL[GW * ACCW];               // 1808 B
    __shared__ __align__(16) float hS[16 * HPAD];   // 6272 B
    __shared__ __align__(16) float vS[16 * VSW];    // 3328 B
    __shared__ __align__(16) float rnS[16 * 4];     // 256 B
    __shared__ int rsW[2][GW + 1];

    const int tid  = threadIdx.x;
    const int lane = tid & 63;
    const int wid  = __builtin_amdgcn_readfirstlane(tid >> 6);  // scalar role id
    const int l15  = lane & 15, l4 = lane >> 4;
    const int n0   = blockIdx.x * GW;

    const int NT     = wid ? 2 : 4;
    const int ntBase = wid ? 4 : 0;

    // ---- B fragments for this wave's column tiles ----
    bf16x8 Bfrag[5][4];
    #pragma unroll
    for (int kk = 0; kk < 5; ++kk)
        #pragma unroll
        for (int j = 0; j < 4; ++j)
            if (j < NT)
                Bfrag[kk][j] = *reinterpret_cast<const bf16x8*>(
                    wp + ((size_t)(kk * 4 + l4) * Hdim + (ntBase + j) * 16 + l15) * 8);
    float bias[4];
    #pragma unroll
    for (int j = 0; j < 4; ++j)
        if (j < NT) bias[j] = bg[(ntBase + j) * 16 + l15];

    // ---- zero own accL region; own rowStart copy ----
    if (wid == 0) {
        #pragma unroll
        for (int i = 0; i < GW; ++i) accL[i * ACCW + lane] = 0.0f;
    } else {
        if (lane < 49)
            #pragma unroll
            for (int i = 0; i < GW; ++i) accL[i * ACCW + 64 + lane] = 0.0f;
    }
    if (lane <= GW) rsW[wid][lane] = rowStart[n0 + lane];

    const int eW0 = __builtin_amdgcn_readfirstlane(rsW[wid][0]);
    const int eW1 = __builtin_amdgcn_readfirstlane(rsW[wid][GW]);

    for (int base = eW0; base < eW1; base += 16) {
        const int nvalid = min(16, eW1 - base);

        // ---- stage (wave1 only): v[src] + rn into LDS ----
        if (wid == 1) {
            const int el = lane >> 2, q = lane & 3;
            const int e = base + el;
            if (e < eW1) {
                const int s = srcS[e];
                const float4* vp = reinterpret_cast<const float4*>(v_in + (size_t)s * NVdim + q * 12);
                float4 a0 = vp[0], a1 = vp[1], a2 = vp[2];
                *reinterpret_cast<float4*>(&vS[el * VSW + q * 12 + 0]) = a0;
                *reinterpret_cast<float4*>(&vS[el * VSW + q * 12 + 4]) = a1;
                *reinterpret_cast<float4*>(&vS[el * VSW + q * 12 + 8]) = a2;
            }
            if (lane < 16 && base + lane < eW1)
                *reinterpret_cast<float4*>(&rnS[lane * 4]) = rn4[base + lane];
        }

        // ---- MFMA: 16 edges x this wave's col tiles x K=160 ----
        const int eC = min(base + l15, eW1 - 1);
        const int sM = srcS[eC];
        const int tM = tgtS[eC];
        f32x4 acc[4];
        #pragma unroll
        for (int j = 0; j < 4; ++j) acc[j] = (f32x4){0.f, 0.f, 0.f, 0.f};
        #pragma unroll
        for (int kk = 0; kk < 5; ++kk) {
            bf16x8 a;
            if (kk < 2)
                a = *reinterpret_cast<const bf16x8*>(sbf_in + (size_t)sM * Sdim + kk * 32 + l4 * 8);
            else if (kk < 4)
                a = *reinterpret_cast<const bf16x8*>(sbf_in + (size_t)tM * Sdim + (kk - 2) * 32 + l4 * 8);
            else
                a = *reinterpret_cast<const bf16x8*>(rbfb + (size_t)eC * 32 + l4 * 8);
            #pragma unroll
            for (int j = 0; j < 4; ++j)
                if (j < NT)
                    acc[j] = __builtin_amdgcn_mfma_f32_16x16x32_bf16(a, Bfrag[kk][j], acc[j], 0, 0, 0);
        }

        // ---- epilogue: bias + silu -> own hS columns ----
        #pragma unroll
        for (int j = 0; j < 4; ++j)
            if (j < NT) {
                #pragma unroll
                for (int r = 0; r < 4; ++r)
                    hS[(l4 * 4 + r) * HPAD + (ntBase + j) * 16 + l15] =
                        silu_f(acc[j][r] + bias[j]);
            }

        // ---- ownership reduce (own cols only; no cross-wave data) ----
        if (wid == 0) {
            for (int i = 0; i < GW; ++i) {
                int lo = rsW[0][i] - base;     if (lo < 0) lo = 0;
                int hi = rsW[0][i + 1] - base; if (hi > nvalid) hi = nvalid;
                if (lo >= hi) continue;
                float msum = 0.0f;
                for (int e2 = lo; e2 < hi; ++e2) msum += hS[e2 * HPAD + lane];
                accL[i * ACCW + lane] += msum;
            }
        } else if (lane < NVdim) {
            const int m = l15, dd = l4;
            for (int i = 0; i < GW; ++i) {
                int lo = rsW[1][i] - base;     if (lo < 0) lo = 0;
                int hi = rsW[1][i + 1] - base; if (hi > nvalid) hi = nvalid;
                if (lo >= hi) continue;
                float vsum = 0.0f;
                for (int e2 = lo; e2 < hi; ++e2)
                    vsum += vS[e2 * VSW + lane] * hS[e2 * HPAD + 64 + m]
                          + rnS[e2 * 4 + dd]    * hS[e2 * HPAD + 80 + m];
                accL[i * ACCW + 64 + lane] += vsum;
            }
        }
    }
    __syncthreads();

    // ---- node update: node i handled by wave (i&1) ----
    #pragma unroll
    for (int p = 0; p < GW / 2; ++p) {
        const int i = p * 2 + wid;
        const int node = n0 + i;
        const float cntn = (float)(rsW[wid][i + 1] - rsW[wid][i]);
        const float ic = 1.0f / fmaxf(cntn, 1.0f);
        const float* al = &accL[i * ACCW];
        float dot = 0.0f;
        #pragma unroll 8
        for (int ii = 0; ii < Sdim; ++ii) dot = fmaf(al[ii], wu[ii * Sdim + lane], dot);
        float sn = s_in[(size_t)node * Sdim + lane] + silu_f(fmaf(dot, ic, bu[lane]));
        if (do_ln) {
            float mm = sn;
            #pragma unroll
            for (int off = 32; off >= 1; off >>= 1) mm += __shfl_xor(mm, off);
            mm *= (1.0f / 64.0f);
            float dv = sn - mm;
            float var = dv * dv;
            #pragma unroll
            for (int off = 32; off >= 1; off >>= 1) var += __shfl_xor(var, off);
            var *= (1.0f / 64.0f);
            sn = dv * rsqrtf(var + 1e-5f) * lng[lane] + lnb[lane];
        }
        s_out[(size_t)node * Sdim + lane]   = sn;
        sbf_out[(size_t)node * Sdim + lane] = f2bf(sn);
        if (lane < NVdim)
            v_out[(size_t)node * NVdim + lane] =
                v_in[(size_t)node * NVdim + lane] + accL[i * ACCW + Sdim + lane] * ic;
    }
}

// ---------------------------------------------------------------------------
// Head
// ---------------------------------------------------------------------------
__global__ __launch_bounds__(64) void head1_kernel(
    const float* __restrict__ sfeat, const float* __restrict__ vfeat,
    const float* __restrict__ wd, const float* __restrict__ wo,
    float* __restrict__ dsc, float* __restrict__ out)
{
    int node = blockIdx.x, j = threadIdx.x;
    float val = silu_f(sfeat[(size_t)node * Sdim + j]) * wd[j];
    #pragma unroll
    for (int off = 32; off >= 1; off >>= 1) val += __shfl_xor(val, off);
    if (j == 0) dsc[node] = val;
    if (j < 3) {
        float a = 0.0f;
        #pragma unroll
        for (int m = 0; m < Vdim; ++m)
            a += vfeat[(size_t)node * NVdim + j * Vdim + m] * wo[m];
        out[(size_t)node * 3 + j] = a;
    }
}

__global__ __launch_bounds__(256) void head2_kernel(
    const float* __restrict__ dsc, const float* __restrict__ pos,
    const int* __restrict__ eig, float* __restrict__ out, int E)
{
    int e = blockIdx.x * 256 + threadIdx.x;
    if (e >= E) return;
    int src = eig[e], tgt = eig[E + e];
    float w = dsc[src] + dsc[tgt];
    atomicAdd(out + 3 * tgt + 0, w * (pos[3*src+0] - pos[3*tgt+0]));
    atomicAdd(out + 3 * tgt + 1, w * (pos[3*src+1] - pos[3*tgt+1]));
    atomicAdd(out + 3 * tgt + 2, w * (pos[3*src+2] - pos[3*tgt+2]));
}

// ---------------------------------------------------------------------------
extern "C" void kernel_launch(void* const* d_in, const int* in_sizes, int n_in,
                              void* d_out, int out_size, void* d_ws, size_t ws_size,
                              hipStream_t stream)
{
    const int*   x     = (const int*)d_in[0];
    const float* t     = (const float*)d_in[1];
    const float* pos   = (const float*)d_in[2];
    const int*   eil   = (const int*)d_in[3];
    const int*   eig   = (const int*)d_in[4];
    const int*   eal   = (const int*)d_in[5];
    const int*   eag   = (const int*)d_in[6];
    const int*   batch = (const int*)d_in[7];
    const float* aemb  = (const float*)d_in[8];
    const float* bemb  = (const float*)d_in[9];
    const float* t_w1  = (const float*)d_in[10];
    const float* t_b1  = (const float*)d_in[11];
    const float* t_w2  = (const float*)d_in[12];
    const float* t_b2  = (const float*)d_in[13];
    const float* wm    = (const float*)d_in[14];
    const float* bm    = (const float*)d_in[15];
    const float* wu    = (const float*)d_in[16];
    const float* bu    = (const float*)d_in[17];
    const float* lng   = (const float*)d_in[18];
    const float* lnb   = (const float*)d_in[19];
    const float* wd    = (const float*)d_in[20];
    const float* wo    = (const float*)d_in[21];

    const int n  = in_sizes[7];          // 16384
    const int B  = in_sizes[1] / TDdim;  // 64
    const int EL = in_sizes[3] / 2;      // 131072
    const int EG = in_sizes[4] / 2;      // 262144

    // ---- workspace layout ----
    char* p = (char*)d_ws;
    auto alignup = [](char* q) { return (char*)(((size_t)q + 15) & ~(size_t)15); };

    float* temb = (float*)p;                 p += (size_t)B * Sdim * 4;
    float* dsc  = (float*)p;                 p += (size_t)n * 4;
    float* sA   = (float*)p;                 p += (size_t)n * Sdim * 4;
    float* sB   = (float*)p;                 p += (size_t)n * Sdim * 4;
    float* vA   = (float*)p;                 p += (size_t)n * NVdim * 4;
    float* vB   = (float*)p;                 p += (size_t)n * NVdim * 4;
    int* counts = (int*)p;                   p += (size_t)n * 4;
    int* cursor = (int*)p;                   p += (size_t)n * 4;
    int* rsL    = (int*)p;                   p += (size_t)(n + 4) * 4;
    int* srcL   = (int*)p;                   p += (size_t)EL * 4;
    int* tgtL   = (int*)p;                   p += (size_t)EL * 4;
    int* eaL    = (int*)p;                   p += (size_t)EL * 4;
    int* rsG    = (int*)p;                   p += (size_t)(n + 4) * 4;
    int* srcG   = (int*)p;                   p += (size_t)EG * 4;
    int* tgtG   = (int*)p;                   p += (size_t)EG * 4;
    int* eaG    = (int*)p;                   p += (size_t)EG * 4;
    p = alignup(p);
    unsigned short* wp     = (unsigned short*)p;  p += (size_t)10 * FINdim * Hdim * 2;
    p = alignup(p);
    unsigned short* bondbf = (unsigned short*)p;  p += 96 * 2;
    p = alignup(p);
    unsigned short* sbfA   = (unsigned short*)p;  p += (size_t)n * Sdim * 2;
    unsigned short* sbfB   = (unsigned short*)p;  p += (size_t)n * Sdim * 2;
    p = alignup(p);
    float4* rn4L = (float4*)p;               p += (size_t)EL * 16;
    float4* rn4G = (float4*)p;               p += (size_t)EG * 16;
    unsigned short* rbfbL = (unsigned short*)p;  p += (size_t)EL * 32 * 2;
    unsigned short* rbfbG = (unsigned short*)p;  p += (size_t)EG * 32 * 2;

    float* out = (float*)d_out;

    // ---- precompute packed weights + init ----
    pack_kernel<<<(10 * FINdim * Hdim + 80 + 255) / 256, 256, 0, stream>>>(wm, bemb, wp, bondbf);
    temb_kernel<<<B, 64, 0, stream>>>(t, t_w1, t_b1, t_w2, t_b2, temb);
    node_init_kernel<<<(n * Sdim + 255) / 256, 256, 0, stream>>>(x, batch, aemb, temb, sA, sbfA, n);
    hipMemsetAsync(vA, 0, (size_t)n * NVdim * sizeof(float), stream);

    // ---- CSR build ----
    hipMemsetAsync(counts, 0, (size_t)n * sizeof(int), stream);
    count_kernel<<<(EL + 255) / 256, 256, 0, stream>>>(eil, EL, counts);
    scan_kernel<<<1, 256, 0, stream>>>(counts, n, rsL, cursor);
    scatter_kernel<<<(EL + 255) / 256, 256, 0, stream>>>(eil, eal, EL, cursor, srcL, tgtL, eaL);

    hipMemsetAsync(counts, 0, (size_t)n * sizeof(int), stream);
    count_kernel<<<(EG + 255) / 256, 256, 0, stream>>>(eig, EG, counts);
    scan_kernel<<<1, 256, 0, stream>>>(counts, n, rsG, cursor);
    scatter_kernel<<<(EG + 255) / 256, 256, 0, stream>>>(eig, eag, EG, cursor, srcG, tgtG, eaG);

    // ---- one-time edge geometry (layer-invariant) ----
    geom_kernel<<<(EL + 255) / 256, 256, 0, stream>>>(pos, srcL, tgtL, eaL, bondbf, rn4L, rbfbL, EL, 3.0f);
    geom_kernel<<<(EG + 255) / 256, 256, 0, stream>>>(pos, srcG, tgtG, eaG, bondbf, rn4G, rbfbG, EG, 10.0f);

    // ---- layers ----
    float* s_cur = sA; float* s_nxt = sB;
    float* v_cur = vA; float* v_nxt = vB;
    unsigned short* sb_cur = sbfA; unsigned short* sb_nxt = sbfB;

    for (int l = 0; l < NLAYER; ++l) {
        for (int k = 0; k < 2; ++k) {
            int ls = l * 2 + k;
            const unsigned short* wpk = wp + (size_t)ls * FINdim * Hdim;
            const float* bgk = bm + (size_t)ls * Hdim;
            const float* wuk = wu + (size_t)ls * Sdim * Sdim;
            const float* buk = bu + (size_t)ls * Sdim;
            if (k == 0) {
                fused_layer_dual<<<n / GW, 128, 0, stream>>>(
                    s_cur, s_nxt, sb_cur, sb_nxt, v_cur, v_nxt,
                    rsL, srcL, tgtL, rn4L, rbfbL, wpk, bgk, wuk, buk,
                    lng + (size_t)l * Sdim, lnb + (size_t)l * Sdim, 0);
            } else {
                fused_layer_dual<<<n / GW, 128, 0, stream>>>(
                    s_cur, s_nxt, sb_cur, sb_nxt, v_cur, v_nxt,
                    rsG, srcG, tgtG, rn4G, rbfbG, wpk, bgk, wuk, buk,
                    lng + (size_t)l * Sdim, lnb + (size_t)l * Sdim, 1);
            }
            float* tmp = s_cur; s_cur = s_nxt; s_nxt = tmp;
            tmp = v_cur; v_cur = v_nxt; v_nxt = tmp;
            unsigned short* tb = sb_cur; sb_cur = sb_nxt; sb_nxt = tb;
        }
    }

    head1_kernel<<<n, 64, 0, stream>>>(s_cur, v_cur, wd, wo, dsc, out);
    head2_kernel<<<(EG + 255) / 256, 256, 0, stream>>>(dsc, pos, eig, out, EG);
}

// Round 8
// 731.477 us; speedup vs baseline: 17.3399x; 1.0547x over previous
//
#include <hip/hip_runtime.h>
#include <math.h>

#define Sdim 64
#define Vdim 16
#define NLAYER 5
#define EDdim 16
#define RDdim 16
#define TDdim 64
#define FINdim 160   // 2*S + RD + ED
#define Hdim 96      // S + 2*V
#define NVdim 48     // 3*V
#define ACCW 113     // 64 ms + 48 vm + pad
#define HPAD 98      // hS row stride in floats
#define VSW 52       // vS row stride in floats
#define GW 16        // nodes per block (3 waves)

typedef __attribute__((ext_vector_type(8))) short bf16x8;
typedef __attribute__((ext_vector_type(4))) float f32x4;

__device__ __forceinline__ float silu_f(float x) {
    return x / (1.0f + __expf(-x));
}

__device__ __forceinline__ unsigned short f2bf(float x) {
    union { float f; unsigned u; } v; v.f = x;
    unsigned r = v.u + 0x7fffu + ((v.u >> 16) & 1u);
    return (unsigned short)(r >> 16);
}

// ---------------------------------------------------------------------------
// Pack W (10 layer-sets, [160][96] fp32) into MFMA B-fragment bf16 layout.
// ---------------------------------------------------------------------------
__global__ __launch_bounds__(256) void pack_kernel(
    const float* __restrict__ wm, const float* __restrict__ bemb,
    unsigned short* __restrict__ wp, unsigned short* __restrict__ bondbf)
{
    int idx = blockIdx.x * 256 + threadIdx.x;
    if (idx < 10 * FINdim * Hdim) {
        int ls = idx / (FINdim * Hdim), rem = idx % (FINdim * Hdim);
        int k = rem / Hdim, c = rem % Hdim;
        wp[(size_t)ls * FINdim * Hdim + ((size_t)(k >> 3) * Hdim + c) * 8 + (k & 7)] =
            f2bf(wm[idx]);
    } else if (idx < 10 * FINdim * Hdim + 80) {
        int i = idx - 10 * FINdim * Hdim;
        bondbf[i] = f2bf(bemb[i]);
    }
}

// ---------------------------------------------------------------------------
__global__ __launch_bounds__(64) void temb_kernel(
    const float* __restrict__ t, const float* __restrict__ w1, const float* __restrict__ b1,
    const float* __restrict__ w2, const float* __restrict__ b2, float* __restrict__ temb)
{
    int b = blockIdx.x, j = threadIdx.x;
    __shared__ float row[TDdim];
    __shared__ float hid[TDdim];
    row[j] = t[b * TDdim + j];
    __syncthreads();
    float h = b1[j];
    #pragma unroll 8
    for (int i = 0; i < TDdim; ++i) h = fmaf(row[i], w1[i * TDdim + j], h);
    h = silu_f(h);
    hid[j] = h;
    __syncthreads();
    float o = b2[j];
    #pragma unroll 8
    for (int i = 0; i < TDdim; ++i) o = fmaf(hid[i], w2[i * Sdim + j], o);
    temb[b * Sdim + j] = silu_f(o);
}

// ---------------------------------------------------------------------------
__global__ __launch_bounds__(256) void node_init_kernel(
    const int* __restrict__ x, const int* __restrict__ batch,
    const float* __restrict__ aemb, const float* __restrict__ temb,
    float* __restrict__ sfeat, unsigned short* __restrict__ sbf, int n)
{
    int idx = blockIdx.x * 256 + threadIdx.x;
    if (idx >= n * Sdim) return;
    int node = idx >> 6, j = idx & 63;
    int x0 = x[node * 3 + 0], x1 = x[node * 3 + 1], x2 = x[node * 3 + 2];
    float v = aemb[(0 * 16 + x0) * Sdim + j] + aemb[(16 + x1) * Sdim + j]
            + aemb[(32 + x2) * Sdim + j] + temb[batch[node] * Sdim + j];
    sfeat[idx] = v;
    sbf[idx]   = f2bf(v);
}

// ---------------------------------------------------------------------------
// CSR build
// ---------------------------------------------------------------------------
__global__ __launch_bounds__(256) void count_kernel(
    const int* __restrict__ ei, int E, int* __restrict__ counts)
{
    int e = blockIdx.x * 256 + threadIdx.x;
    if (e >= E) return;
    atomicAdd(&counts[ei[E + e]], 1);
}

__global__ __launch_bounds__(256) void scan_kernel(
    const int* __restrict__ counts, int n,
    int* __restrict__ rowStart, int* __restrict__ cursor)
{
    __shared__ int partial[256];
    __shared__ int spart[257];
    int t = threadIdx.x;
    int chunk = n / 256;
    int base = t * chunk;
    int s = 0;
    for (int i = 0; i < chunk; ++i) s += counts[base + i];
    partial[t] = s;
    __syncthreads();
    if (t == 0) {
        int a = 0;
        for (int i = 0; i < 256; ++i) { spart[i] = a; a += partial[i]; }
        spart[256] = a;
    }
    __syncthreads();
    int off = spart[t];
    for (int i = 0; i < chunk; ++i) {
        rowStart[base + i] = off;
        cursor[base + i]   = off;
        off += counts[base + i];
    }
    if (t == 255) rowStart[n] = spart[256];
}

__global__ __launch_bounds__(256) void scatter_kernel(
    const int* __restrict__ ei, const int* __restrict__ ea, int E,
    int* __restrict__ cursor, int2* __restrict__ st2, int* __restrict__ eaS)
{
    int e = blockIdx.x * 256 + threadIdx.x;
    if (e >= E) return;
    int tgt = ei[E + e];
    int p = atomicAdd(&cursor[tgt], 1);
    st2[p] = make_int2(ei[e], tgt);
    eaS[p] = ea[e];
}

// ---------------------------------------------------------------------------
// One-time per-edge geometry (layer-invariant).
// ---------------------------------------------------------------------------
__global__ __launch_bounds__(256) void geom_kernel(
    const float* __restrict__ pos,
    const int2* __restrict__ st2, const int* __restrict__ eaS,
    const unsigned short* __restrict__ bondbf,
    float4* __restrict__ rn4, unsigned short* __restrict__ rbfb,
    int E, float cutoff)
{
    int e = blockIdx.x * 256 + threadIdx.x;
    if (e >= E) return;
    int2 st = st2[e];
    int s = st.x, t = st.y;
    float rx = pos[3*t]-pos[3*s], ry = pos[3*t+1]-pos[3*s+1], rz = pos[3*t+2]-pos[3*s+2];
    float d = sqrtf(fmaxf(rx*rx + ry*ry + rz*rz, 1e-6f));
    float invd = 1.0f / d;
    rn4[e] = make_float4(rx*invd, ry*invd, rz*invd, d);
    float env = (d < cutoff) ? 0.5f * (__cosf(3.14159265358979f * d / cutoff) + 1.0f) : 0.0f;
    float invw = (float)RDdim / cutoff;
    unsigned int pk[8];
    #pragma unroll
    for (int i2 = 0; i2 < 8; ++i2) {
        float c0 = cutoff * ((float)(2*i2)     / 15.0f);
        float c1 = cutoff * ((float)(2*i2 + 1) / 15.0f);
        float t0 = (d - c0) * invw, t1 = (d - c1) * invw;
        unsigned short b0 = f2bf(__expf(-0.5f * t0 * t0) * env);
        unsigned short b1 = f2bf(__expf(-0.5f * t1 * t1) * env);
        pk[i2] = (unsigned)b0 | ((unsigned)b1 << 16);
    }
    uint4* o = reinterpret_cast<uint4*>(rbfb + (size_t)e * 32);
    o[0] = make_uint4(pk[0], pk[1], pk[2], pk[3]);
    o[1] = make_uint4(pk[4], pk[5], pk[6], pk[7]);
    int ea = eaS[e];
    const uint4* bp = reinterpret_cast<const uint4*>(bondbf + ea * EDdim);
    o[2] = bp[0];
    o[3] = bp[1];
}

// ---------------------------------------------------------------------------
// Fused layer-set kernel: 3 waves per block, 2 column-tiles per wave
// (Bfrag = 40 VGPR, uniform -> resident), one-chunk software pipeline,
// zero barriers in the chunk loop.
//   wave0: cols  0-31 (ms) ; wave1: cols 32-63 (ms)
//   wave2: cols 64-95 (wv) + v/rn staging + vm reduce
// Per iteration: issue gathers (this chunk A, next chunk indices, v/rn)
// -> reduce PREVIOUS chunk (LDS-only, covers load latency) -> MFMA ->
// epilogue -> commit staging.  In-wave DS ordering makes this race-free.
// ---------------------------------------------------------------------------
__global__ __launch_bounds__(192, 4) void fused_layer_tri(
    const float* __restrict__ s_in, float* __restrict__ s_out,
    const unsigned short* __restrict__ sbf_in, unsigned short* __restrict__ sbf_out,
    const float* __restrict__ v_in, float* __restrict__ v_out,
    const int* __restrict__ rowStart,
    const int2* __restrict__ st2,
    const float4* __restrict__ rn4, const unsigned short* __restrict__ rbfb,
    const unsigned short* __restrict__ wp, const float* __restrict__ bg,
    const float* __restrict__ wu, const float* __restrict__ bu,
    const float* __restrict__ lng, const float* __restrict__ lnb,
    int do_ln)
{
    __shared__ float accL[GW * ACCW];               // 7232 B
    __shared__ __align__(16) float hS[16 * HPAD];   // 6272 B
    __shared__ __align__(16) float vS[16 * VSW];    // 3328 B
    __shared__ __align__(16) float rnS[16 * 4];     // 256 B
    __shared__ int rsW[3][GW + 1];

    const int tid  = threadIdx.x;
    const int lane = tid & 63;
    const int wid  = __builtin_amdgcn_readfirstlane(tid >> 6);  // 0,1,2
    const int l15  = lane & 15, l4 = lane >> 4;
    const int n0   = blockIdx.x * GW;

    // ---- B fragments: 2 col tiles per wave (40 VGPR, uniform) ----
    bf16x8 B0[5], B1[5];
    #pragma unroll
    for (int kk = 0; kk < 5; ++kk) {
        B0[kk] = *reinterpret_cast<const bf16x8*>(
            wp + ((size_t)(kk * 4 + l4) * Hdim + (wid * 2 + 0) * 16 + l15) * 8);
        B1[kk] = *reinterpret_cast<const bf16x8*>(
            wp + ((size_t)(kk * 4 + l4) * Hdim + (wid * 2 + 1) * 16 + l15) * 8);
    }
    const float bias0 = bg[(wid * 2 + 0) * 16 + l15];
    const float bias1 = bg[(wid * 2 + 1) * 16 + l15];

    // ---- zero own accL region; own rowStart copy ----
    if (wid < 2) {
        if (lane < 32)
            #pragma unroll
            for (int i = 0; i < GW; ++i) accL[i * ACCW + wid * 32 + lane] = 0.0f;
    } else if (lane < 49) {
        #pragma unroll
        for (int i = 0; i < GW; ++i) accL[i * ACCW + 64 + lane] = 0.0f;
    }
    if (lane <= GW) rsW[wid][lane] = rowStart[n0 + lane];

    const int eW0 = __builtin_amdgcn_readfirstlane(rsW[wid][0]);
    const int eW1 = __builtin_amdgcn_readfirstlane(rsW[wid][GW]);
    const int eLast = max(eW1 - 1, 0);

    auto reduceChunk = [&](int pb) {
        const int pv = min(16, eW1 - pb);
        if (wid < 2) {
            if (lane < 32) {
                const int col = wid * 32 + lane;
                for (int i = 0; i < GW; ++i) {
                    int lo = rsW[wid][i] - pb;     if (lo < 0) lo = 0;
                    int hi = rsW[wid][i + 1] - pb; if (hi > pv) hi = pv;
                    if (lo >= hi) continue;
                    float msum = 0.0f;
                    for (int e2 = lo; e2 < hi; ++e2) msum += hS[e2 * HPAD + col];
                    accL[i * ACCW + col] += msum;
                }
            }
        } else if (lane < NVdim) {
            const int m = l15, dd = l4;
            for (int i = 0; i < GW; ++i) {
                int lo = rsW[2][i] - pb;     if (lo < 0) lo = 0;
                int hi = rsW[2][i + 1] - pb; if (hi > pv) hi = pv;
                if (lo >= hi) continue;
                float vsum = 0.0f;
                for (int e2 = lo; e2 < hi; ++e2)
                    vsum += vS[e2 * VSW + lane] * hS[e2 * HPAD + 64 + m]
                          + rnS[e2 * 4 + dd]   * hS[e2 * HPAD + 80 + m];
                accL[i * ACCW + 64 + lane] += vsum;
            }
        }
    };

    // ---- pipeline prologue: indices for chunk 0 ----
    int2 stM = st2[min(eW0 + l15, eLast)];
    int  sSt = 0;
    if (wid == 2) sSt = st2[min(eW0 + (lane >> 2), eLast)].x;
    int prevBase = -1;

    for (int base = eW0; base < eW1; base += 16) {
        // 1. A-fragment gathers for current chunk (issue early)
        const unsigned short* sp = sbf_in + (size_t)stM.x * Sdim;
        const unsigned short* tp = sbf_in + (size_t)stM.y * Sdim;
        bf16x8 a0 = *reinterpret_cast<const bf16x8*>(sp + l4 * 8);
        bf16x8 a1 = *reinterpret_cast<const bf16x8*>(sp + 32 + l4 * 8);
        bf16x8 a2 = *reinterpret_cast<const bf16x8*>(tp + l4 * 8);
        bf16x8 a3 = *reinterpret_cast<const bf16x8*>(tp + 32 + l4 * 8);
        bf16x8 a4 = *reinterpret_cast<const bf16x8*>(
            rbfb + (size_t)min(base + l15, eLast) * 32 + l4 * 8);

        // 2. next-chunk index prefetch
        int2 stMn = st2[min(base + 16 + l15, eLast)];
        int  sStn = 0;
        float4 va, vb, vc, rnv;
        if (wid == 2) {
            sStn = st2[min(base + 16 + (lane >> 2), eLast)].x;
            const int q = lane & 3;
            const float* vp = v_in + (size_t)sSt * NVdim + q * 12;
            va = *reinterpret_cast<const float4*>(vp);
            vb = *reinterpret_cast<const float4*>(vp + 4);
            vc = *reinterpret_cast<const float4*>(vp + 8);
            if (lane < 16) rnv = rn4[min(base + lane, eLast)];
        }

        // 3. reduce previous chunk (LDS-only; covers the load latency above)
        if (prevBase >= 0) reduceChunk(prevBase);

        // 4. MFMA: 16 edges x 32 cols x K=160
        f32x4 c0 = (f32x4){0.f, 0.f, 0.f, 0.f};
        f32x4 c1 = (f32x4){0.f, 0.f, 0.f, 0.f};
        c0 = __builtin_amdgcn_mfma_f32_16x16x32_bf16(a0, B0[0], c0, 0, 0, 0);
        c1 = __builtin_amdgcn_mfma_f32_16x16x32_bf16(a0, B1[0], c1, 0, 0, 0);
        c0 = __builtin_amdgcn_mfma_f32_16x16x32_bf16(a1, B0[1], c0, 0, 0, 0);
        c1 = __builtin_amdgcn_mfma_f32_16x16x32_bf16(a1, B1[1], c1, 0, 0, 0);
        c0 = __builtin_amdgcn_mfma_f32_16x16x32_bf16(a2, B0[2], c0, 0, 0, 0);
        c1 = __builtin_amdgcn_mfma_f32_16x16x32_bf16(a2, B1[2], c1, 0, 0, 0);
        c0 = __builtin_amdgcn_mfma_f32_16x16x32_bf16(a3, B0[3], c0, 0, 0, 0);
        c1 = __builtin_amdgcn_mfma_f32_16x16x32_bf16(a3, B1[3], c1, 0, 0, 0);
        c0 = __builtin_amdgcn_mfma_f32_16x16x32_bf16(a4, B0[4], c0, 0, 0, 0);
        c1 = __builtin_amdgcn_mfma_f32_16x16x32_bf16(a4, B1[4], c1, 0, 0, 0);

        // 5. epilogue: bias + silu -> own hS columns
        #pragma unroll
        for (int r = 0; r < 4; ++r) {
            hS[(l4 * 4 + r) * HPAD + wid * 32 + l15]      = silu_f(c0[r] + bias0);
            hS[(l4 * 4 + r) * HPAD + wid * 32 + 16 + l15] = silu_f(c1[r] + bias1);
        }
        // 6. commit staging for this chunk (read by reduce next iteration)
        if (wid == 2) {
            const int el = lane >> 2, q = lane & 3;
            *reinterpret_cast<float4*>(&vS[el * VSW + q * 12 + 0]) = va;
            *reinterpret_cast<float4*>(&vS[el * VSW + q * 12 + 4]) = vb;
            *reinterpret_cast<float4*>(&vS[el * VSW + q * 12 + 8]) = vc;
            if (lane < 16) *reinterpret_cast<float4*>(&rnS[lane * 4]) = rnv;
        }
        prevBase = base;
        stM = stMn; sSt = sStn;
    }
    if (prevBase >= 0) reduceChunk(prevBase);
    __syncthreads();

    // ---- node update: wave w handles nodes w, w+3, ... ----
    for (int i = wid; i < GW; i += 3) {
        const int node = n0 + i;
        const float cntn = (float)(rsW[wid][i + 1] - rsW[wid][i]);
        const float ic = 1.0f / fmaxf(cntn, 1.0f);
        const float* al = &accL[i * ACCW];
        float dot = 0.0f;
        #pragma unroll 8
        for (int ii = 0; ii < Sdim; ++ii) dot = fmaf(al[ii], wu[ii * Sdim + lane], dot);
        float sn = s_in[(size_t)node * Sdim + lane] + silu_f(fmaf(dot, ic, bu[lane]));
        if (do_ln) {
            float mm = sn;
            #pragma unroll
            for (int off = 32; off >= 1; off >>= 1) mm += __shfl_xor(mm, off);
            mm *= (1.0f / 64.0f);
            float dv = sn - mm;
            float var = dv * dv;
            #pragma unroll
            for (int off = 32; off >= 1; off >>= 1) var += __shfl_xor(var, off);
            var *= (1.0f / 64.0f);
            sn = dv * rsqrtf(var + 1e-5f) * lng[lane] + lnb[lane];
        }
        s_out[(size_t)node * Sdim + lane]   = sn;
        sbf_out[(size_t)node * Sdim + lane] = f2bf(sn);
        if (lane < NVdim)
            v_out[(size_t)node * NVdim + lane] =
                v_in[(size_t)node * NVdim + lane] + accL[i * ACCW + Sdim + lane] * ic;
    }
}

// ---------------------------------------------------------------------------
// Head
// ---------------------------------------------------------------------------
__global__ __launch_bounds__(64) void head1_kernel(
    const float* __restrict__ sfeat, const float* __restrict__ vfeat,
    const float* __restrict__ wd, const float* __restrict__ wo,
    float* __restrict__ dsc, float* __restrict__ out)
{
    int node = blockIdx.x, j = threadIdx.x;
    float val = silu_f(sfeat[(size_t)node * Sdim + j]) * wd[j];
    #pragma unroll
    for (int off = 32; off >= 1; off >>= 1) val += __shfl_xor(val, off);
    if (j == 0) dsc[node] = val;
    if (j < 3) {
        float a = 0.0f;
        #pragma unroll
        for (int m = 0; m < Vdim; ++m)
            a += vfeat[(size_t)node * NVdim + j * Vdim + m] * wo[m];
        out[(size_t)node * 3 + j] = a;
    }
}

__global__ __launch_bounds__(256) void head2_kernel(
    const float* __restrict__ dsc, const float* __restrict__ pos,
    const int* __restrict__ eig, float* __restrict__ out, int E)
{
    int e = blockIdx.x * 256 + threadIdx.x;
    if (e >= E) return;
    int src = eig[e], tgt = eig[E + e];
    float w = dsc[src] + dsc[tgt];
    atomicAdd(out + 3 * tgt + 0, w * (pos[3*src+0] - pos[3*tgt+0]));
    atomicAdd(out + 3 * tgt + 1, w * (pos[3*src+1] - pos[3*tgt+1]));
    atomicAdd(out + 3 * tgt + 2, w * (pos[3*src+2] - pos[3*tgt+2]));
}

// ---------------------------------------------------------------------------
extern "C" void kernel_launch(void* const* d_in, const int* in_sizes, int n_in,
                              void* d_out, int out_size, void* d_ws, size_t ws_size,
                              hipStream_t stream)
{
    const int*   x     = (const int*)d_in[0];
    const float* t     = (const float*)d_in[1];
    const float* pos   = (const float*)d_in[2];
    const int*   eil   = (const int*)d_in[3];
    const int*   eig   = (const int*)d_in[4];
    const int*   eal   = (const int*)d_in[5];
    const int*   eag   = (const int*)d_in[6];
    const int*   batch = (const int*)d_in[7];
    const float* aemb  = (const float*)d_in[8];
    const float* bemb  = (const float*)d_in[9];
    const float* t_w1  = (const float*)d_in[10];
    const float* t_b1  = (const float*)d_in[11];
    const float* t_w2  = (const float*)d_in[12];
    const float* t_b2  = (const float*)d_in[13];
    const float* wm    = (const float*)d_in[14];
    const float* bm    = (const float*)d_in[15];
    const float* wu    = (const float*)d_in[16];
    const float* bu    = (const float*)d_in[17];
    const float* lng   = (const float*)d_in[18];
    const float* lnb   = (const float*)d_in[19];
    const float* wd    = (const float*)d_in[20];
    const float* wo    = (const float*)d_in[21];

    const int n  = in_sizes[7];          // 16384
    const int B  = in_sizes[1] / TDdim;  // 64
    const int EL = in_sizes[3] / 2;      // 131072
    const int EG = in_sizes[4] / 2;      // 262144

    // ---- workspace layout ----
    char* p = (char*)d_ws;
    auto alignup = [](char* q) { return (char*)(((size_t)q + 15) & ~(size_t)15); };

    float* temb = (float*)p;                 p += (size_t)B * Sdim * 4;
    float* dsc  = (float*)p;                 p += (size_t)n * 4;
    float* sA   = (float*)p;                 p += (size_t)n * Sdim * 4;
    float* sB   = (float*)p;                 p += (size_t)n * Sdim * 4;
    float* vA   = (float*)p;                 p += (size_t)n * NVdim * 4;
    float* vB   = (float*)p;                 p += (size_t)n * NVdim * 4;
    int* counts = (int*)p;                   p += (size_t)n * 4;
    int* cursor = (int*)p;                   p += (size_t)n * 4;
    int* rsL    = (int*)p;                   p += (size_t)(n + 4) * 4;
    int* rsG    = (int*)p;                   p += (size_t)(n + 4) * 4;
    int* eaL2   = (int*)p;                   p += (size_t)EL * 4;
    int* eaG2   = (int*)p;                   p += (size_t)EG * 4;
    p = alignup(p);
    int2* st2L  = (int2*)p;                  p += (size_t)EL * 8;
    int2* st2G  = (int2*)p;                  p += (size_t)EG * 8;
    p = alignup(p);
    unsigned short* wp     = (unsigned short*)p;  p += (size_t)10 * FINdim * Hdim * 2;
    p = alignup(p);
    unsigned short* bondbf = (unsigned short*)p;  p += 96 * 2;
    p = alignup(p);
    unsigned short* sbfA   = (unsigned short*)p;  p += (size_t)n * Sdim * 2;
    unsigned short* sbfB   = (unsigned short*)p;  p += (size_t)n * Sdim * 2;
    p = alignup(p);
    float4* rn4L = (float4*)p;               p += (size_t)EL * 16;
    float4* rn4G = (float4*)p;               p += (size_t)EG * 16;
    unsigned short* rbfbL = (unsigned short*)p;  p += (size_t)EL * 32 * 2;
    unsigned short* rbfbG = (unsigned short*)p;  p += (size_t)EG * 32 * 2;

    float* out = (float*)d_out;

    // ---- precompute packed weights + init ----
    pack_kernel<<<(10 * FINdim * Hdim + 80 + 255) / 256, 256, 0, stream>>>(wm, bemb, wp, bondbf);
    temb_kernel<<<B, 64, 0, stream>>>(t, t_w1, t_b1, t_w2, t_b2, temb);
    node_init_kernel<<<(n * Sdim + 255) / 256, 256, 0, stream>>>(x, batch, aemb, temb, sA, sbfA, n);
    hipMemsetAsync(vA, 0, (size_t)n * NVdim * sizeof(float), stream);

    // ---- CSR build ----
    hipMemsetAsync(counts, 0, (size_t)n * sizeof(int), stream);
    count_kernel<<<(EL + 255) / 256, 256, 0, stream>>>(eil, EL, counts);
    scan_kernel<<<1, 256, 0, stream>>>(counts, n, rsL, cursor);
    scatter_kernel<<<(EL + 255) / 256, 256, 0, stream>>>(eil, eal, EL, cursor, st2L, eaL2);

    hipMemsetAsync(counts, 0, (size_t)n * sizeof(int), stream);
    count_kernel<<<(EG + 255) / 256, 256, 0, stream>>>(eig, EG, counts);
    scan_kernel<<<1, 256, 0, stream>>>(counts, n, rsG, cursor);
    scatter_kernel<<<(EG + 255) / 256, 256, 0, stream>>>(eig, eag, EG, cursor, st2G, eaG2);

    // ---- one-time edge geometry (layer-invariant) ----
    geom_kernel<<<(EL + 255) / 256, 256, 0, stream>>>(pos, st2L, eaL2, bondbf, rn4L, rbfbL, EL, 3.0f);
    geom_kernel<<<(EG + 255) / 256, 256, 0, stream>>>(pos, st2G, eaG2, bondbf, rn4G, rbfbG, EG, 10.0f);

    // ---- layers ----
    float* s_cur = sA; float* s_nxt = sB;
    float* v_cur = vA; float* v_nxt = vB;
    unsigned short* sb_cur = sbfA; unsigned short* sb_nxt = sbfB;

    for (int l = 0; l < NLAYER; ++l) {
        for (int k = 0; k < 2; ++k) {
            int ls = l * 2 + k;
            const unsigned short* wpk = wp + (size_t)ls * FINdim * Hdim;
            const float* bgk = bm + (size_t)ls * Hdim;
            const float* wuk = wu + (size_t)ls * Sdim * Sdim;
            const float* buk = bu + (size_t)ls * Sdim;
            if (k == 0) {
                fused_layer_tri<<<n / GW, 192, 0, stream>>>(
                    s_cur, s_nxt, sb_cur, sb_nxt, v_cur, v_nxt,
                    rsL, st2L, rn4L, rbfbL, wpk, bgk, wuk, buk,
                    lng + (size_t)l * Sdim, lnb + (size_t)l * Sdim, 0);
            } else {
                fused_layer_tri<<<n / GW, 192, 0, stream>>>(
                    s_cur, s_nxt, sb_cur, sb_nxt, v_cur, v_nxt,
                    rsG, st2G, rn4G, rbfbG, wpk, bgk, wuk, buk,
                    lng + (size_t)l * Sdim, lnb + (size_t)l * Sdim, 1);
            }
            float* tmp = s_cur; s_cur = s_nxt; s_nxt = tmp;
            tmp = v_cur; v_cur = v_nxt; v_nxt = tmp;
            unsigned short* tb = sb_cur; sb_cur = sb_nxt; sb_nxt = tb;
        }
    }

    head1_kernel<<<n, 64, 0, stream>>>(s_cur, v_cur, wd, wo, dsc, out);
    head2_kernel<<<(EG + 255) / 256, 256, 0, stream>>>(dsc, pos, eig, out, EG);
}

// Round 9
// 662.792 us; speedup vs baseline: 19.1368x; 1.1036x over previous
//
#include <hip/hip_runtime.h>
#include <math.h>

#define Sdim 64
#define Vdim 16
#define NLAYER 5
#define EDdim 16
#define RDdim 16
#define TDdim 64
#define FINdim 160   // 2*S + RD + ED
#define Hdim 96      // S + 2*V
#define NVdim 48     // 3*V
#define ACCW 113     // 64 ms + 48 vm + pad
#define HPAD 98      // hS row stride in floats (2-way banked = free)
#define VSW 52       // vS row stride in floats
#define GW 8         // nodes per block (3 waves)

typedef __attribute__((ext_vector_type(8))) short bf16x8;
typedef __attribute__((ext_vector_type(4))) float f32x4;

__device__ __forceinline__ float silu_f(float x) {
    return x / (1.0f + __expf(-x));
}

__device__ __forceinline__ unsigned short f2bf(float x) {
    union { float f; unsigned u; } v; v.f = x;
    unsigned r = v.u + 0x7fffu + ((v.u >> 16) & 1u);
    return (unsigned short)(r >> 16);
}

// ---------------------------------------------------------------------------
// Pack W (10 layer-sets, [160][96] fp32) into MFMA B-fragment bf16 layout.
// ---------------------------------------------------------------------------
__global__ __launch_bounds__(256) void pack_kernel(
    const float* __restrict__ wm, const float* __restrict__ bemb,
    unsigned short* __restrict__ wp, unsigned short* __restrict__ bondbf)
{
    int idx = blockIdx.x * 256 + threadIdx.x;
    if (idx < 10 * FINdim * Hdim) {
        int ls = idx / (FINdim * Hdim), rem = idx % (FINdim * Hdim);
        int k = rem / Hdim, c = rem % Hdim;
        wp[(size_t)ls * FINdim * Hdim + ((size_t)(k >> 3) * Hdim + c) * 8 + (k & 7)] =
            f2bf(wm[idx]);
    } else if (idx < 10 * FINdim * Hdim + 80) {
        int i = idx - 10 * FINdim * Hdim;
        bondbf[i] = f2bf(bemb[i]);
    }
}

// ---------------------------------------------------------------------------
__global__ __launch_bounds__(64) void temb_kernel(
    const float* __restrict__ t, const float* __restrict__ w1, const float* __restrict__ b1,
    const float* __restrict__ w2, const float* __restrict__ b2, float* __restrict__ temb)
{
    int b = blockIdx.x, j = threadIdx.x;
    __shared__ float row[TDdim];
    __shared__ float hid[TDdim];
    row[j] = t[b * TDdim + j];
    __syncthreads();
    float h = b1[j];
    #pragma unroll 8
    for (int i = 0; i < TDdim; ++i) h = fmaf(row[i], w1[i * TDdim + j], h);
    h = silu_f(h);
    hid[j] = h;
    __syncthreads();
    float o = b2[j];
    #pragma unroll 8
    for (int i = 0; i < TDdim; ++i) o = fmaf(hid[i], w2[i * Sdim + j], o);
    temb[b * Sdim + j] = silu_f(o);
}

// ---------------------------------------------------------------------------
__global__ __launch_bounds__(256) void node_init_kernel(
    const int* __restrict__ x, const int* __restrict__ batch,
    const float* __restrict__ aemb, const float* __restrict__ temb,
    float* __restrict__ sfeat, unsigned short* __restrict__ sbf, int n)
{
    int idx = blockIdx.x * 256 + threadIdx.x;
    if (idx >= n * Sdim) return;
    int node = idx >> 6, j = idx & 63;
    int x0 = x[node * 3 + 0], x1 = x[node * 3 + 1], x2 = x[node * 3 + 2];
    float v = aemb[(0 * 16 + x0) * Sdim + j] + aemb[(16 + x1) * Sdim + j]
            + aemb[(32 + x2) * Sdim + j] + temb[batch[node] * Sdim + j];
    sfeat[idx] = v;
    sbf[idx]   = f2bf(v);
}

// ---------------------------------------------------------------------------
// CSR build
// ---------------------------------------------------------------------------
__global__ __launch_bounds__(256) void count_kernel(
    const int* __restrict__ ei, int E, int* __restrict__ counts)
{
    int e = blockIdx.x * 256 + threadIdx.x;
    if (e >= E) return;
    atomicAdd(&counts[ei[E + e]], 1);
}

// single block; parallel scan (wave shuffle-scan + cross-wave offsets)
__global__ __launch_bounds__(256) void scan_kernel(
    const int* __restrict__ counts, int n,
    int* __restrict__ rowStart, int* __restrict__ cursor)
{
    __shared__ int wsum[4];
    int t = threadIdx.x;
    int chunk = n / 256;
    int base = t * chunk;
    int s = 0;
    for (int i = 0; i < chunk; ++i) s += counts[base + i];
    int lane = t & 63, w = t >> 6;
    int sc = s;
    #pragma unroll
    for (int off = 1; off < 64; off <<= 1) {
        int xv = __shfl_up(sc, off);
        if (lane >= off) sc += xv;
    }
    if (lane == 63) wsum[w] = sc;
    __syncthreads();
    int woff = 0;
    for (int i = 0; i < w; ++i) woff += wsum[i];
    int off = woff + sc - s;   // exclusive prefix for this thread's chunk
    for (int i = 0; i < chunk; ++i) {
        rowStart[base + i] = off;
        cursor[base + i]   = off;
        off += counts[base + i];
    }
    if (t == 255) rowStart[n] = off;
}

__global__ __launch_bounds__(256) void scatter_kernel(
    const int* __restrict__ ei, const int* __restrict__ ea, int E,
    int* __restrict__ cursor, int2* __restrict__ st2, int* __restrict__ eaS)
{
    int e = blockIdx.x * 256 + threadIdx.x;
    if (e >= E) return;
    int tgt = ei[E + e];
    int p = atomicAdd(&cursor[tgt], 1);
    st2[p] = make_int2(ei[e], tgt);
    eaS[p] = ea[e];
}

// ---------------------------------------------------------------------------
// One-time per-edge geometry (layer-invariant).
// ---------------------------------------------------------------------------
__global__ __launch_bounds__(256) void geom_kernel(
    const float* __restrict__ pos,
    const int2* __restrict__ st2, const int* __restrict__ eaS,
    const unsigned short* __restrict__ bondbf,
    float4* __restrict__ rn4, unsigned short* __restrict__ rbfb,
    int E, float cutoff)
{
    int e = blockIdx.x * 256 + threadIdx.x;
    if (e >= E) return;
    int2 st = st2[e];
    int s = st.x, t = st.y;
    float rx = pos[3*t]-pos[3*s], ry = pos[3*t+1]-pos[3*s+1], rz = pos[3*t+2]-pos[3*s+2];
    float d = sqrtf(fmaxf(rx*rx + ry*ry + rz*rz, 1e-6f));
    float invd = 1.0f / d;
    rn4[e] = make_float4(rx*invd, ry*invd, rz*invd, d);
    float env = (d < cutoff) ? 0.5f * (__cosf(3.14159265358979f * d / cutoff) + 1.0f) : 0.0f;
    float invw = (float)RDdim / cutoff;
    unsigned int pk[8];
    #pragma unroll
    for (int i2 = 0; i2 < 8; ++i2) {
        float c0 = cutoff * ((float)(2*i2)     / 15.0f);
        float c1 = cutoff * ((float)(2*i2 + 1) / 15.0f);
        float t0 = (d - c0) * invw, t1 = (d - c1) * invw;
        unsigned short b0 = f2bf(__expf(-0.5f * t0 * t0) * env);
        unsigned short b1 = f2bf(__expf(-0.5f * t1 * t1) * env);
        pk[i2] = (unsigned)b0 | ((unsigned)b1 << 16);
    }
    uint4* o = reinterpret_cast<uint4*>(rbfb + (size_t)e * 32);
    o[0] = make_uint4(pk[0], pk[1], pk[2], pk[3]);
    o[1] = make_uint4(pk[4], pk[5], pk[6], pk[7]);
    int ea = eaS[e];
    const uint4* bp = reinterpret_cast<const uint4*>(bondbf + ea * EDdim);
    o[2] = bp[0];
    o[3] = bp[1];
}

// ---------------------------------------------------------------------------
// Fused layer-set kernel: 3 waves/block, 2 col-tiles per wave, B-fragments
// PINNED in VGPRs (asm residency barrier), rowStart in SGPRs, one-chunk
// software pipeline, zero barriers in the chunk loop.  GW=8 -> 2048 blocks
// (8 blocks/CU) for latency hiding via TLP.
// ---------------------------------------------------------------------------
__global__ __launch_bounds__(192, 4) void fused_layer_tri(
    const float* __restrict__ s_in, float* __restrict__ s_out,
    const unsigned short* __restrict__ sbf_in, unsigned short* __restrict__ sbf_out,
    const float* __restrict__ v_in, float* __restrict__ v_out,
    const int* __restrict__ rowStart,
    const int2* __restrict__ st2,
    const float4* __restrict__ rn4, const unsigned short* __restrict__ rbfb,
    const unsigned short* __restrict__ wp, const float* __restrict__ bg,
    const float* __restrict__ wu, const float* __restrict__ bu,
    const float* __restrict__ lng, const float* __restrict__ lnb,
    int do_ln)
{
    __shared__ float accL[GW * ACCW];               // 3616 B
    __shared__ __align__(16) float hS[16 * HPAD];   // 6272 B
    __shared__ __align__(16) float vS[16 * VSW];    // 3328 B
    __shared__ __align__(16) float rnS[16 * 4];     // 256 B

    const int tid  = threadIdx.x;
    const int lane = tid & 63;
    const int wid  = __builtin_amdgcn_readfirstlane(tid >> 6);  // 0,1,2
    const int l15  = lane & 15, l4 = lane >> 4;
    const int n0   = blockIdx.x * GW;

    // ---- B fragments: 2 col tiles per wave; pinned resident ----
    bf16x8 B0[5], B1[5];
    #pragma unroll
    for (int kk = 0; kk < 5; ++kk) {
        B0[kk] = *reinterpret_cast<const bf16x8*>(
            wp + ((size_t)(kk * 4 + l4) * Hdim + (wid * 2 + 0) * 16 + l15) * 8);
        B1[kk] = *reinterpret_cast<const bf16x8*>(
            wp + ((size_t)(kk * 4 + l4) * Hdim + (wid * 2 + 1) * 16 + l15) * 8);
    }
    #pragma unroll
    for (int kk = 0; kk < 5; ++kk)
        asm volatile("" : "+v"(B0[kk]), "+v"(B1[kk]));   // forbid remat into loop
    const float bias0 = bg[(wid * 2 + 0) * 16 + l15];
    const float bias1 = bg[(wid * 2 + 1) * 16 + l15];

    // ---- rowStart in SGPRs (wave-uniform) ----
    int rs[GW + 1];
    #pragma unroll
    for (int i = 0; i <= GW; ++i)
        rs[i] = __builtin_amdgcn_readfirstlane(rowStart[n0 + i]);

    // ---- zero own accL region ----
    if (wid < 2) {
        if (lane < 32)
            #pragma unroll
            for (int i = 0; i < GW; ++i) accL[i * ACCW + wid * 32 + lane] = 0.0f;
    } else if (lane < 49) {
        #pragma unroll
        for (int i = 0; i < GW; ++i) accL[i * ACCW + 64 + lane] = 0.0f;
    }

    const int eW0 = rs[0];
    const int eW1 = rs[GW];
    const int eLast = max(eW1 - 1, 0);

    auto reduceChunk = [&](int pb) {
        const int pv = min(16, eW1 - pb);
        if (wid < 2) {
            if (lane < 32) {
                const int col = wid * 32 + lane;
                #pragma unroll
                for (int i = 0; i < GW; ++i) {
                    int lo = rs[i] - pb;     if (lo < 0) lo = 0;
                    int hi = rs[i + 1] - pb; if (hi > pv) hi = pv;
                    if (lo >= hi) continue;
                    float msum = 0.0f;
                    for (int e2 = lo; e2 < hi; ++e2) msum += hS[e2 * HPAD + col];
                    accL[i * ACCW + col] += msum;
                }
            }
        } else if (lane < NVdim) {
            const int m = l15, dd = l4;
            #pragma unroll
            for (int i = 0; i < GW; ++i) {
                int lo = rs[i] - pb;     if (lo < 0) lo = 0;
                int hi = rs[i + 1] - pb; if (hi > pv) hi = pv;
                if (lo >= hi) continue;
                float vsum = 0.0f;
                for (int e2 = lo; e2 < hi; ++e2)
                    vsum += vS[e2 * VSW + lane] * hS[e2 * HPAD + 64 + m]
                          + rnS[e2 * 4 + dd]   * hS[e2 * HPAD + 80 + m];
                accL[i * ACCW + 64 + lane] += vsum;
            }
        }
    };

    // ---- pipeline prologue: indices for chunk 0 ----
    int2 stM = st2[min(eW0 + l15, eLast)];
    int  sSt = 0;
    if (wid == 2) sSt = st2[min(eW0 + (lane >> 2), eLast)].x;
    int prevBase = -1;

    for (int base = eW0; base < eW1; base += 16) {
        // 1. A-fragment gathers for current chunk (issue early)
        const unsigned short* sp = sbf_in + (size_t)stM.x * Sdim;
        const unsigned short* tp = sbf_in + (size_t)stM.y * Sdim;
        bf16x8 a0 = *reinterpret_cast<const bf16x8*>(sp + l4 * 8);
        bf16x8 a1 = *reinterpret_cast<const bf16x8*>(sp + 32 + l4 * 8);
        bf16x8 a2 = *reinterpret_cast<const bf16x8*>(tp + l4 * 8);
        bf16x8 a3 = *reinterpret_cast<const bf16x8*>(tp + 32 + l4 * 8);
        bf16x8 a4 = *reinterpret_cast<const bf16x8*>(
            rbfb + (size_t)min(base + l15, eLast) * 32 + l4 * 8);

        // 2. next-chunk index prefetch + v/rn gathers
        int2 stMn = st2[min(base + 16 + l15, eLast)];
        int  sStn = 0;
        float4 va, vb, vc, rnv;
        if (wid == 2) {
            sStn = st2[min(base + 16 + (lane >> 2), eLast)].x;
            const int q = lane & 3;
            const float* vp = v_in + (size_t)sSt * NVdim + q * 12;
            va = *reinterpret_cast<const float4*>(vp);
            vb = *reinterpret_cast<const float4*>(vp + 4);
            vc = *reinterpret_cast<const float4*>(vp + 8);
            if (lane < 16) rnv = rn4[min(base + lane, eLast)];
        }

        // 3. reduce previous chunk (LDS-only; covers the load latency above)
        if (prevBase >= 0) reduceChunk(prevBase);

        // 4. MFMA: 16 edges x 32 cols x K=160
        f32x4 c0 = (f32x4){0.f, 0.f, 0.f, 0.f};
        f32x4 c1 = (f32x4){0.f, 0.f, 0.f, 0.f};
        c0 = __builtin_amdgcn_mfma_f32_16x16x32_bf16(a0, B0[0], c0, 0, 0, 0);
        c1 = __builtin_amdgcn_mfma_f32_16x16x32_bf16(a0, B1[0], c1, 0, 0, 0);
        c0 = __builtin_amdgcn_mfma_f32_16x16x32_bf16(a1, B0[1], c0, 0, 0, 0);
        c1 = __builtin_amdgcn_mfma_f32_16x16x32_bf16(a1, B1[1], c1, 0, 0, 0);
        c0 = __builtin_amdgcn_mfma_f32_16x16x32_bf16(a2, B0[2], c0, 0, 0, 0);
        c1 = __builtin_amdgcn_mfma_f32_16x16x32_bf16(a2, B1[2], c1, 0, 0, 0);
        c0 = __builtin_amdgcn_mfma_f32_16x16x32_bf16(a3, B0[3], c0, 0, 0, 0);
        c1 = __builtin_amdgcn_mfma_f32_16x16x32_bf16(a3, B1[3], c1, 0, 0, 0);
        c0 = __builtin_amdgcn_mfma_f32_16x16x32_bf16(a4, B0[4], c0, 0, 0, 0);
        c1 = __builtin_amdgcn_mfma_f32_16x16x32_bf16(a4, B1[4], c1, 0, 0, 0);

        // 5. epilogue: bias + silu -> own hS columns
        #pragma unroll
        for (int r = 0; r < 4; ++r) {
            hS[(l4 * 4 + r) * HPAD + wid * 32 + l15]      = silu_f(c0[r] + bias0);
            hS[(l4 * 4 + r) * HPAD + wid * 32 + 16 + l15] = silu_f(c1[r] + bias1);
        }
        // 6. commit staging for this chunk (read by reduce next iteration)
        if (wid == 2) {
            const int el = lane >> 2, q = lane & 3;
            *reinterpret_cast<float4*>(&vS[el * VSW + q * 12 + 0]) = va;
            *reinterpret_cast<float4*>(&vS[el * VSW + q * 12 + 4]) = vb;
            *reinterpret_cast<float4*>(&vS[el * VSW + q * 12 + 8]) = vc;
            if (lane < 16) *reinterpret_cast<float4*>(&rnS[lane * 4]) = rnv;
        }
        prevBase = base;
        stM = stMn; sSt = sStn;
    }
    if (prevBase >= 0) reduceChunk(prevBase);
    __syncthreads();

    // ---- node update: wave w handles nodes w, w+3, ... ----
    for (int i = wid; i < GW; i += 3) {
        const int node = n0 + i;
        const float cntn = (float)(rs[i + 1] - rs[i]);
        const float ic = 1.0f / fmaxf(cntn, 1.0f);
        const float* al = &accL[i * ACCW];
        float dot = 0.0f;
        #pragma unroll 8
        for (int ii = 0; ii < Sdim; ++ii) dot = fmaf(al[ii], wu[ii * Sdim + lane], dot);
        float sn = s_in[(size_t)node * Sdim + lane] + silu_f(fmaf(dot, ic, bu[lane]));
        if (do_ln) {
            float mm = sn;
            #pragma unroll
            for (int off = 32; off >= 1; off >>= 1) mm += __shfl_xor(mm, off);
            mm *= (1.0f / 64.0f);
            float dv = sn - mm;
            float var = dv * dv;
            #pragma unroll
            for (int off = 32; off >= 1; off >>= 1) var += __shfl_xor(var, off);
            var *= (1.0f / 64.0f);
            sn = dv * rsqrtf(var + 1e-5f) * lng[lane] + lnb[lane];
        }
        s_out[(size_t)node * Sdim + lane]   = sn;
        sbf_out[(size_t)node * Sdim + lane] = f2bf(sn);
        if (lane < NVdim)
            v_out[(size_t)node * NVdim + lane] =
                v_in[(size_t)node * NVdim + lane] + accL[i * ACCW + Sdim + lane] * ic;
    }
}

// ---------------------------------------------------------------------------
// Head
// ---------------------------------------------------------------------------
__global__ __launch_bounds__(64) void head1_kernel(
    const float* __restrict__ sfeat, const float* __restrict__ vfeat,
    const float* __restrict__ wd, const float* __restrict__ wo,
    float* __restrict__ dsc, float* __restrict__ out)
{
    int node = blockIdx.x, j = threadIdx.x;
    float val = silu_f(sfeat[(size_t)node * Sdim + j]) * wd[j];
    #pragma unroll
    for (int off = 32; off >= 1; off >>= 1) val += __shfl_xor(val, off);
    if (j == 0) dsc[node] = val;
    if (j < 3) {
        float a = 0.0f;
        #pragma unroll
        for (int m = 0; m < Vdim; ++m)
            a += vfeat[(size_t)node * NVdim + j * Vdim + m] * wo[m];
        out[(size_t)node * 3 + j] = a;
    }
}

// node-parallel over CSR-G; no atomics.  pos[src]-pos[tgt] = -rn.xyz * d.
__global__ __launch_bounds__(256) void head2_kernel(
    const float* __restrict__ dsc, const int* __restrict__ rsG,
    const int2* __restrict__ st2G, const float4* __restrict__ rn4G,
    float* __restrict__ out, int n)
{
    int t = blockIdx.x * 256 + threadIdx.x;
    if (t >= n) return;
    int lo = rsG[t], hi = rsG[t + 1];
    float dt = dsc[t];
    float ax = 0.f, ay = 0.f, az = 0.f;
    for (int e = lo; e < hi; ++e) {
        float w = dsc[st2G[e].x] + dt;
        float4 rn = rn4G[e];
        float wd_ = w * rn.w;
        ax -= wd_ * rn.x; ay -= wd_ * rn.y; az -= wd_ * rn.z;
    }
    out[3 * t + 0] += ax;
    out[3 * t + 1] += ay;
    out[3 * t + 2] += az;
}

// ---------------------------------------------------------------------------
extern "C" void kernel_launch(void* const* d_in, const int* in_sizes, int n_in,
                              void* d_out, int out_size, void* d_ws, size_t ws_size,
                              hipStream_t stream)
{
    const int*   x     = (const int*)d_in[0];
    const float* t     = (const float*)d_in[1];
    const float* pos   = (const float*)d_in[2];
    const int*   eil   = (const int*)d_in[3];
    const int*   eig   = (const int*)d_in[4];
    const int*   eal   = (const int*)d_in[5];
    const int*   eag   = (const int*)d_in[6];
    const int*   batch = (const int*)d_in[7];
    const float* aemb  = (const float*)d_in[8];
    const float* bemb  = (const float*)d_in[9];
    const float* t_w1  = (const float*)d_in[10];
    const float* t_b1  = (const float*)d_in[11];
    const float* t_w2  = (const float*)d_in[12];
    const float* t_b2  = (const float*)d_in[13];
    const float* wm    = (const float*)d_in[14];
    const float* bm    = (const float*)d_in[15];
    const float* wu    = (const float*)d_in[16];
    const float* bu    = (const float*)d_in[17];
    const float* lng   = (const float*)d_in[18];
    const float* lnb   = (const float*)d_in[19];
    const float* wd    = (const float*)d_in[20];
    const float* wo    = (const float*)d_in[21];

    const int n  = in_sizes[7];          // 16384
    const int B  = in_sizes[1] / TDdim;  // 64
    const int EL = in_sizes[3] / 2;      // 131072
    const int EG = in_sizes[4] / 2;      // 262144

    // ---- workspace layout ----
    char* p = (char*)d_ws;
    auto alignup = [](char* q) { return (char*)(((size_t)q + 15) & ~(size_t)15); };

    float* temb = (float*)p;                 p += (size_t)B * Sdim * 4;
    float* dsc  = (float*)p;                 p += (size_t)n * 4;
    float* sA   = (float*)p;                 p += (size_t)n * Sdim * 4;
    float* sB   = (float*)p;                 p += (size_t)n * Sdim * 4;
    float* vA   = (float*)p;                 p += (size_t)n * NVdim * 4;
    float* vB   = (float*)p;                 p += (size_t)n * NVdim * 4;
    int* counts = (int*)p;                   p += (size_t)n * 4;
    int* cursor = (int*)p;                   p += (size_t)n * 4;
    int* rsL    = (int*)p;                   p += (size_t)(n + 4) * 4;
    int* rsG    = (int*)p;                   p += (size_t)(n + 4) * 4;
    int* eaL2   = (int*)p;                   p += (size_t)EL * 4;
    int* eaG2   = (int*)p;                   p += (size_t)EG * 4;
    p = alignup(p);
    int2* st2L  = (int2*)p;                  p += (size_t)EL * 8;
    int2* st2G  = (int2*)p;                  p += (size_t)EG * 8;
    p = alignup(p);
    unsigned short* wp     = (unsigned short*)p;  p += (size_t)10 * FINdim * Hdim * 2;
    p = alignup(p);
    unsigned short* bondbf = (unsigned short*)p;  p += 96 * 2;
    p = alignup(p);
    unsigned short* sbfA   = (unsigned short*)p;  p += (size_t)n * Sdim * 2;
    unsigned short* sbfB   = (unsigned short*)p;  p += (size_t)n * Sdim * 2;
    p = alignup(p);
    float4* rn4L = (float4*)p;               p += (size_t)EL * 16;
    float4* rn4G = (float4*)p;               p += (size_t)EG * 16;
    unsigned short* rbfbL = (unsigned short*)p;  p += (size_t)EL * 32 * 2;
    unsigned short* rbfbG = (unsigned short*)p;  p += (size_t)EG * 32 * 2;

    float* out = (float*)d_out;

    // ---- precompute packed weights + init ----
    pack_kernel<<<(10 * FINdim * Hdim + 80 + 255) / 256, 256, 0, stream>>>(wm, bemb, wp, bondbf);
    temb_kernel<<<B, 64, 0, stream>>>(t, t_w1, t_b1, t_w2, t_b2, temb);
    node_init_kernel<<<(n * Sdim + 255) / 256, 256, 0, stream>>>(x, batch, aemb, temb, sA, sbfA, n);
    hipMemsetAsync(vA, 0, (size_t)n * NVdim * sizeof(float), stream);

    // ---- CSR build ----
    hipMemsetAsync(counts, 0, (size_t)n * sizeof(int), stream);
    count_kernel<<<(EL + 255) / 256, 256, 0, stream>>>(eil, EL, counts);
    scan_kernel<<<1, 256, 0, stream>>>(counts, n, rsL, cursor);
    scatter_kernel<<<(EL + 255) / 256, 256, 0, stream>>>(eil, eal, EL, cursor, st2L, eaL2);

    hipMemsetAsync(counts, 0, (size_t)n * sizeof(int), stream);
    count_kernel<<<(EG + 255) / 256, 256, 0, stream>>>(eig, EG, counts);
    scan_kernel<<<1, 256, 0, stream>>>(counts, n, rsG, cursor);
    scatter_kernel<<<(EG + 255) / 256, 256, 0, stream>>>(eig, eag, EG, cursor, st2G, eaG2);

    // ---- one-time edge geometry (layer-invariant) ----
    geom_kernel<<<(EL + 255) / 256, 256, 0, stream>>>(pos, st2L, eaL2, bondbf, rn4L, rbfbL, EL, 3.0f);
    geom_kernel<<<(EG + 255) / 256, 256, 0, stream>>>(pos, st2G, eaG2, bondbf, rn4G, rbfbG, EG, 10.0f);

    // ---- layers ----
    float* s_cur = sA; float* s_nxt = sB;
    float* v_cur = vA; float* v_nxt = vB;
    unsigned short* sb_cur = sbfA; unsigned short* sb_nxt = sbfB;

    for (int l = 0; l < NLAYER; ++l) {
        for (int k = 0; k < 2; ++k) {
            int ls = l * 2 + k;
            const unsigned short* wpk = wp + (size_t)ls * FINdim * Hdim;
            const float* bgk = bm + (size_t)ls * Hdim;
            const float* wuk = wu + (size_t)ls * Sdim * Sdim;
            const float* buk = bu + (size_t)ls * Sdim;
            if (k == 0) {
                fused_layer_tri<<<n / GW, 192, 0, stream>>>(
                    s_cur, s_nxt, sb_cur, sb_nxt, v_cur, v_nxt,
                    rsL, st2L, rn4L, rbfbL, wpk, bgk, wuk, buk,
                    lng + (size_t)l * Sdim, lnb + (size_t)l * Sdim, 0);
            } else {
                fused_layer_tri<<<n / GW, 192, 0, stream>>>(
                    s_cur, s_nxt, sb_cur, sb_nxt, v_cur, v_nxt,
                    rsG, st2G, rn4G, rbfbG, wpk, bgk, wuk, buk,
                    lng + (size_t)l * Sdim, lnb + (size_t)l * Sdim, 1);
            }
            float* tmp = s_cur; s_cur = s_nxt; s_nxt = tmp;
            tmp = v_cur; v_cur = v_nxt; v_nxt = tmp;
            unsigned short* tb = sb_cur; sb_cur = sb_nxt; sb_nxt = tb;
        }
    }

    head1_kernel<<<n, 64, 0, stream>>>(s_cur, v_cur, wd, wo, dsc, out);
    head2_kernel<<<(n + 255) / 256, 256, 0, stream>>>(dsc, rsG, st2G, rn4G, out, n);
}